// Round 8
// baseline (343.316 us; speedup 1.0000x reference)
//
#include <hip/hip_runtime.h>
#include <math.h>
#include <stdint.h>

constexpr int BB = 16384;   // batch
constexpr int NF = 39;      // fields
constexpr int NE = 16;      // embed dim
constexpr int ND = NF * NE; // 624
constexpr int FIELD_DIM = 26000;
constexpr float EPS_ = 1e-5f;

typedef __bf16 bfx8 __attribute__((ext_vector_type(8)));
typedef float f32x4 __attribute__((ext_vector_type(4)));
typedef short s16x8 __attribute__((ext_vector_type(8)));

static __device__ __forceinline__ unsigned short f2bf(float f) {
    union { float f; unsigned u; } a; a.f = f;
    unsigned r = a.u + 0x7fffu + ((a.u >> 16) & 1u); // RNE
    return (unsigned short)(r >> 16);
}
static __device__ __forceinline__ float bf2f(unsigned short u) {
    union { unsigned u; float f; } a; a.u = ((unsigned)u) << 16;
    return a.f;
}

// ---------------- fused prep: weight transposes + ctrl fp64 transpose + stats zero ----------------
// grid: [0,2560) w1t | [2560,4608) w2t | [4608,5120) w3t | [5120,5218) wcd | rest: zero stats
__global__ void k_prep(const float* __restrict__ w1, const float* __restrict__ w2,
                       const float* __restrict__ w3, const float* __restrict__ cw,
                       unsigned short* __restrict__ w1t, unsigned short* __restrict__ w2t,
                       unsigned short* __restrict__ w3t, double* __restrict__ wcd,
                       double* __restrict__ stats, int nstats) {
    int b = blockIdx.x;
    if (b < 2560) {                       // w1t: (1024, 640) bf16, K 624->640 zero-pad
        int gid = b * 256 + threadIdx.x;  // < 655360
        int n = gid / 640, k = gid % 640;
        w1t[gid] = f2bf(k < 624 ? w1[(size_t)k * 1024 + n] : 0.f);
    } else if (b < 4608) {                // w2t: (512, 1024)
        int gid = (b - 2560) * 256 + threadIdx.x;
        int n = gid >> 10, k = gid & 1023;
        w2t[gid] = f2bf(w2[(size_t)k * 512 + n]);
    } else if (b < 5120) {                // w3t: (256, 512)
        int gid = (b - 4608) * 256 + threadIdx.x;
        int n = gid >> 9, k = gid & 511;
        w3t[gid] = f2bf(w3[(size_t)k * 256 + n]);
    } else if (b < 5218) {                // wcd: (40, 624) fp64, cols>=39 zero
        int gid = (b - 5120) * 256 + threadIdx.x;
        if (gid < 40 * ND) {
            int j = gid / ND, k = gid % ND;
            wcd[gid] = (j < NF) ? (double)cw[(size_t)k * NF + j] : 0.0;
        }
    } else {                              // zero fp64 stats
        int gid = (b - 5218) * 256 + threadIdx.x;
        if (gid < nstats) stats[gid] = 0.0;
    }
}

// ---------------- field BN stats: sum/sumsq per field over (B, E), fp64 atomics ----------------
__global__ void k_field_stats(const int* __restrict__ x, const float* __restrict__ emb,
                              double* __restrict__ stats /* 2*NF */) {
    int f = blockIdx.x;
    int r = blockIdx.y * blockDim.x + threadIdx.x;
    double s = 0.0, q = 0.0;
    if (r < BB) {
        long long id = (long long)x[r * NF + f] + (long long)f * FIELD_DIM;
        const float4* p = (const float4*)(emb + id * NE);
#pragma unroll
        for (int i = 0; i < 4; ++i) {
            float4 v = p[i];
            s += (double)v.x; s += (double)v.y; s += (double)v.z; s += (double)v.w;
            q += (double)v.x * v.x; q += (double)v.y * v.y;
            q += (double)v.z * v.z; q += (double)v.w * v.w;
        }
    }
    __shared__ double ls[256], lq[256];
    ls[threadIdx.x] = s; lq[threadIdx.x] = q;
    __syncthreads();
    for (int off = 128; off > 0; off >>= 1) {
        if ((int)threadIdx.x < off) {
            ls[threadIdx.x] += ls[threadIdx.x + off];
            lq[threadIdx.x] += lq[threadIdx.x + off];
        }
        __syncthreads();
    }
    if (threadIdx.x == 0) {
        atomicAdd(&stats[f], ls[0]);
        atomicAdd(&stats[NF + f], lq[0]);
    }
}

// ---------------- gather + normalize -> flat (B, 624) fp32; field-BN finalize fused ----------------
__global__ void k_flat_norm(const int* __restrict__ x, const float* __restrict__ emb,
                            const double* __restrict__ stats, const float* __restrict__ bng,
                            const float* __restrict__ bnb, float* __restrict__ flat) {
    __shared__ float sc_s[NF], sh_s[NF];
    if ((int)threadIdx.x < NF) {
        int f = threadIdx.x;
        double cnt = (double)BB * NE;
        double mu = stats[f] / cnt;
        double var = stats[NF + f] / cnt - mu * mu;
        float sc = (float)((double)bng[f] / sqrt(var + (double)EPS_));
        sc_s[f] = sc;
        sh_s[f] = bnb[f] - (float)mu * sc;
    }
    __syncthreads();
    int gid = blockIdx.x * blockDim.x + threadIdx.x; // r*NF + f
    if (gid >= BB * NF) return;
    int f = gid % NF;
    long long id = (long long)x[gid] + (long long)f * FIELD_DIM;
    float sc = sc_s[f], sh = sh_s[f];
    const float4* p = (const float4*)(emb + id * NE);
    float4* o = (float4*)(flat) + (size_t)gid * 4;
#pragma unroll
    for (int i = 0; i < 4; ++i) {
        float4 v = p[i];
        o[i] = make_float4(fmaf(v.x, sc, sh), fmaf(v.y, sc, sh),
                           fmaf(v.z, sc, sh), fmaf(v.w, sc, sh));
    }
}

// ---------------- controller GEMM (B,624)@(624,39)+b, fp64, W via scalar loads ----------------
// 256 blocks x 256 threads (4 waves). Block = 64 rows (lane = row); wave = 10 cols.
// A staged row-major in LDS (b128/lane/4k); W fp64 read wave-uniform (s_load path).
__launch_bounds__(256)
__global__ void k_ctrl_gemm(const float* __restrict__ flat, const double* __restrict__ wcd,
                            const float* __restrict__ bias, float* __restrict__ z,
                            double* __restrict__ stats /* 2*NF */) {
    __shared__ __align__(16) float As[64][212];  // 212 = 4*53: aligned b128 rows, spread banks
    const int t = threadIdx.x;
    const int lane = t & 63;
    const int wid = __builtin_amdgcn_readfirstlane(t >> 6);
    const int m0 = blockIdx.x * 64;
    const int col0 = wid * 10;
    double acc[10] = {};
    for (int k0 = 0; k0 < ND; k0 += 208) {
        // stage 64 rows x 208 floats (3328 float4, 13 per thread, coalesced)
#pragma unroll
        for (int i = 0; i < 13; ++i) {
            int idx = t + 256 * i;          // 0..3327
            int row = idx / 52, c4 = idx % 52;
            float4 v = *(const float4*)(flat + (size_t)(m0 + row) * ND + k0 + c4 * 4);
            *(float4*)&As[row][c4 * 4] = v;
        }
        __syncthreads();
        const double* wp = wcd + (size_t)col0 * ND + k0;
#pragma unroll 2
        for (int g = 0; g < 52; ++g) {
            float4 a4 = *(const float4*)&As[lane][g * 4];
            double a0 = (double)a4.x, a1 = (double)a4.y,
                   a2 = (double)a4.z, a3 = (double)a4.w;
#pragma unroll
            for (int c = 0; c < 10; ++c) {
                const double* wc = wp + (size_t)c * ND + g * 4;
                acc[c] += a0 * wc[0];
                acc[c] += a1 * wc[1];
                acc[c] += a2 * wc[2];
                acc[c] += a3 * wc[3];
            }
        }
        __syncthreads();
    }
    // epilogue: bias, z store (fp32), fused per-column stats via wave reduce + fp64 atomics
#pragma unroll
    for (int c = 0; c < 10; ++c) {
        int col = col0 + c;
        if (col < NF) {
            float v = (float)(acc[c] + (double)bias[col]);
            z[(size_t)(m0 + lane) * NF + col] = v;
            double s = (double)v, q = (double)v * (double)v;
#pragma unroll
            for (int off = 32; off > 0; off >>= 1) {
                s += __shfl_xor(s, off, 64);
                q += __shfl_xor(q, off, 64);
            }
            if (lane == 0) {
                atomicAdd(&stats[col], s);
                atomicAdd(&stats[NF + col], q);
            }
        }
    }
}

// ---------------- ctrl-BN finalize + BN+ReLU + top-k + gate -> flatg (fused) ----------------
__global__ void k_topk_gate(const float* __restrict__ zc, const double* __restrict__ stats,
                            const float* __restrict__ cbg, const float* __restrict__ cbb,
                            const int* __restrict__ kptr, const float* __restrict__ flat,
                            unsigned short* __restrict__ flatg) {
    __shared__ float sc_s[NF], sh_s[NF];
    int t = threadIdx.x;
    if (t < NF) {
        double mu = stats[t] / (double)BB;
        double var = stats[NF + t] / (double)BB - mu * mu;
        float sc = (float)((double)cbg[t] / sqrt(var + (double)EPS_));
        sc_s[t] = sc;
        sh_s[t] = cbb[t] - (float)mu * sc;
    }
    __syncthreads();
    int r = blockIdx.x * 4 + (t >> 6);
    int lane = t & 63;
    int k = kptr[0];
    bool active = (lane < NF);
    float w = 0.f;
    if (active) {
        float v = zc[(size_t)r * NF + lane];
        w = fmaxf(fmaf(v, sc_s[lane], sh_s[lane]), 0.f);
    }
    float cur = active ? w : -1.f;
    bool sel = false;
    float sum = 0.f;
    for (int it = 0; it < k; ++it) {
        // key: (value bits)<<32 | (63-lane); value>=0 so bit order == value order.
        unsigned hi = 0u, lo = 0u;
        if (cur >= 0.f) { hi = __float_as_uint(cur); lo = (unsigned)(63 - lane); }
#pragma unroll
        for (int off = 32; off > 0; off >>= 1) {
            unsigned ohi = __shfl_xor(hi, off, 64);
            unsigned olo = __shfl_xor(lo, off, 64);
            if (ohi > hi || (ohi == hi && olo > lo)) { hi = ohi; lo = olo; }
        }
        int wlane = 63 - (int)(lo & 63u);
        float wval = __uint_as_float(hi);
        sum += wval;
        if (lane == wlane) { sel = true; cur = -1.f; }
    }
    if (active) {
        float ms = sel ? ((sum > 0.f) ? (w / sum) : 0.f) : 0.f;
        const float* src = flat + (size_t)r * ND + lane * 16;
        unsigned short* dst = flatg + (size_t)r * 640 + lane * 16;
#pragma unroll
        for (int h = 0; h < 2; ++h) {
            union { s16x8 v; unsigned short u[8]; } p;
#pragma unroll
            for (int j = 0; j < 8; ++j) p.u[j] = f2bf(src[h * 8 + j] * ms);
            *(s16x8*)(dst + h * 8) = p.v;
        }
    } else if (lane == NF) {
        s16x8 zv = {};
        *(s16x8*)(flatg + (size_t)r * 640 + 624) = zv;
        *(s16x8*)(flatg + (size_t)r * 640 + 632) = zv;
    }
}

// ---------------- bf16 MFMA GEMM: C(M,N) = A(M,K) @ Bt(N,K)^T + bias, fused col stats ----------------
// 128x128 tile, 4 waves, BK=64, mfma 16x16x32 bf16, XOR-swizzled LDS, global_load_lds x16.
__launch_bounds__(256)
__global__ void k_mfma_gemm(const unsigned short* __restrict__ A,  // M x K bf16
                            const unsigned short* __restrict__ Bt, // N x K bf16
                            const float* __restrict__ bias,
                            unsigned short* __restrict__ C,        // M x N bf16
                            double* __restrict__ stats,            // 2*N fp64
                            int M, int K, int N) {
    __shared__ char lds[32768];
    char* As = lds;
    char* Bs = lds + 16384;
    const int t = threadIdx.x;
    const int l = t & 63;
    const int w = t >> 6;
    const int m0 = blockIdx.y * 128, n0 = blockIdx.x * 128;
    const int Wr = (w >> 1) * 64, Wc = (w & 1) * 64;

    const int srow = t >> 3;            // 0..31
    const int sswz = (t & 7) ^ (srow & 7);
    const unsigned short* ga[4];
    const unsigned short* gb[4];
#pragma unroll
    for (int i = 0; i < 4; ++i) {
        ga[i] = A + (size_t)(m0 + i * 32 + srow) * K + sswz * 8;
        gb[i] = Bt + (size_t)(n0 + i * 32 + srow) * K + sswz * 8;
    }
    int a_off[4][2], b_off[4][2];
#pragma unroll
    for (int m = 0; m < 4; ++m) {
#pragma unroll
        for (int h = 0; h < 2; ++h) {
            int r = Wr + m * 16 + (l & 15);
            a_off[m][h] = r * 128 + (((h * 4 + (l >> 4)) ^ (r & 7)) << 4);
            int c = Wc + m * 16 + (l & 15);
            b_off[m][h] = c * 128 + (((h * 4 + (l >> 4)) ^ (c & 7)) << 4);
        }
    }
    f32x4 acc[4][4] = {};
    for (int k0 = 0; k0 < K; k0 += 64) {
#pragma unroll
        for (int i = 0; i < 4; ++i) {
            __builtin_amdgcn_global_load_lds(
                (const __attribute__((address_space(1))) void*)ga[i],
                (__attribute__((address_space(3))) void*)(As + i * 4096 + t * 16), 16, 0, 0);
            __builtin_amdgcn_global_load_lds(
                (const __attribute__((address_space(1))) void*)gb[i],
                (__attribute__((address_space(3))) void*)(Bs + i * 4096 + t * 16), 16, 0, 0);
            ga[i] += 64; gb[i] += 64;
        }
        __syncthreads();
#pragma unroll
        for (int h = 0; h < 2; ++h) {
            bfx8 af[4], bv[4];
#pragma unroll
            for (int m = 0; m < 4; ++m)
                af[m] = __builtin_bit_cast(bfx8, *(const s16x8*)(As + a_off[m][h]));
#pragma unroll
            for (int n = 0; n < 4; ++n)
                bv[n] = __builtin_bit_cast(bfx8, *(const s16x8*)(Bs + b_off[n][h]));
#pragma unroll
            for (int m = 0; m < 4; ++m)
#pragma unroll
                for (int n = 0; n < 4; ++n)
                    acc[m][n] = __builtin_amdgcn_mfma_f32_16x16x32_bf16(af[m], bv[n], acc[m][n], 0, 0, 0);
        }
        __syncthreads();
    }
#pragma unroll
    for (int n = 0; n < 4; ++n) {
        int nc = n0 + Wc + n * 16 + (l & 15);
        float bs = bias[nc];
        double s = 0.0, q = 0.0;
#pragma unroll
        for (int m = 0; m < 4; ++m) {
            int rbase = m0 + Wr + m * 16 + ((l >> 4) << 2);
#pragma unroll
            for (int i = 0; i < 4; ++i) {
                float v = acc[m][n][i] + bs;
                C[(size_t)(rbase + i) * N + nc] = f2bf(v);
                s += (double)v;
                q += (double)v * (double)v;
            }
        }
        s += __shfl_xor(s, 16, 64); s += __shfl_xor(s, 32, 64);
        q += __shfl_xor(q, 16, 64); q += __shfl_xor(q, 32, 64);
        if ((l >> 4) == 0) {
            atomicAdd(&stats[nc], s);
            atomicAdd(&stats[N + nc], q);
        }
    }
}

// ---------------- fused BN finalize (fp32) + BN + ReLU in place on bf16 ----------------
__global__ void k_bn_relu_b(unsigned short* __restrict__ h, const double* __restrict__ stats,
                            const float* __restrict__ g, const float* __restrict__ be,
                            int N, int total8) {
    __shared__ float scs[1024], shs[1024];
    constexpr double inv_bb = 1.0 / (double)BB; // 2^-14, exact
    for (int c = threadIdx.x; c < N; c += 256) {
        double mu = stats[c] * inv_bb;
        double var = stats[N + c] * inv_bb - mu * mu;
        float sc = g[c] / sqrtf((float)var + EPS_);
        scs[c] = sc;
        shs[c] = be[c] - (float)mu * sc;
    }
    __syncthreads();
#pragma unroll
    for (int it = 0; it < 4; ++it) {
        int gid = blockIdx.x * 1024 + it * 256 + threadIdx.x;
        if (gid >= total8) continue;
        size_t base = (size_t)gid * 8;
        int c = (int)(base & (size_t)(N - 1)); // N power of two
        union { s16x8 v; unsigned short u[8]; } p;
        p.v = *(const s16x8*)(h + base);
#pragma unroll
        for (int j = 0; j < 8; ++j) {
            float x = bf2f(p.u[j]);
            p.u[j] = f2bf(fmaxf(fmaf(x, scs[c + j], shs[c + j]), 0.f));
        }
        *(s16x8*)(h + base) = p.v;
    }
}

// ---------------- final: sigmoid(wide_linear + h3@w_out + b_out), wide part fused ----------------
__global__ void k_out(const unsigned short* __restrict__ h3, const float* __restrict__ wo,
                      const float* __restrict__ bo, const int* __restrict__ x,
                      const float* __restrict__ lt, const float* __restrict__ lb,
                      float* __restrict__ out) {
    int r = blockIdx.x * (blockDim.x >> 6) + ((int)threadIdx.x >> 6);
    int lane = threadIdx.x & 63;
    float s = 0.f;
#pragma unroll
    for (int k = lane; k < 256; k += 64) s += bf2f(h3[(size_t)r * 256 + k]) * wo[k];
    if (lane < NF) {
        long long id = (long long)x[r * NF + lane] + (long long)lane * FIELD_DIM;
        s += lt[id];
    }
#pragma unroll
    for (int off = 32; off > 0; off >>= 1) s += __shfl_xor(s, off, 64);
    if (lane == 0) {
        float tt = s + bo[0] + lb[0];
        out[r] = 1.f / (1.f + expf(-tt));
    }
}

extern "C" void kernel_launch(void* const* d_in, const int* in_sizes, int n_in,
                              void* d_out, int out_size, void* d_ws, size_t ws_size,
                              hipStream_t stream) {
    const int* x = (const int*)d_in[0];
    const float* emb = (const float*)d_in[1];
    const float* lint = (const float*)d_in[2];
    const float* linb = (const float*)d_in[3];
    const float* bng = (const float*)d_in[4];
    const float* bnb = (const float*)d_in[5];
    const float* cw = (const float*)d_in[6];
    const float* cb = (const float*)d_in[7];
    const float* cbg = (const float*)d_in[8];
    const float* cbb = (const float*)d_in[9];
    const float* w1 = (const float*)d_in[10];
    const float* b1 = (const float*)d_in[11];
    const float* g1 = (const float*)d_in[12];
    const float* be1 = (const float*)d_in[13];
    const float* w2 = (const float*)d_in[14];
    const float* b2 = (const float*)d_in[15];
    const float* g2 = (const float*)d_in[16];
    const float* be2 = (const float*)d_in[17];
    const float* w3 = (const float*)d_in[18];
    const float* b3 = (const float*)d_in[19];
    const float* g3 = (const float*)d_in[20];
    const float* be3 = (const float*)d_in[21];
    const float* wo = (const float*)d_in[22];
    const float* bo = (const float*)d_in[23];
    const int* kptr = (const int*)d_in[24];
    float* out = (float*)d_out;

    char* p = (char*)d_ws;
    float* flat = (float*)p;                 p += (size_t)BB * ND * 4;      // fp32, ctrl path
    unsigned short* flatg = (unsigned short*)p; p += (size_t)BB * 640 * 2;  // gated bf16, K-padded
    unsigned short* h1 = (unsigned short*)p; p += (size_t)BB * 1024 * 2;
    unsigned short* h2 = (unsigned short*)p; p += (size_t)BB * 512 * 2;
    unsigned short* h3 = (unsigned short*)p; p += (size_t)BB * 256 * 2;
    unsigned short* w1t = (unsigned short*)p; p += (size_t)1024 * 640 * 2;
    unsigned short* w2t = (unsigned short*)p; p += (size_t)512 * 1024 * 2;
    unsigned short* w3t = (unsigned short*)p; p += (size_t)256 * 512 * 2;
    double* wcd = (double*)p;                p += (size_t)40 * ND * 8;      // ctrl w fp64 (40 cols x 624)
    float* zc = (float*)p;                   p += (size_t)BB * NF * 4;
    // disjoint per-layer fp64 stat regions, zeroed inside k_prep
    double* stats_all = (double*)p;
    double* stats_f = stats_all;             // 2*39
    double* stats_c = stats_f + 2 * NF;      // 2*39
    double* stats_1 = stats_c + 2 * NF;      // 2*1024
    double* stats_2 = stats_1 + 2 * 1024;    // 2*512
    double* stats_3 = stats_2 + 2 * 512;     // 2*256
    int stats_doubles = 2 * (NF + NF + 1024 + 512 + 256); // 3662

    // ---- prep: weight transposes + stats zero (one kernel) ----
    int zero_blocks = (stats_doubles + 255) / 256;        // 15
    k_prep<<<5218 + zero_blocks, 256, 0, stream>>>(w1, w2, w3, cw, w1t, w2t, w3t, wcd,
                                                   stats_all, stats_doubles);

    // ---- field BN (finalize fused into flat_norm) ----
    k_field_stats<<<dim3(NF, BB / 256), 256, 0, stream>>>(x, emb, stats_f);
    k_flat_norm<<<(BB * NF + 255) / 256, 256, 0, stream>>>(x, emb, stats_f, bng, bnb, flat);

    // ---- controller (fp64, scalar-W + per-lane-row LDS; finalize+topk+gate fused) ----
    k_ctrl_gemm<<<BB / 64, 256, 0, stream>>>(flat, wcd, cb, zc, stats_c);
    k_topk_gate<<<BB / 4, 256, 0, stream>>>(zc, stats_c, cbg, cbb, kptr, flat, flatg);

    // ---- MLP layer 1: 640(pad) -> 1024 ----
    k_mfma_gemm<<<dim3(1024 / 128, BB / 128), 256, 0, stream>>>(flatg, w1t, b1, h1, stats_1, BB, 640, 1024);
    k_bn_relu_b<<<(BB * 1024 / 8 + 1023) / 1024, 256, 0, stream>>>(h1, stats_1, g1, be1, 1024, BB * 1024 / 8);

    // ---- MLP layer 2: 1024 -> 512 ----
    k_mfma_gemm<<<dim3(512 / 128, BB / 128), 256, 0, stream>>>(h1, w2t, b2, h2, stats_2, BB, 1024, 512);
    k_bn_relu_b<<<(BB * 512 / 8 + 1023) / 1024, 256, 0, stream>>>(h2, stats_2, g2, be2, 512, BB * 512 / 8);

    // ---- MLP layer 3: 512 -> 256 ----
    k_mfma_gemm<<<dim3(256 / 128, BB / 128), 256, 0, stream>>>(h2, w3t, b3, h3, stats_3, BB, 512, 256);
    k_bn_relu_b<<<(BB * 256 / 8 + 1023) / 1024, 256, 0, stream>>>(h3, stats_3, g3, be3, 256, BB * 256 / 8);

    // ---- output (wide linear fused) ----
    k_out<<<BB / 4, 256, 0, stream>>>(h3, wo, bo, x, lint, linb, out);
}

// Round 9
// 278.993 us; speedup vs baseline: 1.2306x; 1.2306x over previous
//
#include <hip/hip_runtime.h>
#include <math.h>
#include <stdint.h>

constexpr int BB = 16384;   // batch
constexpr int NF = 39;      // fields
constexpr int NE = 16;      // embed dim
constexpr int ND = NF * NE; // 624
constexpr int FIELD_DIM = 26000;
constexpr float EPS_ = 1e-5f;

typedef __bf16 bfx8 __attribute__((ext_vector_type(8)));
typedef float f32x4 __attribute__((ext_vector_type(4)));
typedef short s16x8 __attribute__((ext_vector_type(8)));

static __device__ __forceinline__ unsigned short f2bf(float f) {
    union { float f; unsigned u; } a; a.f = f;
    unsigned r = a.u + 0x7fffu + ((a.u >> 16) & 1u); // RNE
    return (unsigned short)(r >> 16);
}
static __device__ __forceinline__ float bf2f(unsigned short u) {
    union { unsigned u; float f; } a; a.u = ((unsigned)u) << 16;
    return a.f;
}

// ---------------- fused prep: weight transposes + ctrl transpose + stats zero ----------------
// grid: [0,2560) w1t | [2560,4608) w2t | [4608,5120) w3t | [5120,5237) wct | rest: zero stats
__global__ void k_prep(const float* __restrict__ w1, const float* __restrict__ w2,
                       const float* __restrict__ w3, const float* __restrict__ cw,
                       unsigned short* __restrict__ w1t, unsigned short* __restrict__ w2t,
                       unsigned short* __restrict__ w3t, float* __restrict__ wct,
                       double* __restrict__ stats, int nstats) {
    int b = blockIdx.x;
    if (b < 2560) {                       // w1t: (1024, 640) bf16, K 624->640 zero-pad
        int gid = b * 256 + threadIdx.x;  // < 655360
        int n = gid / 640, k = gid % 640;
        w1t[gid] = f2bf(k < 624 ? w1[(size_t)k * 1024 + n] : 0.f);
    } else if (b < 4608) {                // w2t: (512, 1024)
        int gid = (b - 2560) * 256 + threadIdx.x;
        int n = gid >> 10, k = gid & 1023;
        w2t[gid] = f2bf(w2[(size_t)k * 512 + n]);
    } else if (b < 5120) {                // w3t: (256, 512)
        int gid = (b - 4608) * 256 + threadIdx.x;
        int n = gid >> 9, k = gid & 511;
        w3t[gid] = f2bf(w3[(size_t)k * 256 + n]);
    } else if (b < 5237) {                // wct: (48, 624) fp32, rows>=39 zero
        int gid = (b - 5120) * 256 + threadIdx.x;
        if (gid < 48 * ND) {
            int j = gid / ND, k = gid % ND;
            wct[gid] = (j < NF) ? cw[(size_t)k * NF + j] : 0.f;
        }
    } else {                              // zero fp64 stats
        int gid = (b - 5237) * 256 + threadIdx.x;
        if (gid < nstats) stats[gid] = 0.0;
    }
}

// ---------------- field BN stats: sum/sumsq per field over (B, E), fp64 atomics ----------------
__global__ void k_field_stats(const int* __restrict__ x, const float* __restrict__ emb,
                              double* __restrict__ stats /* 2*NF */) {
    int f = blockIdx.x;
    int r = blockIdx.y * blockDim.x + threadIdx.x;
    double s = 0.0, q = 0.0;
    if (r < BB) {
        long long id = (long long)x[r * NF + f] + (long long)f * FIELD_DIM;
        const float4* p = (const float4*)(emb + id * NE);
#pragma unroll
        for (int i = 0; i < 4; ++i) {
            float4 v = p[i];
            s += (double)v.x; s += (double)v.y; s += (double)v.z; s += (double)v.w;
            q += (double)v.x * v.x; q += (double)v.y * v.y;
            q += (double)v.z * v.z; q += (double)v.w * v.w;
        }
    }
    __shared__ double ls[256], lq[256];
    ls[threadIdx.x] = s; lq[threadIdx.x] = q;
    __syncthreads();
    for (int off = 128; off > 0; off >>= 1) {
        if ((int)threadIdx.x < off) {
            ls[threadIdx.x] += ls[threadIdx.x + off];
            lq[threadIdx.x] += lq[threadIdx.x + off];
        }
        __syncthreads();
    }
    if (threadIdx.x == 0) {
        atomicAdd(&stats[f], ls[0]);
        atomicAdd(&stats[NF + f], lq[0]);
    }
}

// ---------------- gather + normalize -> flat (B, 624) fp32; field-BN finalize fused ----------------
__global__ void k_flat_norm(const int* __restrict__ x, const float* __restrict__ emb,
                            const double* __restrict__ stats, const float* __restrict__ bng,
                            const float* __restrict__ bnb, float* __restrict__ flat) {
    __shared__ float sc_s[NF], sh_s[NF];
    if ((int)threadIdx.x < NF) {
        int f = threadIdx.x;
        double cnt = (double)BB * NE;
        double mu = stats[f] / cnt;
        double var = stats[NF + f] / cnt - mu * mu;
        float sc = (float)((double)bng[f] / sqrt(var + (double)EPS_));
        sc_s[f] = sc;
        sh_s[f] = bnb[f] - (float)mu * sc;
    }
    __syncthreads();
    int gid = blockIdx.x * blockDim.x + threadIdx.x; // r*NF + f
    if (gid >= BB * NF) return;
    int f = gid % NF;
    long long id = (long long)x[gid] + (long long)f * FIELD_DIM;
    float sc = sc_s[f], sh = sh_s[f];
    const float4* p = (const float4*)(emb + id * NE);
    float4* o = (float4*)(flat) + (size_t)gid * 4;
#pragma unroll
    for (int i = 0; i < 4; ++i) {
        float4 v = p[i];
        o[i] = make_float4(fmaf(v.x, sc, sh), fmaf(v.y, sc, sh),
                           fmaf(v.z, sc, sh), fmaf(v.w, sc, sh));
    }
}

// ---------------- controller GEMM (B,624)@(624,39)+b, fp64 accum, LDS-tiled, fused col stats ----------------
// ROUND-5 RESTORED (measured 54.2 us). 256 blocks x 256 threads. Tile 64 rows x 48 cols, K-chunks 64.
__launch_bounds__(256)
__global__ void k_ctrl_gemm(const float* __restrict__ flat, const float* __restrict__ wct,
                            const float* __restrict__ bias, float* __restrict__ z,
                            double* __restrict__ stats /* 2*NF */) {
    __shared__ float As[64][68];       // [row][kk], padded
    __shared__ float Ws[64][49];       // [kk][col]
    __shared__ double Sred[2][16][48];
    const int t = threadIdx.x;
    const int tn = t & 15;             // col group: cols 3tn..3tn+2
    const int tm = t >> 4;             // row group: rows 4tm..4tm+3
    const int m0 = blockIdx.x * 64;
    double acc[4][3] = {};
    for (int k0 = 0; k0 < ND; k0 += 64) {
        const int kl = (ND - k0 >= 64) ? 64 : (ND - k0);   // 64 or 48
        const int kl4 = kl >> 2;
        // stage A: 64 rows x kl floats (float4, coalesced)
#pragma unroll
        for (int i = 0; i < 4; ++i) {
            int idx = t + 256 * i;     // 0..1023
            int row = idx >> 4, c4 = idx & 15;
            if (c4 < kl4) {
                float4 v = *(const float4*)(flat + (size_t)(m0 + row) * ND + k0 + c4 * 4);
                *(float4*)&As[row][c4 * 4] = v;
            }
        }
        // stage W: 48 cols x kl floats, transposed into [kk][col]
        {
            int col = t >> 4;          // 0..15
            int c4 = t & 15;
#pragma unroll
            for (int cp = 0; cp < 3; ++cp, col += 16) {
                if (c4 < kl4) {
                    float4 v = *(const float4*)(wct + (size_t)col * ND + k0 + c4 * 4);
                    Ws[c4 * 4 + 0][col] = v.x; Ws[c4 * 4 + 1][col] = v.y;
                    Ws[c4 * 4 + 2][col] = v.z; Ws[c4 * 4 + 3][col] = v.w;
                }
            }
        }
        __syncthreads();
#pragma unroll 4
        for (int kk = 0; kk < kl; ++kk) {
            double a0 = (double)As[4 * tm + 0][kk];
            double a1 = (double)As[4 * tm + 1][kk];
            double a2 = (double)As[4 * tm + 2][kk];
            double a3 = (double)As[4 * tm + 3][kk];
            double w0 = (double)Ws[kk][3 * tn + 0];
            double w1 = (double)Ws[kk][3 * tn + 1];
            double w2 = (double)Ws[kk][3 * tn + 2];
            acc[0][0] += a0 * w0; acc[0][1] += a0 * w1; acc[0][2] += a0 * w2;
            acc[1][0] += a1 * w0; acc[1][1] += a1 * w1; acc[1][2] += a1 * w2;
            acc[2][0] += a2 * w0; acc[2][1] += a2 * w1; acc[2][2] += a2 * w2;
            acc[3][0] += a3 * w0; acc[3][1] += a3 * w1; acc[3][2] += a3 * w2;
        }
        __syncthreads();
    }
    // store + fused per-column stats (over stored f32 values, accumulated in fp64)
#pragma unroll
    for (int j = 0; j < 3; ++j) {
        int col = 3 * tn + j;
        double s = 0.0, q = 0.0;
        if (col < NF) {
            float bs = bias[col];
#pragma unroll
            for (int i = 0; i < 4; ++i) {
                float v = (float)(acc[i][j] + (double)bs);
                z[(size_t)(m0 + 4 * tm + i) * NF + col] = v;
                s += (double)v;
                q += (double)v * (double)v;
            }
        }
        Sred[0][tm][col] = s;
        Sred[1][tm][col] = q;
    }
    __syncthreads();
    if (t < NF) {
        double ts = 0.0, tq = 0.0;
#pragma unroll
        for (int i = 0; i < 16; ++i) { ts += Sred[0][i][t]; tq += Sred[1][i][t]; }
        atomicAdd(&stats[t], ts);
        atomicAdd(&stats[NF + t], tq);
    }
}

// ---------------- ctrl-BN finalize + BN+ReLU + top-k + gate -> flatg (fused) ----------------
__global__ void k_topk_gate(const float* __restrict__ zc, const double* __restrict__ stats,
                            const float* __restrict__ cbg, const float* __restrict__ cbb,
                            const int* __restrict__ kptr, const float* __restrict__ flat,
                            unsigned short* __restrict__ flatg) {
    __shared__ float sc_s[NF], sh_s[NF];
    int t = threadIdx.x;
    if (t < NF) {
        double mu = stats[t] / (double)BB;
        double var = stats[NF + t] / (double)BB - mu * mu;
        float sc = (float)((double)cbg[t] / sqrt(var + (double)EPS_));
        sc_s[t] = sc;
        sh_s[t] = cbb[t] - (float)mu * sc;
    }
    __syncthreads();
    int r = blockIdx.x * 4 + (t >> 6);
    int lane = t & 63;
    int k = kptr[0];
    bool active = (lane < NF);
    float w = 0.f;
    if (active) {
        float v = zc[(size_t)r * NF + lane];
        w = fmaxf(fmaf(v, sc_s[lane], sh_s[lane]), 0.f);
    }
    float cur = active ? w : -1.f;
    bool sel = false;
    float sum = 0.f;
    for (int it = 0; it < k; ++it) {
        // key: (value bits)<<32 | (63-lane); value>=0 so bit order == value order.
        unsigned hi = 0u, lo = 0u;
        if (cur >= 0.f) { hi = __float_as_uint(cur); lo = (unsigned)(63 - lane); }
#pragma unroll
        for (int off = 32; off > 0; off >>= 1) {
            unsigned ohi = __shfl_xor(hi, off, 64);
            unsigned olo = __shfl_xor(lo, off, 64);
            if (ohi > hi || (ohi == hi && olo > lo)) { hi = ohi; lo = olo; }
        }
        int wlane = 63 - (int)(lo & 63u);
        float wval = __uint_as_float(hi);
        sum += wval;
        if (lane == wlane) { sel = true; cur = -1.f; }
    }
    if (active) {
        float ms = sel ? ((sum > 0.f) ? (w / sum) : 0.f) : 0.f;
        const float* src = flat + (size_t)r * ND + lane * 16;
        unsigned short* dst = flatg + (size_t)r * 640 + lane * 16;
#pragma unroll
        for (int h = 0; h < 2; ++h) {
            union { s16x8 v; unsigned short u[8]; } p;
#pragma unroll
            for (int j = 0; j < 8; ++j) p.u[j] = f2bf(src[h * 8 + j] * ms);
            *(s16x8*)(dst + h * 8) = p.v;
        }
    } else if (lane == NF) {
        s16x8 zv = {};
        *(s16x8*)(flatg + (size_t)r * 640 + 624) = zv;
        *(s16x8*)(flatg + (size_t)r * 640 + 632) = zv;
    }
}

// ---------------- bf16 MFMA GEMM (layer 1): C = A @ Bt^T + bias, fused col stats ----------------
__launch_bounds__(256)
__global__ void k_mfma_gemm(const unsigned short* __restrict__ A,  // M x K bf16
                            const unsigned short* __restrict__ Bt, // N x K bf16
                            const float* __restrict__ bias,
                            unsigned short* __restrict__ C,        // M x N bf16
                            double* __restrict__ stats,            // 2*N fp64
                            int M, int K, int N) {
    __shared__ char lds[32768];
    char* As = lds;
    char* Bs = lds + 16384;
    const int t = threadIdx.x;
    const int l = t & 63;
    const int w = t >> 6;
    const int m0 = blockIdx.y * 128, n0 = blockIdx.x * 128;
    const int Wr = (w >> 1) * 64, Wc = (w & 1) * 64;

    const int srow = t >> 3;            // 0..31
    const int sswz = (t & 7) ^ (srow & 7);
    const unsigned short* ga[4];
    const unsigned short* gb[4];
#pragma unroll
    for (int i = 0; i < 4; ++i) {
        ga[i] = A + (size_t)(m0 + i * 32 + srow) * K + sswz * 8;
        gb[i] = Bt + (size_t)(n0 + i * 32 + srow) * K + sswz * 8;
    }
    int a_off[4][2], b_off[4][2];
#pragma unroll
    for (int m = 0; m < 4; ++m) {
#pragma unroll
        for (int h = 0; h < 2; ++h) {
            int r = Wr + m * 16 + (l & 15);
            a_off[m][h] = r * 128 + (((h * 4 + (l >> 4)) ^ (r & 7)) << 4);
            int c = Wc + m * 16 + (l & 15);
            b_off[m][h] = c * 128 + (((h * 4 + (l >> 4)) ^ (c & 7)) << 4);
        }
    }
    f32x4 acc[4][4] = {};
    for (int k0 = 0; k0 < K; k0 += 64) {
#pragma unroll
        for (int i = 0; i < 4; ++i) {
            __builtin_amdgcn_global_load_lds(
                (const __attribute__((address_space(1))) void*)ga[i],
                (__attribute__((address_space(3))) void*)(As + i * 4096 + t * 16), 16, 0, 0);
            __builtin_amdgcn_global_load_lds(
                (const __attribute__((address_space(1))) void*)gb[i],
                (__attribute__((address_space(3))) void*)(Bs + i * 4096 + t * 16), 16, 0, 0);
            ga[i] += 64; gb[i] += 64;
        }
        __syncthreads();
#pragma unroll
        for (int h = 0; h < 2; ++h) {
            bfx8 af[4], bv[4];
#pragma unroll
            for (int m = 0; m < 4; ++m)
                af[m] = __builtin_bit_cast(bfx8, *(const s16x8*)(As + a_off[m][h]));
#pragma unroll
            for (int n = 0; n < 4; ++n)
                bv[n] = __builtin_bit_cast(bfx8, *(const s16x8*)(Bs + b_off[n][h]));
#pragma unroll
            for (int m = 0; m < 4; ++m)
#pragma unroll
                for (int n = 0; n < 4; ++n)
                    acc[m][n] = __builtin_amdgcn_mfma_f32_16x16x32_bf16(af[m], bv[n], acc[m][n], 0, 0, 0);
        }
        __syncthreads();
    }
#pragma unroll
    for (int n = 0; n < 4; ++n) {
        int nc = n0 + Wc + n * 16 + (l & 15);
        float bs = bias[nc];
        double s = 0.0, q = 0.0;
#pragma unroll
        for (int m = 0; m < 4; ++m) {
            int rbase = m0 + Wr + m * 16 + ((l >> 4) << 2);
#pragma unroll
            for (int i = 0; i < 4; ++i) {
                float v = acc[m][n][i] + bs;
                C[(size_t)(rbase + i) * N + nc] = f2bf(v);
                s += (double)v;
                q += (double)v * (double)v;
            }
        }
        s += __shfl_xor(s, 16, 64); s += __shfl_xor(s, 32, 64);
        q += __shfl_xor(q, 16, 64); q += __shfl_xor(q, 32, 64);
        if ((l >> 4) == 0) {
            atomicAdd(&stats[nc], s);
            atomicAdd(&stats[N + nc], q);
        }
    }
}

// ---------------- bf16 MFMA GEMM with fused input-BN+ReLU on A (layers 2,3) ----------------
// A is RAW GEMM output (bf16, pre-BN). scale/shift computed per block from fp64 statsIn
// with the exact bn_relu formula; A staged via registers (BN applied) into swizzled LDS.
__launch_bounds__(256)
__global__ void k_mfma_gemm_bn(const unsigned short* __restrict__ A,   // M x K bf16 raw
                               const double* __restrict__ statsIn,     // 2*K (A's BN stats)
                               const float* __restrict__ g, const float* __restrict__ be,
                               const unsigned short* __restrict__ Bt,  // N x K bf16
                               const float* __restrict__ bias,
                               unsigned short* __restrict__ C,         // M x N bf16
                               double* __restrict__ stats,             // 2*N fp64
                               int M, int K, int N) {
    __shared__ char lds[40960];
    char* As = lds;
    char* Bs = lds + 16384;
    float* scs = (float*)(lds + 32768);   // K floats
    float* shs = scs + K;                 // K floats (K<=1024 -> fits 8KB)
    const int t = threadIdx.x;
    const int l = t & 63;
    const int w = t >> 6;
    const int m0 = blockIdx.y * 128, n0 = blockIdx.x * 128;
    const int Wr = (w >> 1) * 64, Wc = (w & 1) * 64;

    // per-block BN finalize (identical formula to prior k_bn_relu_b)
    constexpr double inv_bb = 1.0 / (double)BB;
    for (int c = t; c < K; c += 256) {
        double mu = statsIn[c] * inv_bb;
        double var = statsIn[K + c] * inv_bb - mu * mu;
        float sc = g[c] / sqrtf((float)var + EPS_);
        scs[c] = sc;
        shs[c] = be[c] - (float)mu * sc;
    }
    __syncthreads();

    const int srow = t >> 3;            // 0..31
    const int sswz = (t & 7) ^ (srow & 7);
    const unsigned short* ga[4];
    const unsigned short* gb[4];
#pragma unroll
    for (int i = 0; i < 4; ++i) {
        ga[i] = A + (size_t)(m0 + i * 32 + srow) * K + sswz * 8;
        gb[i] = Bt + (size_t)(n0 + i * 32 + srow) * K + sswz * 8;
    }
    int a_off[4][2], b_off[4][2];
#pragma unroll
    for (int m = 0; m < 4; ++m) {
#pragma unroll
        for (int h = 0; h < 2; ++h) {
            int r = Wr + m * 16 + (l & 15);
            a_off[m][h] = r * 128 + (((h * 4 + (l >> 4)) ^ (r & 7)) << 4);
            int c = Wc + m * 16 + (l & 15);
            b_off[m][h] = c * 128 + (((h * 4 + (l >> 4)) ^ (c & 7)) << 4);
        }
    }
    f32x4 acc[4][4] = {};
    for (int k0 = 0; k0 < K; k0 += 64) {
        // B: async global->LDS (unchanged)
#pragma unroll
        for (int i = 0; i < 4; ++i) {
            __builtin_amdgcn_global_load_lds(
                (const __attribute__((address_space(1))) void*)gb[i],
                (__attribute__((address_space(3))) void*)(Bs + i * 4096 + t * 16), 16, 0, 0);
            gb[i] += 64;
        }
        // A: reg-staged with BN+ReLU, write to same swizzled LDS slots
        {
            int kb = k0 + sswz * 8;
            float4 sc0 = *(const float4*)&scs[kb];
            float4 sc1 = *(const float4*)&scs[kb + 4];
            float4 sh0 = *(const float4*)&shs[kb];
            float4 sh1 = *(const float4*)&shs[kb + 4];
            float scl[8] = {sc0.x, sc0.y, sc0.z, sc0.w, sc1.x, sc1.y, sc1.z, sc1.w};
            float shl[8] = {sh0.x, sh0.y, sh0.z, sh0.w, sh1.x, sh1.y, sh1.z, sh1.w};
#pragma unroll
            for (int i = 0; i < 4; ++i) {
                union { s16x8 v; unsigned short u[8]; } pin, pout;
                pin.v = *(const s16x8*)ga[i];
#pragma unroll
                for (int j = 0; j < 8; ++j)
                    pout.u[j] = f2bf(fmaxf(fmaf(bf2f(pin.u[j]), scl[j], shl[j]), 0.f));
                *(s16x8*)(As + i * 4096 + t * 16) = pout.v;
                ga[i] += 64;
            }
        }
        __syncthreads();
#pragma unroll
        for (int h = 0; h < 2; ++h) {
            bfx8 af[4], bv[4];
#pragma unroll
            for (int m = 0; m < 4; ++m)
                af[m] = __builtin_bit_cast(bfx8, *(const s16x8*)(As + a_off[m][h]));
#pragma unroll
            for (int n = 0; n < 4; ++n)
                bv[n] = __builtin_bit_cast(bfx8, *(const s16x8*)(Bs + b_off[n][h]));
#pragma unroll
            for (int m = 0; m < 4; ++m)
#pragma unroll
                for (int n = 0; n < 4; ++n)
                    acc[m][n] = __builtin_amdgcn_mfma_f32_16x16x32_bf16(af[m], bv[n], acc[m][n], 0, 0, 0);
        }
        __syncthreads();
    }
#pragma unroll
    for (int n = 0; n < 4; ++n) {
        int nc = n0 + Wc + n * 16 + (l & 15);
        float bs = bias[nc];
        double s = 0.0, q = 0.0;
#pragma unroll
        for (int m = 0; m < 4; ++m) {
            int rbase = m0 + Wr + m * 16 + ((l >> 4) << 2);
#pragma unroll
            for (int i = 0; i < 4; ++i) {
                float v = acc[m][n][i] + bs;
                C[(size_t)(rbase + i) * N + nc] = f2bf(v);
                s += (double)v;
                q += (double)v * (double)v;
            }
        }
        s += __shfl_xor(s, 16, 64); s += __shfl_xor(s, 32, 64);
        q += __shfl_xor(q, 16, 64); q += __shfl_xor(q, 32, 64);
        if ((l >> 4) == 0) {
            atomicAdd(&stats[nc], s);
            atomicAdd(&stats[N + nc], q);
        }
    }
}

// ---------------- final: bn3+ReLU on raw h3, dot w_out, + wide linear, sigmoid ----------------
__global__ void k_out(const unsigned short* __restrict__ h3, const double* __restrict__ stats3,
                      const float* __restrict__ g3, const float* __restrict__ be3,
                      const float* __restrict__ wo, const float* __restrict__ bo,
                      const int* __restrict__ x, const float* __restrict__ lt,
                      const float* __restrict__ lb, float* __restrict__ out) {
    __shared__ float scs[256], shs[256];
    int t = threadIdx.x;
    {
        constexpr double inv_bb = 1.0 / (double)BB;
        double mu = stats3[t] * inv_bb;
        double var = stats3[256 + t] * inv_bb - mu * mu;
        float sc = g3[t] / sqrtf((float)var + EPS_);
        scs[t] = sc;
        shs[t] = be3[t] - (float)mu * sc;
    }
    __syncthreads();
    int r = blockIdx.x * 4 + (t >> 6);
    int lane = t & 63;
    float s = 0.f;
#pragma unroll
    for (int k = lane; k < 256; k += 64) {
        float xv = bf2f(h3[(size_t)r * 256 + k]);
        // replicate prior bf16 store+load round-trip for bit-identical result
        float hb = bf2f(f2bf(fmaxf(fmaf(xv, scs[k], shs[k]), 0.f)));
        s += hb * wo[k];
    }
    if (lane < NF) {
        long long id = (long long)x[r * NF + lane] + (long long)lane * FIELD_DIM;
        s += lt[id];
    }
#pragma unroll
    for (int off = 32; off > 0; off >>= 1) s += __shfl_xor(s, off, 64);
    if (lane == 0) {
        float tt = s + bo[0] + lb[0];
        out[r] = 1.f / (1.f + expf(-tt));
    }
}

extern "C" void kernel_launch(void* const* d_in, const int* in_sizes, int n_in,
                              void* d_out, int out_size, void* d_ws, size_t ws_size,
                              hipStream_t stream) {
    const int* x = (const int*)d_in[0];
    const float* emb = (const float*)d_in[1];
    const float* lint = (const float*)d_in[2];
    const float* linb = (const float*)d_in[3];
    const float* bng = (const float*)d_in[4];
    const float* bnb = (const float*)d_in[5];
    const float* cw = (const float*)d_in[6];
    const float* cb = (const float*)d_in[7];
    const float* cbg = (const float*)d_in[8];
    const float* cbb = (const float*)d_in[9];
    const float* w1 = (const float*)d_in[10];
    const float* b1 = (const float*)d_in[11];
    const float* g1 = (const float*)d_in[12];
    const float* be1 = (const float*)d_in[13];
    const float* w2 = (const float*)d_in[14];
    const float* b2 = (const float*)d_in[15];
    const float* g2 = (const float*)d_in[16];
    const float* be2 = (const float*)d_in[17];
    const float* w3 = (const float*)d_in[18];
    const float* b3 = (const float*)d_in[19];
    const float* g3 = (const float*)d_in[20];
    const float* be3 = (const float*)d_in[21];
    const float* wo = (const float*)d_in[22];
    const float* bo = (const float*)d_in[23];
    const int* kptr = (const int*)d_in[24];
    float* out = (float*)d_out;

    char* p = (char*)d_ws;
    float* flat = (float*)p;                 p += (size_t)BB * ND * 4;      // fp32, ctrl path
    unsigned short* flatg = (unsigned short*)p; p += (size_t)BB * 640 * 2;  // gated bf16, K-padded
    unsigned short* h1 = (unsigned short*)p; p += (size_t)BB * 1024 * 2;    // raw (pre-BN)
    unsigned short* h2 = (unsigned short*)p; p += (size_t)BB * 512 * 2;     // raw
    unsigned short* h3 = (unsigned short*)p; p += (size_t)BB * 256 * 2;     // raw
    unsigned short* w1t = (unsigned short*)p; p += (size_t)1024 * 640 * 2;
    unsigned short* w2t = (unsigned short*)p; p += (size_t)512 * 1024 * 2;
    unsigned short* w3t = (unsigned short*)p; p += (size_t)256 * 512 * 2;
    float* wct = (float*)p;                  p += (size_t)48 * ND * 4;      // ctrl w transposed fp32
    float* zc = (float*)p;                   p += (size_t)BB * NF * 4;
    // disjoint per-layer fp64 stat regions, zeroed inside k_prep
    double* stats_all = (double*)p;
    double* stats_f = stats_all;             // 2*39
    double* stats_c = stats_f + 2 * NF;      // 2*39
    double* stats_1 = stats_c + 2 * NF;      // 2*1024
    double* stats_2 = stats_1 + 2 * 1024;    // 2*512
    double* stats_3 = stats_2 + 2 * 512;     // 2*256
    int stats_doubles = 2 * (NF + NF + 1024 + 512 + 256); // 3662

    // ---- prep: weight transposes + stats zero (one kernel) ----
    int zero_blocks = (stats_doubles + 255) / 256;        // 15
    k_prep<<<5237 + zero_blocks, 256, 0, stream>>>(w1, w2, w3, cw, w1t, w2t, w3t, wct,
                                                   stats_all, stats_doubles);

    // ---- field BN (finalize fused into flat_norm) ----
    k_field_stats<<<dim3(NF, BB / 256), 256, 0, stream>>>(x, emb, stats_f);
    k_flat_norm<<<(BB * NF + 255) / 256, 256, 0, stream>>>(x, emb, stats_f, bng, bnb, flat);

    // ---- controller (round-5 structure) + fused finalize/topk/gate ----
    k_ctrl_gemm<<<BB / 64, 256, 0, stream>>>(flat, wct, cb, zc, stats_c);
    k_topk_gate<<<BB / 4, 256, 0, stream>>>(zc, stats_c, cbg, cbb, kptr, flat, flatg);

    // ---- MLP layer 1: 640(pad) -> 1024 (h1 raw) ----
    k_mfma_gemm<<<dim3(1024 / 128, BB / 128), 256, 0, stream>>>(flatg, w1t, b1, h1, stats_1, BB, 640, 1024);

    // ---- MLP layer 2: BN1+ReLU fused into A-staging; 1024 -> 512 (h2 raw) ----
    k_mfma_gemm_bn<<<dim3(512 / 128, BB / 128), 256, 0, stream>>>(h1, stats_1, g1, be1,
                                                                  w2t, b2, h2, stats_2, BB, 1024, 512);

    // ---- MLP layer 3: BN2+ReLU fused; 512 -> 256 (h3 raw) ----
    k_mfma_gemm_bn<<<dim3(256 / 128, BB / 128), 256, 0, stream>>>(h2, stats_2, g2, be2,
                                                                  w3t, b3, h3, stats_3, BB, 512, 256);

    // ---- output: BN3+ReLU + dot w_out + wide linear + sigmoid ----
    k_out<<<BB / 4, 256, 0, stream>>>(h3, stats_3, g3, be3, wo, bo, x, lint, linb, out);
}

// Round 10
// 273.116 us; speedup vs baseline: 1.2570x; 1.0215x over previous
//
#include <hip/hip_runtime.h>
#include <math.h>
#include <stdint.h>

constexpr int BB = 16384;   // batch
constexpr int NF = 39;      // fields
constexpr int NE = 16;      // embed dim
constexpr int ND = NF * NE; // 624
constexpr int FIELD_DIM = 26000;
constexpr float EPS_ = 1e-5f;

typedef __bf16 bfx8 __attribute__((ext_vector_type(8)));
typedef float f32x4 __attribute__((ext_vector_type(4)));
typedef short s16x8 __attribute__((ext_vector_type(8)));

static __device__ __forceinline__ unsigned short f2bf(float f) {
    union { float f; unsigned u; } a; a.f = f;
    unsigned r = a.u + 0x7fffu + ((a.u >> 16) & 1u); // RNE
    return (unsigned short)(r >> 16);
}
static __device__ __forceinline__ float bf2f(unsigned short u) {
    union { unsigned u; float f; } a; a.u = ((unsigned)u) << 16;
    return a.f;
}

// ---------------- fused prep: LDS-tiled weight transposes + ctrl transpose + stats zero --------
// grid: [0,640) w1t tiles | [640,1152) w2t | [1152,1280) w3t | [1280,1397) wct | [1397,1412) stats
__global__ void k_prep(const float* __restrict__ w1, const float* __restrict__ w2,
                       const float* __restrict__ w3, const float* __restrict__ cw,
                       unsigned short* __restrict__ w1t, unsigned short* __restrict__ w2t,
                       unsigned short* __restrict__ w3t, float* __restrict__ wct,
                       double* __restrict__ stats, int nstats) {
    int b = blockIdx.x;
    if (b < 1280) {
        const float* in; unsigned short* outp; int K, N, Kpad, tid;
        if (b < 640)        { in = w1; outp = w1t; K = 624;  N = 1024; Kpad = 640;  tid = b; }
        else if (b < 1152)  { in = w2; outp = w2t; K = 1024; N = 512;  Kpad = 1024; tid = b - 640; }
        else                { in = w3; outp = w3t; K = 512;  N = 256;  Kpad = 512;  tid = b - 1152; }
        int tiles_n = N >> 5;
        int tk = tid / tiles_n, tn = tid % tiles_n;
        __shared__ float tile[32][33];
        int tx = threadIdx.x & 31, ty = threadIdx.x >> 5;  // 32 x 8
#pragma unroll
        for (int i = 0; i < 4; ++i) {
            int k = tk * 32 + ty + i * 8, n = tn * 32 + tx;
            tile[ty + i * 8][tx] = (k < K) ? in[(size_t)k * N + n] : 0.f;
        }
        __syncthreads();
#pragma unroll
        for (int i = 0; i < 4; ++i) {
            int n = tn * 32 + ty + i * 8, k = tk * 32 + tx;
            outp[(size_t)n * Kpad + k] = f2bf(tile[tx][ty + i * 8]);
        }
    } else if (b < 1397) {                // wct: (48, 624) fp32, rows>=39 zero
        int gid = (b - 1280) * 256 + threadIdx.x;
        if (gid < 48 * ND) {
            int j = gid / ND, k = gid % ND;
            wct[gid] = (j < NF) ? cw[(size_t)k * NF + j] : 0.f;
        }
    } else {                              // zero fp64 stats
        int gid = (b - 1397) * 256 + threadIdx.x;
        if (gid < nstats) stats[gid] = 0.0;
    }
}

// ---------------- field BN stats: sum/sumsq per field over (B, E), fp64 atomics ----------------
__global__ void k_field_stats(const int* __restrict__ x, const float* __restrict__ emb,
                              double* __restrict__ stats /* 2*NF */) {
    int f = blockIdx.x;
    int r = blockIdx.y * blockDim.x + threadIdx.x;
    double s = 0.0, q = 0.0;
    if (r < BB) {
        long long id = (long long)x[r * NF + f] + (long long)f * FIELD_DIM;
        const float4* p = (const float4*)(emb + id * NE);
#pragma unroll
        for (int i = 0; i < 4; ++i) {
            float4 v = p[i];
            s += (double)v.x; s += (double)v.y; s += (double)v.z; s += (double)v.w;
            q += (double)v.x * v.x; q += (double)v.y * v.y;
            q += (double)v.z * v.z; q += (double)v.w * v.w;
        }
    }
    __shared__ double ls[256], lq[256];
    ls[threadIdx.x] = s; lq[threadIdx.x] = q;
    __syncthreads();
    for (int off = 128; off > 0; off >>= 1) {
        if ((int)threadIdx.x < off) {
            ls[threadIdx.x] += ls[threadIdx.x + off];
            lq[threadIdx.x] += lq[threadIdx.x + off];
        }
        __syncthreads();
    }
    if (threadIdx.x == 0) {
        atomicAdd(&stats[f], ls[0]);
        atomicAdd(&stats[NF + f], lq[0]);
    }
}

// ---------------- gather + normalize -> flat (B, 624) fp32; field-BN finalize fused ----------------
__global__ void k_flat_norm(const int* __restrict__ x, const float* __restrict__ emb,
                            const double* __restrict__ stats, const float* __restrict__ bng,
                            const float* __restrict__ bnb, float* __restrict__ flat) {
    __shared__ float sc_s[NF], sh_s[NF];
    if ((int)threadIdx.x < NF) {
        int f = threadIdx.x;
        double cnt = (double)BB * NE;
        double mu = stats[f] / cnt;
        double var = stats[NF + f] / cnt - mu * mu;
        float sc = (float)((double)bng[f] / sqrt(var + (double)EPS_));
        sc_s[f] = sc;
        sh_s[f] = bnb[f] - (float)mu * sc;
    }
    __syncthreads();
    int gid = blockIdx.x * blockDim.x + threadIdx.x; // r*NF + f
    if (gid >= BB * NF) return;
    int f = gid % NF;
    long long id = (long long)x[gid] + (long long)f * FIELD_DIM;
    float sc = sc_s[f], sh = sh_s[f];
    const float4* p = (const float4*)(emb + id * NE);
    float4* o = (float4*)(flat) + (size_t)gid * 4;
#pragma unroll
    for (int i = 0; i < 4; ++i) {
        float4 v = p[i];
        o[i] = make_float4(fmaf(v.x, sc, sh), fmaf(v.y, sc, sh),
                           fmaf(v.z, sc, sh), fmaf(v.w, sc, sh));
    }
}

// ---------------- controller GEMM split-K: round-5 body, K halves [0,320) / [320,624) ----------
// 512 blocks x 256 threads. Tile 64 rows x 48 cols. Partials -> zp[half][B][NF] fp64.
__launch_bounds__(256)
__global__ void k_ctrl_gemm_sk(const float* __restrict__ flat, const float* __restrict__ wct,
                               double* __restrict__ zp) {
    __shared__ float As[64][68];       // [row][kk], padded
    __shared__ float Ws[64][49];       // [kk][col]
    const int t = threadIdx.x;
    const int tn = t & 15;             // col group: cols 3tn..3tn+2
    const int tm = t >> 4;             // row group: rows 4tm..4tm+3
    const int bm = blockIdx.x & 255;
    const int half = blockIdx.x >> 8;
    const int m0 = bm * 64;
    const int kbeg = half ? 320 : 0;
    const int kend = half ? 624 : 320;
    double acc[4][3] = {};
    for (int k0 = kbeg; k0 < kend; k0 += 64) {
        const int kl = (kend - k0 >= 64) ? 64 : (kend - k0);   // 64 or 48
        const int kl4 = kl >> 2;
        // stage A: 64 rows x kl floats (float4, coalesced)
#pragma unroll
        for (int i = 0; i < 4; ++i) {
            int idx = t + 256 * i;     // 0..1023
            int row = idx >> 4, c4 = idx & 15;
            if (c4 < kl4) {
                float4 v = *(const float4*)(flat + (size_t)(m0 + row) * ND + k0 + c4 * 4);
                *(float4*)&As[row][c4 * 4] = v;
            }
        }
        // stage W: 48 cols x kl floats, transposed into [kk][col]
        {
            int col = t >> 4;          // 0..15
            int c4 = t & 15;
#pragma unroll
            for (int cp = 0; cp < 3; ++cp, col += 16) {
                if (c4 < kl4) {
                    float4 v = *(const float4*)(wct + (size_t)col * ND + k0 + c4 * 4);
                    Ws[c4 * 4 + 0][col] = v.x; Ws[c4 * 4 + 1][col] = v.y;
                    Ws[c4 * 4 + 2][col] = v.z; Ws[c4 * 4 + 3][col] = v.w;
                }
            }
        }
        __syncthreads();
#pragma unroll 4
        for (int kk = 0; kk < kl; ++kk) {
            double a0 = (double)As[4 * tm + 0][kk];
            double a1 = (double)As[4 * tm + 1][kk];
            double a2 = (double)As[4 * tm + 2][kk];
            double a3 = (double)As[4 * tm + 3][kk];
            double w0 = (double)Ws[kk][3 * tn + 0];
            double w1 = (double)Ws[kk][3 * tn + 1];
            double w2 = (double)Ws[kk][3 * tn + 2];
            acc[0][0] += a0 * w0; acc[0][1] += a0 * w1; acc[0][2] += a0 * w2;
            acc[1][0] += a1 * w0; acc[1][1] += a1 * w1; acc[1][2] += a1 * w2;
            acc[2][0] += a2 * w0; acc[2][1] += a2 * w1; acc[2][2] += a2 * w2;
            acc[3][0] += a3 * w0; acc[3][1] += a3 * w1; acc[3][2] += a3 * w2;
        }
        __syncthreads();
    }
    double* zph = zp + (size_t)half * BB * NF;
#pragma unroll
    for (int j = 0; j < 3; ++j) {
        int col = 3 * tn + j;
        if (col < NF) {
#pragma unroll
            for (int i = 0; i < 4; ++i)
                zph[(size_t)(m0 + 4 * tm + i) * NF + col] = acc[i][j];
        }
    }
}

// ---------------- split-K reduce: z = (float)(p0+p1+bias), fused col stats ----------------
__global__ void k_ctrl_reduce(const double* __restrict__ zp, const float* __restrict__ bias,
                              float* __restrict__ z, double* __restrict__ stats) {
    __shared__ double Sred[2][16][48];
    const int t = threadIdx.x;
    const int tn = t & 15;
    const int tm = t >> 4;
    const int m0 = blockIdx.x * 64;
#pragma unroll
    for (int j = 0; j < 3; ++j) {
        int col = 3 * tn + j;
        double s = 0.0, q = 0.0;
        if (col < NF) {
            float bs = bias[col];
#pragma unroll
            for (int i = 0; i < 4; ++i) {
                size_t idx = (size_t)(m0 + 4 * tm + i) * NF + col;
                double p01 = zp[idx] + zp[(size_t)BB * NF + idx];
                float v = (float)(p01 + (double)bs);
                z[idx] = v;
                s += (double)v;
                q += (double)v * (double)v;
            }
        }
        Sred[0][tm][col] = s;
        Sred[1][tm][col] = q;
    }
    __syncthreads();
    if (t < NF) {
        double ts = 0.0, tq = 0.0;
#pragma unroll
        for (int i = 0; i < 16; ++i) { ts += Sred[0][i][t]; tq += Sred[1][i][t]; }
        atomicAdd(&stats[t], ts);
        atomicAdd(&stats[NF + t], tq);
    }
}

// ---------------- ctrl-BN finalize + BN+ReLU + top-k + gate -> flatg (fused) ----------------
__global__ void k_topk_gate(const float* __restrict__ zc, const double* __restrict__ stats,
                            const float* __restrict__ cbg, const float* __restrict__ cbb,
                            const int* __restrict__ kptr, const float* __restrict__ flat,
                            unsigned short* __restrict__ flatg) {
    __shared__ float sc_s[NF], sh_s[NF];
    int t = threadIdx.x;
    if (t < NF) {
        double mu = stats[t] / (double)BB;
        double var = stats[NF + t] / (double)BB - mu * mu;
        float sc = (float)((double)cbg[t] / sqrt(var + (double)EPS_));
        sc_s[t] = sc;
        sh_s[t] = cbb[t] - (float)mu * sc;
    }
    __syncthreads();
    int r = blockIdx.x * 4 + (t >> 6);
    int lane = t & 63;
    int k = kptr[0];
    bool active = (lane < NF);
    float w = 0.f;
    if (active) {
        float v = zc[(size_t)r * NF + lane];
        w = fmaxf(fmaf(v, sc_s[lane], sh_s[lane]), 0.f);
    }
    float cur = active ? w : -1.f;
    bool sel = false;
    float sum = 0.f;
    for (int it = 0; it < k; ++it) {
        // key: (value bits)<<32 | (63-lane); value>=0 so bit order == value order.
        unsigned hi = 0u, lo = 0u;
        if (cur >= 0.f) { hi = __float_as_uint(cur); lo = (unsigned)(63 - lane); }
#pragma unroll
        for (int off = 32; off > 0; off >>= 1) {
            unsigned ohi = __shfl_xor(hi, off, 64);
            unsigned olo = __shfl_xor(lo, off, 64);
            if (ohi > hi || (ohi == hi && olo > lo)) { hi = ohi; lo = olo; }
        }
        int wlane = 63 - (int)(lo & 63u);
        float wval = __uint_as_float(hi);
        sum += wval;
        if (lane == wlane) { sel = true; cur = -1.f; }
    }
    if (active) {
        float ms = sel ? ((sum > 0.f) ? (w / sum) : 0.f) : 0.f;
        const float* src = flat + (size_t)r * ND + lane * 16;
        unsigned short* dst = flatg + (size_t)r * 640 + lane * 16;
#pragma unroll
        for (int h = 0; h < 2; ++h) {
            union { s16x8 v; unsigned short u[8]; } p;
#pragma unroll
            for (int j = 0; j < 8; ++j) p.u[j] = f2bf(src[h * 8 + j] * ms);
            *(s16x8*)(dst + h * 8) = p.v;
        }
    } else if (lane == NF) {
        s16x8 zv = {};
        *(s16x8*)(flatg + (size_t)r * 640 + 624) = zv;
        *(s16x8*)(flatg + (size_t)r * 640 + 632) = zv;
    }
}

// ---------------- bf16 MFMA GEMM (layer 1): C = A @ Bt^T + bias, fused col stats ----------------
__launch_bounds__(256)
__global__ void k_mfma_gemm(const unsigned short* __restrict__ A,  // M x K bf16
                            const unsigned short* __restrict__ Bt, // N x K bf16
                            const float* __restrict__ bias,
                            unsigned short* __restrict__ C,        // M x N bf16
                            double* __restrict__ stats,            // 2*N fp64
                            int M, int K, int N) {
    __shared__ char lds[32768];
    char* As = lds;
    char* Bs = lds + 16384;
    const int t = threadIdx.x;
    const int l = t & 63;
    const int w = t >> 6;
    const int m0 = blockIdx.y * 128, n0 = blockIdx.x * 128;
    const int Wr = (w >> 1) * 64, Wc = (w & 1) * 64;

    const int srow = t >> 3;            // 0..31
    const int sswz = (t & 7) ^ (srow & 7);
    const unsigned short* ga[4];
    const unsigned short* gb[4];
#pragma unroll
    for (int i = 0; i < 4; ++i) {
        ga[i] = A + (size_t)(m0 + i * 32 + srow) * K + sswz * 8;
        gb[i] = Bt + (size_t)(n0 + i * 32 + srow) * K + sswz * 8;
    }
    int a_off[4][2], b_off[4][2];
#pragma unroll
    for (int m = 0; m < 4; ++m) {
#pragma unroll
        for (int h = 0; h < 2; ++h) {
            int r = Wr + m * 16 + (l & 15);
            a_off[m][h] = r * 128 + (((h * 4 + (l >> 4)) ^ (r & 7)) << 4);
            int c = Wc + m * 16 + (l & 15);
            b_off[m][h] = c * 128 + (((h * 4 + (l >> 4)) ^ (c & 7)) << 4);
        }
    }
    f32x4 acc[4][4] = {};
    for (int k0 = 0; k0 < K; k0 += 64) {
#pragma unroll
        for (int i = 0; i < 4; ++i) {
            __builtin_amdgcn_global_load_lds(
                (const __attribute__((address_space(1))) void*)ga[i],
                (__attribute__((address_space(3))) void*)(As + i * 4096 + t * 16), 16, 0, 0);
            __builtin_amdgcn_global_load_lds(
                (const __attribute__((address_space(1))) void*)gb[i],
                (__attribute__((address_space(3))) void*)(Bs + i * 4096 + t * 16), 16, 0, 0);
            ga[i] += 64; gb[i] += 64;
        }
        __syncthreads();
#pragma unroll
        for (int h = 0; h < 2; ++h) {
            bfx8 af[4], bv[4];
#pragma unroll
            for (int m = 0; m < 4; ++m)
                af[m] = __builtin_bit_cast(bfx8, *(const s16x8*)(As + a_off[m][h]));
#pragma unroll
            for (int n = 0; n < 4; ++n)
                bv[n] = __builtin_bit_cast(bfx8, *(const s16x8*)(Bs + b_off[n][h]));
#pragma unroll
            for (int m = 0; m < 4; ++m)
#pragma unroll
                for (int n = 0; n < 4; ++n)
                    acc[m][n] = __builtin_amdgcn_mfma_f32_16x16x32_bf16(af[m], bv[n], acc[m][n], 0, 0, 0);
        }
        __syncthreads();
    }
#pragma unroll
    for (int n = 0; n < 4; ++n) {
        int nc = n0 + Wc + n * 16 + (l & 15);
        float bs = bias[nc];
        double s = 0.0, q = 0.0;
#pragma unroll
        for (int m = 0; m < 4; ++m) {
            int rbase = m0 + Wr + m * 16 + ((l >> 4) << 2);
#pragma unroll
            for (int i = 0; i < 4; ++i) {
                float v = acc[m][n][i] + bs;
                C[(size_t)(rbase + i) * N + nc] = f2bf(v);
                s += (double)v;
                q += (double)v * (double)v;
            }
        }
        s += __shfl_xor(s, 16, 64); s += __shfl_xor(s, 32, 64);
        q += __shfl_xor(q, 16, 64); q += __shfl_xor(q, 32, 64);
        if ((l >> 4) == 0) {
            atomicAdd(&stats[nc], s);
            atomicAdd(&stats[N + nc], q);
        }
    }
}

// ---------------- bf16 MFMA GEMM with fused input-BN+ReLU on A (layers 2,3) ----------------
__launch_bounds__(256)
__global__ void k_mfma_gemm_bn(const unsigned short* __restrict__ A,   // M x K bf16 raw
                               const double* __restrict__ statsIn,     // 2*K (A's BN stats)
                               const float* __restrict__ g, const float* __restrict__ be,
                               const unsigned short* __restrict__ Bt,  // N x K bf16
                               const float* __restrict__ bias,
                               unsigned short* __restrict__ C,         // M x N bf16
                               double* __restrict__ stats,             // 2*N fp64
                               int M, int K, int N) {
    __shared__ char lds[40960];
    char* As = lds;
    char* Bs = lds + 16384;
    float* scs = (float*)(lds + 32768);   // K floats
    float* shs = scs + K;                 // K floats (K<=1024 -> fits 8KB)
    const int t = threadIdx.x;
    const int l = t & 63;
    const int w = t >> 6;
    const int m0 = blockIdx.y * 128, n0 = blockIdx.x * 128;
    const int Wr = (w >> 1) * 64, Wc = (w & 1) * 64;

    constexpr double inv_bb = 1.0 / (double)BB;
    for (int c = t; c < K; c += 256) {
        double mu = statsIn[c] * inv_bb;
        double var = statsIn[K + c] * inv_bb - mu * mu;
        float sc = g[c] / sqrtf((float)var + EPS_);
        scs[c] = sc;
        shs[c] = be[c] - (float)mu * sc;
    }
    __syncthreads();

    const int srow = t >> 3;            // 0..31
    const int sswz = (t & 7) ^ (srow & 7);
    const unsigned short* ga[4];
    const unsigned short* gb[4];
#pragma unroll
    for (int i = 0; i < 4; ++i) {
        ga[i] = A + (size_t)(m0 + i * 32 + srow) * K + sswz * 8;
        gb[i] = Bt + (size_t)(n0 + i * 32 + srow) * K + sswz * 8;
    }
    int a_off[4][2], b_off[4][2];
#pragma unroll
    for (int m = 0; m < 4; ++m) {
#pragma unroll
        for (int h = 0; h < 2; ++h) {
            int r = Wr + m * 16 + (l & 15);
            a_off[m][h] = r * 128 + (((h * 4 + (l >> 4)) ^ (r & 7)) << 4);
            int c = Wc + m * 16 + (l & 15);
            b_off[m][h] = c * 128 + (((h * 4 + (l >> 4)) ^ (c & 7)) << 4);
        }
    }
    f32x4 acc[4][4] = {};
    for (int k0 = 0; k0 < K; k0 += 64) {
#pragma unroll
        for (int i = 0; i < 4; ++i) {
            __builtin_amdgcn_global_load_lds(
                (const __attribute__((address_space(1))) void*)gb[i],
                (__attribute__((address_space(3))) void*)(Bs + i * 4096 + t * 16), 16, 0, 0);
            gb[i] += 64;
        }
        {
            int kb = k0 + sswz * 8;
            float4 sc0 = *(const float4*)&scs[kb];
            float4 sc1 = *(const float4*)&scs[kb + 4];
            float4 sh0 = *(const float4*)&shs[kb];
            float4 sh1 = *(const float4*)&shs[kb + 4];
            float scl[8] = {sc0.x, sc0.y, sc0.z, sc0.w, sc1.x, sc1.y, sc1.z, sc1.w};
            float shl[8] = {sh0.x, sh0.y, sh0.z, sh0.w, sh1.x, sh1.y, sh1.z, sh1.w};
#pragma unroll
            for (int i = 0; i < 4; ++i) {
                union { s16x8 v; unsigned short u[8]; } pin, pout;
                pin.v = *(const s16x8*)ga[i];
#pragma unroll
                for (int j = 0; j < 8; ++j)
                    pout.u[j] = f2bf(fmaxf(fmaf(bf2f(pin.u[j]), scl[j], shl[j]), 0.f));
                *(s16x8*)(As + i * 4096 + t * 16) = pout.v;
                ga[i] += 64;
            }
        }
        __syncthreads();
#pragma unroll
        for (int h = 0; h < 2; ++h) {
            bfx8 af[4], bv[4];
#pragma unroll
            for (int m = 0; m < 4; ++m)
                af[m] = __builtin_bit_cast(bfx8, *(const s16x8*)(As + a_off[m][h]));
#pragma unroll
            for (int n = 0; n < 4; ++n)
                bv[n] = __builtin_bit_cast(bfx8, *(const s16x8*)(Bs + b_off[n][h]));
#pragma unroll
            for (int m = 0; m < 4; ++m)
#pragma unroll
                for (int n = 0; n < 4; ++n)
                    acc[m][n] = __builtin_amdgcn_mfma_f32_16x16x32_bf16(af[m], bv[n], acc[m][n], 0, 0, 0);
        }
        __syncthreads();
    }
#pragma unroll
    for (int n = 0; n < 4; ++n) {
        int nc = n0 + Wc + n * 16 + (l & 15);
        float bs = bias[nc];
        double s = 0.0, q = 0.0;
#pragma unroll
        for (int m = 0; m < 4; ++m) {
            int rbase = m0 + Wr + m * 16 + ((l >> 4) << 2);
#pragma unroll
            for (int i = 0; i < 4; ++i) {
                float v = acc[m][n][i] + bs;
                C[(size_t)(rbase + i) * N + nc] = f2bf(v);
                s += (double)v;
                q += (double)v * (double)v;
            }
        }
        s += __shfl_xor(s, 16, 64); s += __shfl_xor(s, 32, 64);
        q += __shfl_xor(q, 16, 64); q += __shfl_xor(q, 32, 64);
        if ((l >> 4) == 0) {
            atomicAdd(&stats[nc], s);
            atomicAdd(&stats[N + nc], q);
        }
    }
}

// ---------------- final: bn3+ReLU on raw h3, dot w_out, + wide linear, sigmoid ----------------
__global__ void k_out(const unsigned short* __restrict__ h3, const double* __restrict__ stats3,
                      const float* __restrict__ g3, const float* __restrict__ be3,
                      const float* __restrict__ wo, const float* __restrict__ bo,
                      const int* __restrict__ x, const float* __restrict__ lt,
                      const float* __restrict__ lb, float* __restrict__ out) {
    __shared__ float scs[256], shs[256];
    int t = threadIdx.x;
    {
        constexpr double inv_bb = 1.0 / (double)BB;
        double mu = stats3[t] * inv_bb;
        double var = stats3[256 + t] * inv_bb - mu * mu;
        float sc = g3[t] / sqrtf((float)var + EPS_);
        scs[t] = sc;
        shs[t] = be3[t] - (float)mu * sc;
    }
    __syncthreads();
    int r = blockIdx.x * 4 + (t >> 6);
    int lane = t & 63;
    float s = 0.f;
#pragma unroll
    for (int k = lane; k < 256; k += 64) {
        float xv = bf2f(h3[(size_t)r * 256 + k]);
        float hb = bf2f(f2bf(fmaxf(fmaf(xv, scs[k], shs[k]), 0.f)));
        s += hb * wo[k];
    }
    if (lane < NF) {
        long long id = (long long)x[r * NF + lane] + (long long)lane * FIELD_DIM;
        s += lt[id];
    }
#pragma unroll
    for (int off = 32; off > 0; off >>= 1) s += __shfl_xor(s, off, 64);
    if (lane == 0) {
        float tt = s + bo[0] + lb[0];
        out[r] = 1.f / (1.f + expf(-tt));
    }
}

extern "C" void kernel_launch(void* const* d_in, const int* in_sizes, int n_in,
                              void* d_out, int out_size, void* d_ws, size_t ws_size,
                              hipStream_t stream) {
    const int* x = (const int*)d_in[0];
    const float* emb = (const float*)d_in[1];
    const float* lint = (const float*)d_in[2];
    const float* linb = (const float*)d_in[3];
    const float* bng = (const float*)d_in[4];
    const float* bnb = (const float*)d_in[5];
    const float* cw = (const float*)d_in[6];
    const float* cb = (const float*)d_in[7];
    const float* cbg = (const float*)d_in[8];
    const float* cbb = (const float*)d_in[9];
    const float* w1 = (const float*)d_in[10];
    const float* b1 = (const float*)d_in[11];
    const float* g1 = (const float*)d_in[12];
    const float* be1 = (const float*)d_in[13];
    const float* w2 = (const float*)d_in[14];
    const float* b2 = (const float*)d_in[15];
    const float* g2 = (const float*)d_in[16];
    const float* be2 = (const float*)d_in[17];
    const float* w3 = (const float*)d_in[18];
    const float* b3 = (const float*)d_in[19];
    const float* g3 = (const float*)d_in[20];
    const float* be3 = (const float*)d_in[21];
    const float* wo = (const float*)d_in[22];
    const float* bo = (const float*)d_in[23];
    const int* kptr = (const int*)d_in[24];
    float* out = (float*)d_out;

    char* p = (char*)d_ws;
    float* flat = (float*)p;                 p += (size_t)BB * ND * 4;      // fp32, ctrl path
    unsigned short* flatg = (unsigned short*)p; p += (size_t)BB * 640 * 2;  // gated bf16, K-padded
    unsigned short* h1 = (unsigned short*)p; p += (size_t)BB * 1024 * 2;    // raw (pre-BN)
    unsigned short* h2 = (unsigned short*)p; p += (size_t)BB * 512 * 2;     // raw
    unsigned short* h3 = (unsigned short*)p; p += (size_t)BB * 256 * 2;     // raw
    unsigned short* w1t = (unsigned short*)p; p += (size_t)1024 * 640 * 2;
    unsigned short* w2t = (unsigned short*)p; p += (size_t)512 * 1024 * 2;
    unsigned short* w3t = (unsigned short*)p; p += (size_t)256 * 512 * 2;
    float* wct = (float*)p;                  p += (size_t)48 * ND * 4;      // ctrl w transposed fp32
    float* zc = (float*)p;                   p += (size_t)BB * NF * 4;
    double* zp = (double*)p;                 p += (size_t)2 * BB * NF * 8;  // split-K partials fp64
    // disjoint per-layer fp64 stat regions, zeroed inside k_prep
    double* stats_all = (double*)p;
    double* stats_f = stats_all;             // 2*39
    double* stats_c = stats_f + 2 * NF;      // 2*39
    double* stats_1 = stats_c + 2 * NF;      // 2*1024
    double* stats_2 = stats_1 + 2 * 1024;    // 2*512
    double* stats_3 = stats_2 + 2 * 512;     // 2*256
    int stats_doubles = 2 * (NF + NF + 1024 + 512 + 256); // 3662

    // ---- prep: tiled weight transposes + stats zero (one kernel, 1412 blocks) ----
    k_prep<<<1412, 256, 0, stream>>>(w1, w2, w3, cw, w1t, w2t, w3t, wct,
                                     stats_all, stats_doubles);

    // ---- field BN (finalize fused into flat_norm) ----
    k_field_stats<<<dim3(NF, BB / 256), 256, 0, stream>>>(x, emb, stats_f);
    k_flat_norm<<<(BB * NF + 255) / 256, 256, 0, stream>>>(x, emb, stats_f, bng, bnb, flat);

    // ---- controller: split-K GEMM (2 blocks/CU) + reduce/stats + fused finalize/topk/gate ----
    k_ctrl_gemm_sk<<<512, 256, 0, stream>>>(flat, wct, zp);
    k_ctrl_reduce<<<BB / 64, 256, 0, stream>>>(zp, cb, zc, stats_c);
    k_topk_gate<<<BB / 4, 256, 0, stream>>>(zc, stats_c, cbg, cbb, kptr, flat, flatg);

    // ---- MLP layer 1: 640(pad) -> 1024 (h1 raw) ----
    k_mfma_gemm<<<dim3(1024 / 128, BB / 128), 256, 0, stream>>>(flatg, w1t, b1, h1, stats_1, BB, 640, 1024);

    // ---- MLP layer 2: BN1+ReLU fused into A-staging; 1024 -> 512 (h2 raw) ----
    k_mfma_gemm_bn<<<dim3(512 / 128, BB / 128), 256, 0, stream>>>(h1, stats_1, g1, be1,
                                                                  w2t, b2, h2, stats_2, BB, 1024, 512);

    // ---- MLP layer 3: BN2+ReLU fused; 512 -> 256 (h3 raw) ----
    k_mfma_gemm_bn<<<dim3(256 / 128, BB / 128), 256, 0, stream>>>(h2, stats_2, g2, be2,
                                                                  w3t, b3, h3, stats_3, BB, 512, 256);

    // ---- output: BN3+ReLU + dot w_out + wide linear + sigmoid ----
    k_out<<<BB / 4, 256, 0, stream>>>(h3, stats_3, g3, be3, wo, bo, x, lint, linb, out);
}

// Round 11
// 240.943 us; speedup vs baseline: 1.4249x; 1.1335x over previous
//
#include <hip/hip_runtime.h>
#include <math.h>
#include <stdint.h>

constexpr int BB = 16384;   // batch
constexpr int NF = 39;      // fields
constexpr int NE = 16;      // embed dim
constexpr int ND = NF * NE; // 624
constexpr int FIELD_DIM = 26000;
constexpr float EPS_ = 1e-5f;

typedef __bf16 bfx8 __attribute__((ext_vector_type(8)));
typedef float f32x4 __attribute__((ext_vector_type(4)));
typedef short s16x8 __attribute__((ext_vector_type(8)));

static __device__ __forceinline__ unsigned short f2bf(float f) {
    union { float f; unsigned u; } a; a.f = f;
    unsigned r = a.u + 0x7fffu + ((a.u >> 16) & 1u); // RNE
    return (unsigned short)(r >> 16);
}
static __device__ __forceinline__ float bf2f(unsigned short u) {
    union { unsigned u; float f; } a; a.u = ((unsigned)u) << 16;
    return a.f;
}

// ---------------- fused prep: LDS-tiled weight transposes + ctrl transpose + stats zero --------
// grid: [0,640) w1t tiles | [640,1152) w2t | [1152,1280) w3t | [1280,1397) wct | [1397,1412) stats
__global__ void k_prep(const float* __restrict__ w1, const float* __restrict__ w2,
                       const float* __restrict__ w3, const float* __restrict__ cw,
                       unsigned short* __restrict__ w1t, unsigned short* __restrict__ w2t,
                       unsigned short* __restrict__ w3t, float* __restrict__ wct,
                       double* __restrict__ stats, int nstats) {
    int b = blockIdx.x;
    if (b < 1280) {
        const float* in; unsigned short* outp; int K, N, Kpad, tid;
        if (b < 640)        { in = w1; outp = w1t; K = 624;  N = 1024; Kpad = 640;  tid = b; }
        else if (b < 1152)  { in = w2; outp = w2t; K = 1024; N = 512;  Kpad = 1024; tid = b - 640; }
        else                { in = w3; outp = w3t; K = 512;  N = 256;  Kpad = 512;  tid = b - 1152; }
        int tiles_n = N >> 5;
        int tk = tid / tiles_n, tn = tid % tiles_n;
        __shared__ float tile[32][33];
        int tx = threadIdx.x & 31, ty = threadIdx.x >> 5;  // 32 x 8
#pragma unroll
        for (int i = 0; i < 4; ++i) {
            int k = tk * 32 + ty + i * 8, n = tn * 32 + tx;
            tile[ty + i * 8][tx] = (k < K) ? in[(size_t)k * N + n] : 0.f;
        }
        __syncthreads();
#pragma unroll
        for (int i = 0; i < 4; ++i) {
            int n = tn * 32 + ty + i * 8, k = tk * 32 + tx;
            outp[(size_t)n * Kpad + k] = f2bf(tile[tx][ty + i * 8]);
        }
    } else if (b < 1397) {                // wct: (48, 624) fp32, rows>=39 zero
        int gid = (b - 1280) * 256 + threadIdx.x;
        if (gid < 48 * ND) {
            int j = gid / ND, k = gid % ND;
            wct[gid] = (j < NF) ? cw[(size_t)k * NF + j] : 0.f;
        }
    } else {                              // zero fp64 stats
        int gid = (b - 1397) * 256 + threadIdx.x;
        if (gid < nstats) stats[gid] = 0.0;
    }
}

// ---------------- field BN stats: sum/sumsq per field over (B, E), fp64 atomics ----------------
__global__ void k_field_stats(const int* __restrict__ x, const float* __restrict__ emb,
                              double* __restrict__ stats /* 2*NF */) {
    int f = blockIdx.x;
    int r = blockIdx.y * blockDim.x + threadIdx.x;
    double s = 0.0, q = 0.0;
    if (r < BB) {
        long long id = (long long)x[r * NF + f] + (long long)f * FIELD_DIM;
        const float4* p = (const float4*)(emb + id * NE);
#pragma unroll
        for (int i = 0; i < 4; ++i) {
            float4 v = p[i];
            s += (double)v.x; s += (double)v.y; s += (double)v.z; s += (double)v.w;
            q += (double)v.x * v.x; q += (double)v.y * v.y;
            q += (double)v.z * v.z; q += (double)v.w * v.w;
        }
    }
    __shared__ double ls[256], lq[256];
    ls[threadIdx.x] = s; lq[threadIdx.x] = q;
    __syncthreads();
    for (int off = 128; off > 0; off >>= 1) {
        if ((int)threadIdx.x < off) {
            ls[threadIdx.x] += ls[threadIdx.x + off];
            lq[threadIdx.x] += lq[threadIdx.x + off];
        }
        __syncthreads();
    }
    if (threadIdx.x == 0) {
        atomicAdd(&stats[f], ls[0]);
        atomicAdd(&stats[NF + f], lq[0]);
    }
}

// ---------------- gather + normalize -> flat (B, 624) fp32; field-BN finalize fused ----------------
__global__ void k_flat_norm(const int* __restrict__ x, const float* __restrict__ emb,
                            const double* __restrict__ stats, const float* __restrict__ bng,
                            const float* __restrict__ bnb, float* __restrict__ flat) {
    __shared__ float sc_s[NF], sh_s[NF];
    if ((int)threadIdx.x < NF) {
        int f = threadIdx.x;
        double cnt = (double)BB * NE;
        double mu = stats[f] / cnt;
        double var = stats[NF + f] / cnt - mu * mu;
        float sc = (float)((double)bng[f] / sqrt(var + (double)EPS_));
        sc_s[f] = sc;
        sh_s[f] = bnb[f] - (float)mu * sc;
    }
    __syncthreads();
    int gid = blockIdx.x * blockDim.x + threadIdx.x; // r*NF + f
    if (gid >= BB * NF) return;
    int f = gid % NF;
    long long id = (long long)x[gid] + (long long)f * FIELD_DIM;
    float sc = sc_s[f], sh = sh_s[f];
    const float4* p = (const float4*)(emb + id * NE);
    float4* o = (float4*)(flat) + (size_t)gid * 4;
#pragma unroll
    for (int i = 0; i < 4; ++i) {
        float4 v = p[i];
        o[i] = make_float4(fmaf(v.x, sc, sh), fmaf(v.y, sc, sh),
                           fmaf(v.z, sc, sh), fmaf(v.w, sc, sh));
    }
}

// ---------------- controller GEMM split-K: round-5 body, K halves [0,320) / [320,624) ----------
// 512 blocks x 256 threads. Tile 64 rows x 48 cols. Partials -> zp[half][B][NF] fp64.
__launch_bounds__(256)
__global__ void k_ctrl_gemm_sk(const float* __restrict__ flat, const float* __restrict__ wct,
                               double* __restrict__ zp) {
    __shared__ float As[64][68];       // [row][kk], padded
    __shared__ float Ws[64][49];       // [kk][col]
    const int t = threadIdx.x;
    const int tn = t & 15;             // col group: cols 3tn..3tn+2
    const int tm = t >> 4;             // row group: rows 4tm..4tm+3
    const int bm = blockIdx.x & 255;
    const int half = blockIdx.x >> 8;
    const int m0 = bm * 64;
    const int kbeg = half ? 320 : 0;
    const int kend = half ? 624 : 320;
    double acc[4][3] = {};
    for (int k0 = kbeg; k0 < kend; k0 += 64) {
        const int kl = (kend - k0 >= 64) ? 64 : (kend - k0);   // 64 or 48
        const int kl4 = kl >> 2;
        // stage A: 64 rows x kl floats (float4, coalesced)
#pragma unroll
        for (int i = 0; i < 4; ++i) {
            int idx = t + 256 * i;     // 0..1023
            int row = idx >> 4, c4 = idx & 15;
            if (c4 < kl4) {
                float4 v = *(const float4*)(flat + (size_t)(m0 + row) * ND + k0 + c4 * 4);
                *(float4*)&As[row][c4 * 4] = v;
            }
        }
        // stage W: 48 cols x kl floats, transposed into [kk][col]
        {
            int col = t >> 4;          // 0..15
            int c4 = t & 15;
#pragma unroll
            for (int cp = 0; cp < 3; ++cp, col += 16) {
                if (c4 < kl4) {
                    float4 v = *(const float4*)(wct + (size_t)col * ND + k0 + c4 * 4);
                    Ws[c4 * 4 + 0][col] = v.x; Ws[c4 * 4 + 1][col] = v.y;
                    Ws[c4 * 4 + 2][col] = v.z; Ws[c4 * 4 + 3][col] = v.w;
                }
            }
        }
        __syncthreads();
#pragma unroll 4
        for (int kk = 0; kk < kl; ++kk) {
            double a0 = (double)As[4 * tm + 0][kk];
            double a1 = (double)As[4 * tm + 1][kk];
            double a2 = (double)As[4 * tm + 2][kk];
            double a3 = (double)As[4 * tm + 3][kk];
            double w0 = (double)Ws[kk][3 * tn + 0];
            double w1 = (double)Ws[kk][3 * tn + 1];
            double w2 = (double)Ws[kk][3 * tn + 2];
            acc[0][0] += a0 * w0; acc[0][1] += a0 * w1; acc[0][2] += a0 * w2;
            acc[1][0] += a1 * w0; acc[1][1] += a1 * w1; acc[1][2] += a1 * w2;
            acc[2][0] += a2 * w0; acc[2][1] += a2 * w1; acc[2][2] += a2 * w2;
            acc[3][0] += a3 * w0; acc[3][1] += a3 * w1; acc[3][2] += a3 * w2;
        }
        __syncthreads();
    }
    double* zph = zp + (size_t)half * BB * NF;
#pragma unroll
    for (int j = 0; j < 3; ++j) {
        int col = 3 * tn + j;
        if (col < NF) {
#pragma unroll
            for (int i = 0; i < 4; ++i)
                zph[(size_t)(m0 + 4 * tm + i) * NF + col] = acc[i][j];
        }
    }
}

// ---------------- split-K reduce: z = (float)(p0+p1+bias), fused col stats ----------------
__global__ void k_ctrl_reduce(const double* __restrict__ zp, const float* __restrict__ bias,
                              float* __restrict__ z, double* __restrict__ stats) {
    __shared__ double Sred[2][16][48];
    const int t = threadIdx.x;
    const int tn = t & 15;
    const int tm = t >> 4;
    const int m0 = blockIdx.x * 64;
#pragma unroll
    for (int j = 0; j < 3; ++j) {
        int col = 3 * tn + j;
        double s = 0.0, q = 0.0;
        if (col < NF) {
            float bs = bias[col];
#pragma unroll
            for (int i = 0; i < 4; ++i) {
                size_t idx = (size_t)(m0 + 4 * tm + i) * NF + col;
                double p01 = zp[idx] + zp[(size_t)BB * NF + idx];
                float v = (float)(p01 + (double)bs);
                z[idx] = v;
                s += (double)v;
                q += (double)v * (double)v;
            }
        }
        Sred[0][tm][col] = s;
        Sred[1][tm][col] = q;
    }
    __syncthreads();
    if (t < NF) {
        double ts = 0.0, tq = 0.0;
#pragma unroll
        for (int i = 0; i < 16; ++i) { ts += Sred[0][i][t]; tq += Sred[1][i][t]; }
        atomicAdd(&stats[t], ts);
        atomicAdd(&stats[NF + t], tq);
    }
}

// ---------------- ctrl-BN finalize + BN+ReLU + RANK-BASED top-k + gate -> flatg (fused) --------
// Selection: lane i selected iff rank_i < k, rank_i = #{j: w_j > w_i || (w_j==w_i && j<i)}.
// Identical total order to iterative argmax with (value, 63-lane) key -> same selection as before,
// but 39 INDEPENDENT broadcasts instead of k*6 dependent butterfly steps.
__global__ void k_topk_gate(const float* __restrict__ zc, const double* __restrict__ stats,
                            const float* __restrict__ cbg, const float* __restrict__ cbb,
                            const int* __restrict__ kptr, const float* __restrict__ flat,
                            unsigned short* __restrict__ flatg) {
    __shared__ float sc_s[NF], sh_s[NF];
    int t = threadIdx.x;
    if (t < NF) {
        double mu = stats[t] / (double)BB;
        double var = stats[NF + t] / (double)BB - mu * mu;
        float sc = (float)((double)cbg[t] / sqrt(var + (double)EPS_));
        sc_s[t] = sc;
        sh_s[t] = cbb[t] - (float)mu * sc;
    }
    __syncthreads();
    int r = blockIdx.x * 4 + (t >> 6);
    int lane = t & 63;
    int k = kptr[0];
    bool active = (lane < NF);
    float w = -1.f;
    if (active) {
        float v = zc[(size_t)r * NF + lane];
        w = fmaxf(fmaf(v, sc_s[lane], sh_s[lane]), 0.f);
    }
    int rank = 0;
#pragma unroll
    for (int j = 0; j < NF; ++j) {
        float vj = __shfl(w, j, 64);                 // broadcast lane j (readlane, pipelined)
        rank += (vj > w || (vj == w && j < lane)) ? 1 : 0;
    }
    bool sel = active && (rank < k);
    float val = sel ? w : 0.f;
    float sum = val;
#pragma unroll
    for (int off = 32; off > 0; off >>= 1) sum += __shfl_xor(sum, off, 64);
    if (active) {
        float ms = sel ? ((sum > 0.f) ? (w / sum) : 0.f) : 0.f;
        const float* src = flat + (size_t)r * ND + lane * 16;
        unsigned short* dst = flatg + (size_t)r * 640 + lane * 16;
#pragma unroll
        for (int h = 0; h < 2; ++h) {
            union { s16x8 v; unsigned short u[8]; } p;
#pragma unroll
            for (int j = 0; j < 8; ++j) p.u[j] = f2bf(src[h * 8 + j] * ms);
            *(s16x8*)(dst + h * 8) = p.v;
        }
    } else if (lane == NF) {
        s16x8 zv = {};
        *(s16x8*)(flatg + (size_t)r * 640 + 624) = zv;
        *(s16x8*)(flatg + (size_t)r * 640 + 632) = zv;
    }
}

// ---------------- bf16 MFMA GEMM (layer 1): C = A @ Bt^T + bias, fused col stats ----------------
__launch_bounds__(256)
__global__ void k_mfma_gemm(const unsigned short* __restrict__ A,  // M x K bf16
                            const unsigned short* __restrict__ Bt, // N x K bf16
                            const float* __restrict__ bias,
                            unsigned short* __restrict__ C,        // M x N bf16
                            double* __restrict__ stats,            // 2*N fp64
                            int M, int K, int N) {
    __shared__ char lds[32768];
    char* As = lds;
    char* Bs = lds + 16384;
    const int t = threadIdx.x;
    const int l = t & 63;
    const int w = t >> 6;
    const int m0 = blockIdx.y * 128, n0 = blockIdx.x * 128;
    const int Wr = (w >> 1) * 64, Wc = (w & 1) * 64;

    const int srow = t >> 3;            // 0..31
    const int sswz = (t & 7) ^ (srow & 7);
    const unsigned short* ga[4];
    const unsigned short* gb[4];
#pragma unroll
    for (int i = 0; i < 4; ++i) {
        ga[i] = A + (size_t)(m0 + i * 32 + srow) * K + sswz * 8;
        gb[i] = Bt + (size_t)(n0 + i * 32 + srow) * K + sswz * 8;
    }
    int a_off[4][2], b_off[4][2];
#pragma unroll
    for (int m = 0; m < 4; ++m) {
#pragma unroll
        for (int h = 0; h < 2; ++h) {
            int r = Wr + m * 16 + (l & 15);
            a_off[m][h] = r * 128 + (((h * 4 + (l >> 4)) ^ (r & 7)) << 4);
            int c = Wc + m * 16 + (l & 15);
            b_off[m][h] = c * 128 + (((h * 4 + (l >> 4)) ^ (c & 7)) << 4);
        }
    }
    f32x4 acc[4][4] = {};
    for (int k0 = 0; k0 < K; k0 += 64) {
#pragma unroll
        for (int i = 0; i < 4; ++i) {
            __builtin_amdgcn_global_load_lds(
                (const __attribute__((address_space(1))) void*)ga[i],
                (__attribute__((address_space(3))) void*)(As + i * 4096 + t * 16), 16, 0, 0);
            __builtin_amdgcn_global_load_lds(
                (const __attribute__((address_space(1))) void*)gb[i],
                (__attribute__((address_space(3))) void*)(Bs + i * 4096 + t * 16), 16, 0, 0);
            ga[i] += 64; gb[i] += 64;
        }
        __syncthreads();
#pragma unroll
        for (int h = 0; h < 2; ++h) {
            bfx8 af[4], bv[4];
#pragma unroll
            for (int m = 0; m < 4; ++m)
                af[m] = __builtin_bit_cast(bfx8, *(const s16x8*)(As + a_off[m][h]));
#pragma unroll
            for (int n = 0; n < 4; ++n)
                bv[n] = __builtin_bit_cast(bfx8, *(const s16x8*)(Bs + b_off[n][h]));
#pragma unroll
            for (int m = 0; m < 4; ++m)
#pragma unroll
                for (int n = 0; n < 4; ++n)
                    acc[m][n] = __builtin_amdgcn_mfma_f32_16x16x32_bf16(af[m], bv[n], acc[m][n], 0, 0, 0);
        }
        __syncthreads();
    }
#pragma unroll
    for (int n = 0; n < 4; ++n) {
        int nc = n0 + Wc + n * 16 + (l & 15);
        float bs = bias[nc];
        double s = 0.0, q = 0.0;
#pragma unroll
        for (int m = 0; m < 4; ++m) {
            int rbase = m0 + Wr + m * 16 + ((l >> 4) << 2);
#pragma unroll
            for (int i = 0; i < 4; ++i) {
                float v = acc[m][n][i] + bs;
                C[(size_t)(rbase + i) * N + nc] = f2bf(v);
                s += (double)v;
                q += (double)v * (double)v;
            }
        }
        s += __shfl_xor(s, 16, 64); s += __shfl_xor(s, 32, 64);
        q += __shfl_xor(q, 16, 64); q += __shfl_xor(q, 32, 64);
        if ((l >> 4) == 0) {
            atomicAdd(&stats[nc], s);
            atomicAdd(&stats[N + nc], q);
        }
    }
}

// ---------------- bf16 MFMA GEMM with fused input-BN+ReLU on A (layers 2,3) ----------------
__launch_bounds__(256)
__global__ void k_mfma_gemm_bn(const unsigned short* __restrict__ A,   // M x K bf16 raw
                               const double* __restrict__ statsIn,     // 2*K (A's BN stats)
                               const float* __restrict__ g, const float* __restrict__ be,
                               const unsigned short* __restrict__ Bt,  // N x K bf16
                               const float* __restrict__ bias,
                               unsigned short* __restrict__ C,         // M x N bf16
                               double* __restrict__ stats,             // 2*N fp64
                               int M, int K, int N) {
    __shared__ char lds[40960];
    char* As = lds;
    char* Bs = lds + 16384;
    float* scs = (float*)(lds + 32768);   // K floats
    float* shs = scs + K;                 // K floats (K<=1024 -> fits 8KB)
    const int t = threadIdx.x;
    const int l = t & 63;
    const int w = t >> 6;
    const int m0 = blockIdx.y * 128, n0 = blockIdx.x * 128;
    const int Wr = (w >> 1) * 64, Wc = (w & 1) * 64;

    constexpr double inv_bb = 1.0 / (double)BB;
    for (int c = t; c < K; c += 256) {
        double mu = statsIn[c] * inv_bb;
        double var = statsIn[K + c] * inv_bb - mu * mu;
        float sc = g[c] / sqrtf((float)var + EPS_);
        scs[c] = sc;
        shs[c] = be[c] - (float)mu * sc;
    }
    __syncthreads();

    const int srow = t >> 3;            // 0..31
    const int sswz = (t & 7) ^ (srow & 7);
    const unsigned short* ga[4];
    const unsigned short* gb[4];
#pragma unroll
    for (int i = 0; i < 4; ++i) {
        ga[i] = A + (size_t)(m0 + i * 32 + srow) * K + sswz * 8;
        gb[i] = Bt + (size_t)(n0 + i * 32 + srow) * K + sswz * 8;
    }
    int a_off[4][2], b_off[4][2];
#pragma unroll
    for (int m = 0; m < 4; ++m) {
#pragma unroll
        for (int h = 0; h < 2; ++h) {
            int r = Wr + m * 16 + (l & 15);
            a_off[m][h] = r * 128 + (((h * 4 + (l >> 4)) ^ (r & 7)) << 4);
            int c = Wc + m * 16 + (l & 15);
            b_off[m][h] = c * 128 + (((h * 4 + (l >> 4)) ^ (c & 7)) << 4);
        }
    }
    f32x4 acc[4][4] = {};
    for (int k0 = 0; k0 < K; k0 += 64) {
#pragma unroll
        for (int i = 0; i < 4; ++i) {
            __builtin_amdgcn_global_load_lds(
                (const __attribute__((address_space(1))) void*)gb[i],
                (__attribute__((address_space(3))) void*)(Bs + i * 4096 + t * 16), 16, 0, 0);
            gb[i] += 64;
        }
        {
            int kb = k0 + sswz * 8;
            float4 sc0 = *(const float4*)&scs[kb];
            float4 sc1 = *(const float4*)&scs[kb + 4];
            float4 sh0 = *(const float4*)&shs[kb];
            float4 sh1 = *(const float4*)&shs[kb + 4];
            float scl[8] = {sc0.x, sc0.y, sc0.z, sc0.w, sc1.x, sc1.y, sc1.z, sc1.w};
            float shl[8] = {sh0.x, sh0.y, sh0.z, sh0.w, sh1.x, sh1.y, sh1.z, sh1.w};
#pragma unroll
            for (int i = 0; i < 4; ++i) {
                union { s16x8 v; unsigned short u[8]; } pin, pout;
                pin.v = *(const s16x8*)ga[i];
#pragma unroll
                for (int j = 0; j < 8; ++j)
                    pout.u[j] = f2bf(fmaxf(fmaf(bf2f(pin.u[j]), scl[j], shl[j]), 0.f));
                *(s16x8*)(As + i * 4096 + t * 16) = pout.v;
                ga[i] += 64;
            }
        }
        __syncthreads();
#pragma unroll
        for (int h = 0; h < 2; ++h) {
            bfx8 af[4], bv[4];
#pragma unroll
            for (int m = 0; m < 4; ++m)
                af[m] = __builtin_bit_cast(bfx8, *(const s16x8*)(As + a_off[m][h]));
#pragma unroll
            for (int n = 0; n < 4; ++n)
                bv[n] = __builtin_bit_cast(bfx8, *(const s16x8*)(Bs + b_off[n][h]));
#pragma unroll
            for (int m = 0; m < 4; ++m)
#pragma unroll
                for (int n = 0; n < 4; ++n)
                    acc[m][n] = __builtin_amdgcn_mfma_f32_16x16x32_bf16(af[m], bv[n], acc[m][n], 0, 0, 0);
        }
        __syncthreads();
    }
#pragma unroll
    for (int n = 0; n < 4; ++n) {
        int nc = n0 + Wc + n * 16 + (l & 15);
        float bs = bias[nc];
        double s = 0.0, q = 0.0;
#pragma unroll
        for (int m = 0; m < 4; ++m) {
            int rbase = m0 + Wr + m * 16 + ((l >> 4) << 2);
#pragma unroll
            for (int i = 0; i < 4; ++i) {
                float v = acc[m][n][i] + bs;
                C[(size_t)(rbase + i) * N + nc] = f2bf(v);
                s += (double)v;
                q += (double)v * (double)v;
            }
        }
        s += __shfl_xor(s, 16, 64); s += __shfl_xor(s, 32, 64);
        q += __shfl_xor(q, 16, 64); q += __shfl_xor(q, 32, 64);
        if ((l >> 4) == 0) {
            atomicAdd(&stats[nc], s);
            atomicAdd(&stats[N + nc], q);
        }
    }
}

// ---------------- final: bn3+ReLU on raw h3, dot w_out, + wide linear, sigmoid ----------------
__global__ void k_out(const unsigned short* __restrict__ h3, const double* __restrict__ stats3,
                      const float* __restrict__ g3, const float* __restrict__ be3,
                      const float* __restrict__ wo, const float* __restrict__ bo,
                      const int* __restrict__ x, const float* __restrict__ lt,
                      const float* __restrict__ lb, float* __restrict__ out) {
    __shared__ float scs[256], shs[256];
    int t = threadIdx.x;
    {
        constexpr double inv_bb = 1.0 / (double)BB;
        double mu = stats3[t] * inv_bb;
        double var = stats3[256 + t] * inv_bb - mu * mu;
        float sc = g3[t] / sqrtf((float)var + EPS_);
        scs[t] = sc;
        shs[t] = be3[t] - (float)mu * sc;
    }
    __syncthreads();
    int r = blockIdx.x * 4 + (t >> 6);
    int lane = t & 63;
    float s = 0.f;
#pragma unroll
    for (int k = lane; k < 256; k += 64) {
        float xv = bf2f(h3[(size_t)r * 256 + k]);
        float hb = bf2f(f2bf(fmaxf(fmaf(xv, scs[k], shs[k]), 0.f)));
        s += hb * wo[k];
    }
    if (lane < NF) {
        long long id = (long long)x[r * NF + lane] + (long long)lane * FIELD_DIM;
        s += lt[id];
    }
#pragma unroll
    for (int off = 32; off > 0; off >>= 1) s += __shfl_xor(s, off, 64);
    if (lane == 0) {
        float tt = s + bo[0] + lb[0];
        out[r] = 1.f / (1.f + expf(-tt));
    }
}

extern "C" void kernel_launch(void* const* d_in, const int* in_sizes, int n_in,
                              void* d_out, int out_size, void* d_ws, size_t ws_size,
                              hipStream_t stream) {
    const int* x = (const int*)d_in[0];
    const float* emb = (const float*)d_in[1];
    const float* lint = (const float*)d_in[2];
    const float* linb = (const float*)d_in[3];
    const float* bng = (const float*)d_in[4];
    const float* bnb = (const float*)d_in[5];
    const float* cw = (const float*)d_in[6];
    const float* cb = (const float*)d_in[7];
    const float* cbg = (const float*)d_in[8];
    const float* cbb = (const float*)d_in[9];
    const float* w1 = (const float*)d_in[10];
    const float* b1 = (const float*)d_in[11];
    const float* g1 = (const float*)d_in[12];
    const float* be1 = (const float*)d_in[13];
    const float* w2 = (const float*)d_in[14];
    const float* b2 = (const float*)d_in[15];
    const float* g2 = (const float*)d_in[16];
    const float* be2 = (const float*)d_in[17];
    const float* w3 = (const float*)d_in[18];
    const float* b3 = (const float*)d_in[19];
    const float* g3 = (const float*)d_in[20];
    const float* be3 = (const float*)d_in[21];
    const float* wo = (const float*)d_in[22];
    const float* bo = (const float*)d_in[23];
    const int* kptr = (const int*)d_in[24];
    float* out = (float*)d_out;

    char* p = (char*)d_ws;
    float* flat = (float*)p;                 p += (size_t)BB * ND * 4;      // fp32, ctrl path
    unsigned short* flatg = (unsigned short*)p; p += (size_t)BB * 640 * 2;  // gated bf16, K-padded
    unsigned short* h1 = (unsigned short*)p; p += (size_t)BB * 1024 * 2;    // raw (pre-BN)
    unsigned short* h2 = (unsigned short*)p; p += (size_t)BB * 512 * 2;     // raw
    unsigned short* h3 = (unsigned short*)p; p += (size_t)BB * 256 * 2;     // raw
    unsigned short* w1t = (unsigned short*)p; p += (size_t)1024 * 640 * 2;
    unsigned short* w2t = (unsigned short*)p; p += (size_t)512 * 1024 * 2;
    unsigned short* w3t = (unsigned short*)p; p += (size_t)256 * 512 * 2;
    float* wct = (float*)p;                  p += (size_t)48 * ND * 4;      // ctrl w transposed fp32
    float* zc = (float*)p;                   p += (size_t)BB * NF * 4;
    double* zp = (double*)p;                 p += (size_t)2 * BB * NF * 8;  // split-K partials fp64
    // disjoint per-layer fp64 stat regions, zeroed inside k_prep
    double* stats_all = (double*)p;
    double* stats_f = stats_all;             // 2*39
    double* stats_c = stats_f + 2 * NF;      // 2*39
    double* stats_1 = stats_c + 2 * NF;      // 2*1024
    double* stats_2 = stats_1 + 2 * 1024;    // 2*512
    double* stats_3 = stats_2 + 2 * 512;     // 2*256
    int stats_doubles = 2 * (NF + NF + 1024 + 512 + 256); // 3662

    // ---- prep: tiled weight transposes + stats zero (one kernel, 1412 blocks) ----
    k_prep<<<1412, 256, 0, stream>>>(w1, w2, w3, cw, w1t, w2t, w3t, wct,
                                     stats_all, stats_doubles);

    // ---- field BN (finalize fused into flat_norm) ----
    k_field_stats<<<dim3(NF, BB / 256), 256, 0, stream>>>(x, emb, stats_f);
    k_flat_norm<<<(BB * NF + 255) / 256, 256, 0, stream>>>(x, emb, stats_f, bng, bnb, flat);

    // ---- controller: split-K GEMM (2 blocks/CU) + reduce/stats + fused finalize/topk/gate ----
    k_ctrl_gemm_sk<<<512, 256, 0, stream>>>(flat, wct, zp);
    k_ctrl_reduce<<<BB / 64, 256, 0, stream>>>(zp, cb, zc, stats_c);
    k_topk_gate<<<BB / 4, 256, 0, stream>>>(zc, stats_c, cbg, cbb, kptr, flat, flatg);

    // ---- MLP layer 1: 640(pad) -> 1024 (h1 raw) ----
    k_mfma_gemm<<<dim3(1024 / 128, BB / 128), 256, 0, stream>>>(flatg, w1t, b1, h1, stats_1, BB, 640, 1024);

    // ---- MLP layer 2: BN1+ReLU fused into A-staging; 1024 -> 512 (h2 raw) ----
    k_mfma_gemm_bn<<<dim3(512 / 128, BB / 128), 256, 0, stream>>>(h1, stats_1, g1, be1,
                                                                  w2t, b2, h2, stats_2, BB, 1024, 512);

    // ---- MLP layer 3: BN2+ReLU fused; 512 -> 256 (h3 raw) ----
    k_mfma_gemm_bn<<<dim3(256 / 128, BB / 128), 256, 0, stream>>>(h2, stats_2, g2, be2,
                                                                  w3t, b3, h3, stats_3, BB, 512, 256);

    // ---- output: BN3+ReLU + dot w_out + wide linear + sigmoid ----
    k_out<<<BB / 4, 256, 0, stream>>>(h3, stats_3, g3, be3, wo, bo, x, lint, linb, out);
}

// Round 12
// 232.776 us; speedup vs baseline: 1.4749x; 1.0351x over previous
//
#include <hip/hip_runtime.h>
#include <math.h>
#include <stdint.h>

constexpr int BB = 16384;   // batch
constexpr int NF = 39;      // fields
constexpr int NE = 16;      // embed dim
constexpr int ND = NF * NE; // 624
constexpr int FIELD_DIM = 26000;
constexpr float EPS_ = 1e-5f;

typedef __bf16 bfx8 __attribute__((ext_vector_type(8)));
typedef float f32x4 __attribute__((ext_vector_type(4)));
typedef short s16x8 __attribute__((ext_vector_type(8)));

static __device__ __forceinline__ unsigned short f2bf(float f) {
    union { float f; unsigned u; } a; a.f = f;
    unsigned r = a.u + 0x7fffu + ((a.u >> 16) & 1u); // RNE
    return (unsigned short)(r >> 16);
}
static __device__ __forceinline__ float bf2f(unsigned short u) {
    union { unsigned u; float f; } a; a.u = ((unsigned)u) << 16;
    return a.f;
}

// XCD-aware block remap: l -> (bx, by). ny must be 128 (=8 XCDs * 16 panels).
// For fixed xcd (l&7), consecutive blocks iterate bx with the SAME by ->
// A-panel is reused within one XCD's L2 and owned by exactly one XCD.
static __device__ __forceinline__ void xcd_map(int l, int lognx, int& bx, int& by) {
    int s = l >> 3;
    bx = s & ((1 << lognx) - 1);
    by = ((l & 7) << 4) + (s >> lognx);
}

// ---------------- fused prep: LDS-tiled weight transposes + ctrl transpose + stats zero --------
// grid: [0,640) w1t tiles | [640,1152) w2t | [1152,1280) w3t | [1280,1397) wct | [1397,1412) stats
__global__ void k_prep(const float* __restrict__ w1, const float* __restrict__ w2,
                       const float* __restrict__ w3, const float* __restrict__ cw,
                       unsigned short* __restrict__ w1t, unsigned short* __restrict__ w2t,
                       unsigned short* __restrict__ w3t, float* __restrict__ wct,
                       double* __restrict__ stats, int nstats) {
    int b = blockIdx.x;
    if (b < 1280) {
        const float* in; unsigned short* outp; int K, N, Kpad, tid;
        if (b < 640)        { in = w1; outp = w1t; K = 624;  N = 1024; Kpad = 640;  tid = b; }
        else if (b < 1152)  { in = w2; outp = w2t; K = 1024; N = 512;  Kpad = 1024; tid = b - 640; }
        else                { in = w3; outp = w3t; K = 512;  N = 256;  Kpad = 512;  tid = b - 1152; }
        int tiles_n = N >> 5;
        int tk = tid / tiles_n, tn = tid % tiles_n;
        __shared__ float tile[32][33];
        int tx = threadIdx.x & 31, ty = threadIdx.x >> 5;  // 32 x 8
#pragma unroll
        for (int i = 0; i < 4; ++i) {
            int k = tk * 32 + ty + i * 8, n = tn * 32 + tx;
            tile[ty + i * 8][tx] = (k < K) ? in[(size_t)k * N + n] : 0.f;
        }
        __syncthreads();
#pragma unroll
        for (int i = 0; i < 4; ++i) {
            int n = tn * 32 + ty + i * 8, k = tk * 32 + tx;
            outp[(size_t)n * Kpad + k] = f2bf(tile[tx][ty + i * 8]);
        }
    } else if (b < 1397) {                // wct: (48, 624) fp32, rows>=39 zero
        int gid = (b - 1280) * 256 + threadIdx.x;
        if (gid < 48 * ND) {
            int j = gid / ND, k = gid % ND;
            wct[gid] = (j < NF) ? cw[(size_t)k * NF + j] : 0.f;
        }
    } else {                              // zero fp64 stats
        int gid = (b - 1397) * 256 + threadIdx.x;
        if (gid < nstats) stats[gid] = 0.0;
    }
}

// ---------------- field BN stats: sum/sumsq per field over (B, E), fp64 atomics ----------------
__global__ void k_field_stats(const int* __restrict__ x, const float* __restrict__ emb,
                              double* __restrict__ stats /* 2*NF */) {
    int f = blockIdx.x;
    int r = blockIdx.y * blockDim.x + threadIdx.x;
    double s = 0.0, q = 0.0;
    if (r < BB) {
        long long id = (long long)x[r * NF + f] + (long long)f * FIELD_DIM;
        const float4* p = (const float4*)(emb + id * NE);
#pragma unroll
        for (int i = 0; i < 4; ++i) {
            float4 v = p[i];
            s += (double)v.x; s += (double)v.y; s += (double)v.z; s += (double)v.w;
            q += (double)v.x * v.x; q += (double)v.y * v.y;
            q += (double)v.z * v.z; q += (double)v.w * v.w;
        }
    }
    __shared__ double ls[256], lq[256];
    ls[threadIdx.x] = s; lq[threadIdx.x] = q;
    __syncthreads();
    for (int off = 128; off > 0; off >>= 1) {
        if ((int)threadIdx.x < off) {
            ls[threadIdx.x] += ls[threadIdx.x + off];
            lq[threadIdx.x] += lq[threadIdx.x + off];
        }
        __syncthreads();
    }
    if (threadIdx.x == 0) {
        atomicAdd(&stats[f], ls[0]);
        atomicAdd(&stats[NF + f], lq[0]);
    }
}

// ---------------- gather + normalize -> flat (B, 624) fp32; field-BN finalize fused ----------------
__global__ void k_flat_norm(const int* __restrict__ x, const float* __restrict__ emb,
                            const double* __restrict__ stats, const float* __restrict__ bng,
                            const float* __restrict__ bnb, float* __restrict__ flat) {
    __shared__ float sc_s[NF], sh_s[NF];
    if ((int)threadIdx.x < NF) {
        int f = threadIdx.x;
        double cnt = (double)BB * NE;
        double mu = stats[f] / cnt;
        double var = stats[NF + f] / cnt - mu * mu;
        float sc = (float)((double)bng[f] / sqrt(var + (double)EPS_));
        sc_s[f] = sc;
        sh_s[f] = bnb[f] - (float)mu * sc;
    }
    __syncthreads();
    int gid = blockIdx.x * blockDim.x + threadIdx.x; // r*NF + f
    if (gid >= BB * NF) return;
    int f = gid % NF;
    long long id = (long long)x[gid] + (long long)f * FIELD_DIM;
    float sc = sc_s[f], sh = sh_s[f];
    const float4* p = (const float4*)(emb + id * NE);
    float4* o = (float4*)(flat) + (size_t)gid * 4;
#pragma unroll
    for (int i = 0; i < 4; ++i) {
        float4 v = p[i];
        o[i] = make_float4(fmaf(v.x, sc, sh), fmaf(v.y, sc, sh),
                           fmaf(v.z, sc, sh), fmaf(v.w, sc, sh));
    }
}

// ---------------- controller GEMM split-K: round-5 body, K halves [0,320) / [320,624) ----------
__launch_bounds__(256)
__global__ void k_ctrl_gemm_sk(const float* __restrict__ flat, const float* __restrict__ wct,
                               double* __restrict__ zp) {
    __shared__ float As[64][68];       // [row][kk], padded
    __shared__ float Ws[64][49];       // [kk][col]
    const int t = threadIdx.x;
    const int tn = t & 15;             // col group: cols 3tn..3tn+2
    const int tm = t >> 4;             // row group: rows 4tm..4tm+3
    const int bm = blockIdx.x & 255;
    const int half = blockIdx.x >> 8;
    const int m0 = bm * 64;
    const int kbeg = half ? 320 : 0;
    const int kend = half ? 624 : 320;
    double acc[4][3] = {};
    for (int k0 = kbeg; k0 < kend; k0 += 64) {
        const int kl = (kend - k0 >= 64) ? 64 : (kend - k0);   // 64 or 48
        const int kl4 = kl >> 2;
#pragma unroll
        for (int i = 0; i < 4; ++i) {
            int idx = t + 256 * i;     // 0..1023
            int row = idx >> 4, c4 = idx & 15;
            if (c4 < kl4) {
                float4 v = *(const float4*)(flat + (size_t)(m0 + row) * ND + k0 + c4 * 4);
                *(float4*)&As[row][c4 * 4] = v;
            }
        }
        {
            int col = t >> 4;          // 0..15
            int c4 = t & 15;
#pragma unroll
            for (int cp = 0; cp < 3; ++cp, col += 16) {
                if (c4 < kl4) {
                    float4 v = *(const float4*)(wct + (size_t)col * ND + k0 + c4 * 4);
                    Ws[c4 * 4 + 0][col] = v.x; Ws[c4 * 4 + 1][col] = v.y;
                    Ws[c4 * 4 + 2][col] = v.z; Ws[c4 * 4 + 3][col] = v.w;
                }
            }
        }
        __syncthreads();
#pragma unroll 4
        for (int kk = 0; kk < kl; ++kk) {
            double a0 = (double)As[4 * tm + 0][kk];
            double a1 = (double)As[4 * tm + 1][kk];
            double a2 = (double)As[4 * tm + 2][kk];
            double a3 = (double)As[4 * tm + 3][kk];
            double w0 = (double)Ws[kk][3 * tn + 0];
            double w1 = (double)Ws[kk][3 * tn + 1];
            double w2 = (double)Ws[kk][3 * tn + 2];
            acc[0][0] += a0 * w0; acc[0][1] += a0 * w1; acc[0][2] += a0 * w2;
            acc[1][0] += a1 * w0; acc[1][1] += a1 * w1; acc[1][2] += a1 * w2;
            acc[2][0] += a2 * w0; acc[2][1] += a2 * w1; acc[2][2] += a2 * w2;
            acc[3][0] += a3 * w0; acc[3][1] += a3 * w1; acc[3][2] += a3 * w2;
        }
        __syncthreads();
    }
    double* zph = zp + (size_t)half * BB * NF;
#pragma unroll
    for (int j = 0; j < 3; ++j) {
        int col = 3 * tn + j;
        if (col < NF) {
#pragma unroll
            for (int i = 0; i < 4; ++i)
                zph[(size_t)(m0 + 4 * tm + i) * NF + col] = acc[i][j];
        }
    }
}

// ---------------- split-K reduce: z = (float)(p0+p1+bias), fused col stats ----------------
__global__ void k_ctrl_reduce(const double* __restrict__ zp, const float* __restrict__ bias,
                              float* __restrict__ z, double* __restrict__ stats) {
    __shared__ double Sred[2][16][48];
    const int t = threadIdx.x;
    const int tn = t & 15;
    const int tm = t >> 4;
    const int m0 = blockIdx.x * 64;
#pragma unroll
    for (int j = 0; j < 3; ++j) {
        int col = 3 * tn + j;
        double s = 0.0, q = 0.0;
        if (col < NF) {
            float bs = bias[col];
#pragma unroll
            for (int i = 0; i < 4; ++i) {
                size_t idx = (size_t)(m0 + 4 * tm + i) * NF + col;
                double p01 = zp[idx] + zp[(size_t)BB * NF + idx];
                float v = (float)(p01 + (double)bs);
                z[idx] = v;
                s += (double)v;
                q += (double)v * (double)v;
            }
        }
        Sred[0][tm][col] = s;
        Sred[1][tm][col] = q;
    }
    __syncthreads();
    if (t < NF) {
        double ts = 0.0, tq = 0.0;
#pragma unroll
        for (int i = 0; i < 16; ++i) { ts += Sred[0][i][t]; tq += Sred[1][i][t]; }
        atomicAdd(&stats[t], ts);
        atomicAdd(&stats[NF + t], tq);
    }
}

// ---------------- ctrl-BN finalize + BN+ReLU + RANK-BASED top-k + gate -> flatg (fused) --------
__global__ void k_topk_gate(const float* __restrict__ zc, const double* __restrict__ stats,
                            const float* __restrict__ cbg, const float* __restrict__ cbb,
                            const int* __restrict__ kptr, const float* __restrict__ flat,
                            unsigned short* __restrict__ flatg) {
    __shared__ float sc_s[NF], sh_s[NF];
    int t = threadIdx.x;
    if (t < NF) {
        double mu = stats[t] / (double)BB;
        double var = stats[NF + t] / (double)BB - mu * mu;
        float sc = (float)((double)cbg[t] / sqrt(var + (double)EPS_));
        sc_s[t] = sc;
        sh_s[t] = cbb[t] - (float)mu * sc;
    }
    __syncthreads();
    int r = blockIdx.x * 4 + (t >> 6);
    int lane = t & 63;
    int k = kptr[0];
    bool active = (lane < NF);
    float w = -1.f;
    if (active) {
        float v = zc[(size_t)r * NF + lane];
        w = fmaxf(fmaf(v, sc_s[lane], sh_s[lane]), 0.f);
    }
    int rank = 0;
#pragma unroll
    for (int j = 0; j < NF; ++j) {
        float vj = __shfl(w, j, 64);
        rank += (vj > w || (vj == w && j < lane)) ? 1 : 0;
    }
    bool sel = active && (rank < k);
    float val = sel ? w : 0.f;
    float sum = val;
#pragma unroll
    for (int off = 32; off > 0; off >>= 1) sum += __shfl_xor(sum, off, 64);
    if (active) {
        float ms = sel ? ((sum > 0.f) ? (w / sum) : 0.f) : 0.f;
        const float* src = flat + (size_t)r * ND + lane * 16;
        unsigned short* dst = flatg + (size_t)r * 640 + lane * 16;
#pragma unroll
        for (int h = 0; h < 2; ++h) {
            union { s16x8 v; unsigned short u[8]; } p;
#pragma unroll
            for (int j = 0; j < 8; ++j) p.u[j] = f2bf(src[h * 8 + j] * ms);
            *(s16x8*)(dst + h * 8) = p.v;
        }
    } else if (lane == NF) {
        s16x8 zv = {};
        *(s16x8*)(flatg + (size_t)r * 640 + 624) = zv;
        *(s16x8*)(flatg + (size_t)r * 640 + 632) = zv;
    }
}

// ---------------- bf16 MFMA GEMM (layer 1): C = A @ Bt^T + bias, fused col stats ----------------
// 1D grid, XCD-aware remap (lognx = log2(N/128)).
__launch_bounds__(256)
__global__ void k_mfma_gemm(const unsigned short* __restrict__ A,  // M x K bf16
                            const unsigned short* __restrict__ Bt, // N x K bf16
                            const float* __restrict__ bias,
                            unsigned short* __restrict__ C,        // M x N bf16
                            double* __restrict__ stats,            // 2*N fp64
                            int M, int K, int N, int lognx) {
    __shared__ char lds[32768];
    char* As = lds;
    char* Bs = lds + 16384;
    const int t = threadIdx.x;
    const int l = t & 63;
    const int w = t >> 6;
    int bx, by;
    xcd_map(blockIdx.x, lognx, bx, by);
    const int m0 = by * 128, n0 = bx * 128;
    const int Wr = (w >> 1) * 64, Wc = (w & 1) * 64;

    const int srow = t >> 3;            // 0..31
    const int sswz = (t & 7) ^ (srow & 7);
    const unsigned short* ga[4];
    const unsigned short* gb[4];
#pragma unroll
    for (int i = 0; i < 4; ++i) {
        ga[i] = A + (size_t)(m0 + i * 32 + srow) * K + sswz * 8;
        gb[i] = Bt + (size_t)(n0 + i * 32 + srow) * K + sswz * 8;
    }
    int a_off[4][2], b_off[4][2];
#pragma unroll
    for (int m = 0; m < 4; ++m) {
#pragma unroll
        for (int h = 0; h < 2; ++h) {
            int r = Wr + m * 16 + (l & 15);
            a_off[m][h] = r * 128 + (((h * 4 + (l >> 4)) ^ (r & 7)) << 4);
            int c = Wc + m * 16 + (l & 15);
            b_off[m][h] = c * 128 + (((h * 4 + (l >> 4)) ^ (c & 7)) << 4);
        }
    }
    f32x4 acc[4][4] = {};
    for (int k0 = 0; k0 < K; k0 += 64) {
#pragma unroll
        for (int i = 0; i < 4; ++i) {
            __builtin_amdgcn_global_load_lds(
                (const __attribute__((address_space(1))) void*)ga[i],
                (__attribute__((address_space(3))) void*)(As + i * 4096 + t * 16), 16, 0, 0);
            __builtin_amdgcn_global_load_lds(
                (const __attribute__((address_space(1))) void*)gb[i],
                (__attribute__((address_space(3))) void*)(Bs + i * 4096 + t * 16), 16, 0, 0);
            ga[i] += 64; gb[i] += 64;
        }
        __syncthreads();
#pragma unroll
        for (int h = 0; h < 2; ++h) {
            bfx8 af[4], bv[4];
#pragma unroll
            for (int m = 0; m < 4; ++m)
                af[m] = __builtin_bit_cast(bfx8, *(const s16x8*)(As + a_off[m][h]));
#pragma unroll
            for (int n = 0; n < 4; ++n)
                bv[n] = __builtin_bit_cast(bfx8, *(const s16x8*)(Bs + b_off[n][h]));
#pragma unroll
            for (int m = 0; m < 4; ++m)
#pragma unroll
                for (int n = 0; n < 4; ++n)
                    acc[m][n] = __builtin_amdgcn_mfma_f32_16x16x32_bf16(af[m], bv[n], acc[m][n], 0, 0, 0);
        }
        __syncthreads();
    }
#pragma unroll
    for (int n = 0; n < 4; ++n) {
        int nc = n0 + Wc + n * 16 + (l & 15);
        float bs = bias[nc];
        double s = 0.0, q = 0.0;
#pragma unroll
        for (int m = 0; m < 4; ++m) {
            int rbase = m0 + Wr + m * 16 + ((l >> 4) << 2);
#pragma unroll
            for (int i = 0; i < 4; ++i) {
                float v = acc[m][n][i] + bs;
                C[(size_t)(rbase + i) * N + nc] = f2bf(v);
                s += (double)v;
                q += (double)v * (double)v;
            }
        }
        s += __shfl_xor(s, 16, 64); s += __shfl_xor(s, 32, 64);
        q += __shfl_xor(q, 16, 64); q += __shfl_xor(q, 32, 64);
        if ((l >> 4) == 0) {
            atomicAdd(&stats[nc], s);
            atomicAdd(&stats[N + nc], q);
        }
    }
}

// ---------------- bf16 MFMA GEMM with fused input-BN+ReLU on A (layers 2,3) ----------------
__launch_bounds__(256)
__global__ void k_mfma_gemm_bn(const unsigned short* __restrict__ A,   // M x K bf16 raw
                               const double* __restrict__ statsIn,     // 2*K (A's BN stats)
                               const float* __restrict__ g, const float* __restrict__ be,
                               const unsigned short* __restrict__ Bt,  // N x K bf16
                               const float* __restrict__ bias,
                               unsigned short* __restrict__ C,         // M x N bf16
                               double* __restrict__ stats,             // 2*N fp64
                               int M, int K, int N, int lognx) {
    __shared__ char lds[40960];
    char* As = lds;
    char* Bs = lds + 16384;
    float* scs = (float*)(lds + 32768);   // K floats
    float* shs = scs + K;                 // K floats (K<=1024 -> fits 8KB)
    const int t = threadIdx.x;
    const int l = t & 63;
    const int w = t >> 6;
    int bx, by;
    xcd_map(blockIdx.x, lognx, bx, by);
    const int m0 = by * 128, n0 = bx * 128;
    const int Wr = (w >> 1) * 64, Wc = (w & 1) * 64;

    constexpr double inv_bb = 1.0 / (double)BB;
    for (int c = t; c < K; c += 256) {
        double mu = statsIn[c] * inv_bb;
        double var = statsIn[K + c] * inv_bb - mu * mu;
        float sc = g[c] / sqrtf((float)var + EPS_);
        scs[c] = sc;
        shs[c] = be[c] - (float)mu * sc;
    }
    __syncthreads();

    const int srow = t >> 3;            // 0..31
    const int sswz = (t & 7) ^ (srow & 7);
    const unsigned short* ga[4];
    const unsigned short* gb[4];
#pragma unroll
    for (int i = 0; i < 4; ++i) {
        ga[i] = A + (size_t)(m0 + i * 32 + srow) * K + sswz * 8;
        gb[i] = Bt + (size_t)(n0 + i * 32 + srow) * K + sswz * 8;
    }
    int a_off[4][2], b_off[4][2];
#pragma unroll
    for (int m = 0; m < 4; ++m) {
#pragma unroll
        for (int h = 0; h < 2; ++h) {
            int r = Wr + m * 16 + (l & 15);
            a_off[m][h] = r * 128 + (((h * 4 + (l >> 4)) ^ (r & 7)) << 4);
            int c = Wc + m * 16 + (l & 15);
            b_off[m][h] = c * 128 + (((h * 4 + (l >> 4)) ^ (c & 7)) << 4);
        }
    }
    f32x4 acc[4][4] = {};
    for (int k0 = 0; k0 < K; k0 += 64) {
#pragma unroll
        for (int i = 0; i < 4; ++i) {
            __builtin_amdgcn_global_load_lds(
                (const __attribute__((address_space(1))) void*)gb[i],
                (__attribute__((address_space(3))) void*)(Bs + i * 4096 + t * 16), 16, 0, 0);
            gb[i] += 64;
        }
        {
            int kb = k0 + sswz * 8;
            float4 sc0 = *(const float4*)&scs[kb];
            float4 sc1 = *(const float4*)&scs[kb + 4];
            float4 sh0 = *(const float4*)&shs[kb];
            float4 sh1 = *(const float4*)&shs[kb + 4];
            float scl[8] = {sc0.x, sc0.y, sc0.z, sc0.w, sc1.x, sc1.y, sc1.z, sc1.w};
            float shl[8] = {sh0.x, sh0.y, sh0.z, sh0.w, sh1.x, sh1.y, sh1.z, sh1.w};
#pragma unroll
            for (int i = 0; i < 4; ++i) {
                union { s16x8 v; unsigned short u[8]; } pin, pout;
                pin.v = *(const s16x8*)ga[i];
#pragma unroll
                for (int j = 0; j < 8; ++j)
                    pout.u[j] = f2bf(fmaxf(fmaf(bf2f(pin.u[j]), scl[j], shl[j]), 0.f));
                *(s16x8*)(As + i * 4096 + t * 16) = pout.v;
                ga[i] += 64;
            }
        }
        __syncthreads();
#pragma unroll
        for (int h = 0; h < 2; ++h) {
            bfx8 af[4], bv[4];
#pragma unroll
            for (int m = 0; m < 4; ++m)
                af[m] = __builtin_bit_cast(bfx8, *(const s16x8*)(As + a_off[m][h]));
#pragma unroll
            for (int n = 0; n < 4; ++n)
                bv[n] = __builtin_bit_cast(bfx8, *(const s16x8*)(Bs + b_off[n][h]));
#pragma unroll
            for (int m = 0; m < 4; ++m)
#pragma unroll
                for (int n = 0; n < 4; ++n)
                    acc[m][n] = __builtin_amdgcn_mfma_f32_16x16x32_bf16(af[m], bv[n], acc[m][n], 0, 0, 0);
        }
        __syncthreads();
    }
#pragma unroll
    for (int n = 0; n < 4; ++n) {
        int nc = n0 + Wc + n * 16 + (l & 15);
        float bs = bias[nc];
        double s = 0.0, q = 0.0;
#pragma unroll
        for (int m = 0; m < 4; ++m) {
            int rbase = m0 + Wr + m * 16 + ((l >> 4) << 2);
#pragma unroll
            for (int i = 0; i < 4; ++i) {
                float v = acc[m][n][i] + bs;
                C[(size_t)(rbase + i) * N + nc] = f2bf(v);
                s += (double)v;
                q += (double)v * (double)v;
            }
        }
        s += __shfl_xor(s, 16, 64); s += __shfl_xor(s, 32, 64);
        q += __shfl_xor(q, 16, 64); q += __shfl_xor(q, 32, 64);
        if ((l >> 4) == 0) {
            atomicAdd(&stats[nc], s);
            atomicAdd(&stats[N + nc], q);
        }
    }
}

// ---------------- final: bn3+ReLU on raw h3, dot w_out, + wide linear, sigmoid ----------------
__global__ void k_out(const unsigned short* __restrict__ h3, const double* __restrict__ stats3,
                      const float* __restrict__ g3, const float* __restrict__ be3,
                      const float* __restrict__ wo, const float* __restrict__ bo,
                      const int* __restrict__ x, const float* __restrict__ lt,
                      const float* __restrict__ lb, float* __restrict__ out) {
    __shared__ float scs[256], shs[256];
    int t = threadIdx.x;
    {
        constexpr double inv_bb = 1.0 / (double)BB;
        double mu = stats3[t] * inv_bb;
        double var = stats3[256 + t] * inv_bb - mu * mu;
        float sc = g3[t] / sqrtf((float)var + EPS_);
        scs[t] = sc;
        shs[t] = be3[t] - (float)mu * sc;
    }
    __syncthreads();
    int r = blockIdx.x * 4 + (t >> 6);
    int lane = t & 63;
    float s = 0.f;
#pragma unroll
    for (int k = lane; k < 256; k += 64) {
        float xv = bf2f(h3[(size_t)r * 256 + k]);
        float hb = bf2f(f2bf(fmaxf(fmaf(xv, scs[k], shs[k]), 0.f)));
        s += hb * wo[k];
    }
    if (lane < NF) {
        long long id = (long long)x[r * NF + lane] + (long long)lane * FIELD_DIM;
        s += lt[id];
    }
#pragma unroll
    for (int off = 32; off > 0; off >>= 1) s += __shfl_xor(s, off, 64);
    if (lane == 0) {
        float tt = s + bo[0] + lb[0];
        out[r] = 1.f / (1.f + expf(-tt));
    }
}

extern "C" void kernel_launch(void* const* d_in, const int* in_sizes, int n_in,
                              void* d_out, int out_size, void* d_ws, size_t ws_size,
                              hipStream_t stream) {
    const int* x = (const int*)d_in[0];
    const float* emb = (const float*)d_in[1];
    const float* lint = (const float*)d_in[2];
    const float* linb = (const float*)d_in[3];
    const float* bng = (const float*)d_in[4];
    const float* bnb = (const float*)d_in[5];
    const float* cw = (const float*)d_in[6];
    const float* cb = (const float*)d_in[7];
    const float* cbg = (const float*)d_in[8];
    const float* cbb = (const float*)d_in[9];
    const float* w1 = (const float*)d_in[10];
    const float* b1 = (const float*)d_in[11];
    const float* g1 = (const float*)d_in[12];
    const float* be1 = (const float*)d_in[13];
    const float* w2 = (const float*)d_in[14];
    const float* b2 = (const float*)d_in[15];
    const float* g2 = (const float*)d_in[16];
    const float* be2 = (const float*)d_in[17];
    const float* w3 = (const float*)d_in[18];
    const float* b3 = (const float*)d_in[19];
    const float* g3 = (const float*)d_in[20];
    const float* be3 = (const float*)d_in[21];
    const float* wo = (const float*)d_in[22];
    const float* bo = (const float*)d_in[23];
    const int* kptr = (const int*)d_in[24];
    float* out = (float*)d_out;

    char* p = (char*)d_ws;
    float* flat = (float*)p;                 p += (size_t)BB * ND * 4;      // fp32, ctrl path
    unsigned short* flatg = (unsigned short*)p; p += (size_t)BB * 640 * 2;  // gated bf16, K-padded
    unsigned short* h1 = (unsigned short*)p; p += (size_t)BB * 1024 * 2;    // raw (pre-BN)
    unsigned short* h2 = (unsigned short*)p; p += (size_t)BB * 512 * 2;     // raw
    unsigned short* h3 = (unsigned short*)p; p += (size_t)BB * 256 * 2;     // raw
    unsigned short* w1t = (unsigned short*)p; p += (size_t)1024 * 640 * 2;
    unsigned short* w2t = (unsigned short*)p; p += (size_t)512 * 1024 * 2;
    unsigned short* w3t = (unsigned short*)p; p += (size_t)256 * 512 * 2;
    float* wct = (float*)p;                  p += (size_t)48 * ND * 4;      // ctrl w transposed fp32
    float* zc = (float*)p;                   p += (size_t)BB * NF * 4;
    double* zp = (double*)p;                 p += (size_t)2 * BB * NF * 8;  // split-K partials fp64
    // disjoint per-layer fp64 stat regions, zeroed inside k_prep
    double* stats_all = (double*)p;
    double* stats_f = stats_all;             // 2*39
    double* stats_c = stats_f + 2 * NF;      // 2*39
    double* stats_1 = stats_c + 2 * NF;      // 2*1024
    double* stats_2 = stats_1 + 2 * 1024;    // 2*512
    double* stats_3 = stats_2 + 2 * 512;     // 2*256
    int stats_doubles = 2 * (NF + NF + 1024 + 512 + 256); // 3662

    // ---- prep: tiled weight transposes + stats zero (one kernel, 1412 blocks) ----
    k_prep<<<1412, 256, 0, stream>>>(w1, w2, w3, cw, w1t, w2t, w3t, wct,
                                     stats_all, stats_doubles);

    // ---- field BN (finalize fused into flat_norm) ----
    k_field_stats<<<dim3(NF, BB / 256), 256, 0, stream>>>(x, emb, stats_f);
    k_flat_norm<<<(BB * NF + 255) / 256, 256, 0, stream>>>(x, emb, stats_f, bng, bnb, flat);

    // ---- controller: split-K GEMM (2 blocks/CU) + reduce/stats + fused finalize/topk/gate ----
    k_ctrl_gemm_sk<<<512, 256, 0, stream>>>(flat, wct, zp);
    k_ctrl_reduce<<<BB / 64, 256, 0, stream>>>(zp, cb, zc, stats_c);
    k_topk_gate<<<BB / 4, 256, 0, stream>>>(zc, stats_c, cbg, cbb, kptr, flat, flatg);

    // ---- MLP layer 1: 640(pad) -> 1024 (h1 raw), XCD-swizzled 1D grid ----
    k_mfma_gemm<<<(1024 / 128) * (BB / 128), 256, 0, stream>>>(flatg, w1t, b1, h1, stats_1,
                                                               BB, 640, 1024, 3);

    // ---- MLP layer 2: BN1+ReLU fused into A-staging; 1024 -> 512 (h2 raw) ----
    k_mfma_gemm_bn<<<(512 / 128) * (BB / 128), 256, 0, stream>>>(h1, stats_1, g1, be1,
                                                                 w2t, b2, h2, stats_2,
                                                                 BB, 1024, 512, 2);

    // ---- MLP layer 3: BN2+ReLU fused; 512 -> 256 (h3 raw) ----
    k_mfma_gemm_bn<<<(256 / 128) * (BB / 128), 256, 0, stream>>>(h2, stats_2, g2, be2,
                                                                 w3t, b3, h3, stats_3,
                                                                 BB, 512, 256, 1);

    // ---- output: BN3+ReLU + dot w_out + wide linear + sigmoid ----
    k_out<<<BB / 4, 256, 0, stream>>>(h3, stats_3, g3, be3, wo, bo, x, lint, linb, out);
}

// Round 13
// 226.994 us; speedup vs baseline: 1.5124x; 1.0255x over previous
//
#include <hip/hip_runtime.h>
#include <math.h>
#include <stdint.h>

constexpr int BB = 16384;   // batch
constexpr int NF = 39;      // fields
constexpr int NE = 16;      // embed dim
constexpr int ND = NF * NE; // 624
constexpr int FIELD_DIM = 26000;
constexpr float EPS_ = 1e-5f;

typedef __bf16 bfx8 __attribute__((ext_vector_type(8)));
typedef float f32x4 __attribute__((ext_vector_type(4)));
typedef short s16x8 __attribute__((ext_vector_type(8)));

static __device__ __forceinline__ unsigned short f2bf(float f) {
    union { float f; unsigned u; } a; a.f = f;
    unsigned r = a.u + 0x7fffu + ((a.u >> 16) & 1u); // RNE
    return (unsigned short)(r >> 16);
}
static __device__ __forceinline__ float bf2f(unsigned short u) {
    union { unsigned u; float f; } a; a.u = ((unsigned)u) << 16;
    return a.f;
}

// XCD-aware block remap: l -> (bx, by). ny must be 128 (=8 XCDs * 16 panels).
static __device__ __forceinline__ void xcd_map(int l, int lognx, int& bx, int& by) {
    int s = l >> 3;
    bx = s & ((1 << lognx) - 1);
    by = ((l & 7) << 4) + (s >> lognx);
}

// ---------------- fused prep: LDS-tiled weight transposes + ctrl transpose + stats zero --------
__global__ void k_prep(const float* __restrict__ w1, const float* __restrict__ w2,
                       const float* __restrict__ w3, const float* __restrict__ cw,
                       unsigned short* __restrict__ w1t, unsigned short* __restrict__ w2t,
                       unsigned short* __restrict__ w3t, float* __restrict__ wct,
                       double* __restrict__ stats, int nstats) {
    int b = blockIdx.x;
    if (b < 1280) {
        const float* in; unsigned short* outp; int K, N, Kpad, tid;
        if (b < 640)        { in = w1; outp = w1t; K = 624;  N = 1024; Kpad = 640;  tid = b; }
        else if (b < 1152)  { in = w2; outp = w2t; K = 1024; N = 512;  Kpad = 1024; tid = b - 640; }
        else                { in = w3; outp = w3t; K = 512;  N = 256;  Kpad = 512;  tid = b - 1152; }
        int tiles_n = N >> 5;
        int tk = tid / tiles_n, tn = tid % tiles_n;
        __shared__ float tile[32][33];
        int tx = threadIdx.x & 31, ty = threadIdx.x >> 5;  // 32 x 8
#pragma unroll
        for (int i = 0; i < 4; ++i) {
            int k = tk * 32 + ty + i * 8, n = tn * 32 + tx;
            tile[ty + i * 8][tx] = (k < K) ? in[(size_t)k * N + n] : 0.f;
        }
        __syncthreads();
#pragma unroll
        for (int i = 0; i < 4; ++i) {
            int n = tn * 32 + ty + i * 8, k = tk * 32 + tx;
            outp[(size_t)n * Kpad + k] = f2bf(tile[tx][ty + i * 8]);
        }
    } else if (b < 1397) {                // wct: (48, 624) fp32, rows>=39 zero
        int gid = (b - 1280) * 256 + threadIdx.x;
        if (gid < 48 * ND) {
            int j = gid / ND, k = gid % ND;
            wct[gid] = (j < NF) ? cw[(size_t)k * NF + j] : 0.f;
        }
    } else {                              // zero fp64 stats
        int gid = (b - 1397) * 256 + threadIdx.x;
        if (gid < nstats) stats[gid] = 0.0;
    }
}

// ---------------- field BN stats: sum/sumsq per field over (B, E), fp64 atomics ----------------
__global__ void k_field_stats(const int* __restrict__ x, const float* __restrict__ emb,
                              double* __restrict__ stats /* 2*NF */) {
    int f = blockIdx.x;
    int r = blockIdx.y * blockDim.x + threadIdx.x;
    double s = 0.0, q = 0.0;
    if (r < BB) {
        long long id = (long long)x[r * NF + f] + (long long)f * FIELD_DIM;
        const float4* p = (const float4*)(emb + id * NE);
#pragma unroll
        for (int i = 0; i < 4; ++i) {
            float4 v = p[i];
            s += (double)v.x; s += (double)v.y; s += (double)v.z; s += (double)v.w;
            q += (double)v.x * v.x; q += (double)v.y * v.y;
            q += (double)v.z * v.z; q += (double)v.w * v.w;
        }
    }
    __shared__ double ls[256], lq[256];
    ls[threadIdx.x] = s; lq[threadIdx.x] = q;
    __syncthreads();
    for (int off = 128; off > 0; off >>= 1) {
        if ((int)threadIdx.x < off) {
            ls[threadIdx.x] += ls[threadIdx.x + off];
            lq[threadIdx.x] += lq[threadIdx.x + off];
        }
        __syncthreads();
    }
    if (threadIdx.x == 0) {
        atomicAdd(&stats[f], ls[0]);
        atomicAdd(&stats[NF + f], lq[0]);
    }
}

// ---------------- gather + normalize -> flat (B, 624) fp32; field-BN finalize fused ----------------
__global__ void k_flat_norm(const int* __restrict__ x, const float* __restrict__ emb,
                            const double* __restrict__ stats, const float* __restrict__ bng,
                            const float* __restrict__ bnb, float* __restrict__ flat) {
    __shared__ float sc_s[NF], sh_s[NF];
    if ((int)threadIdx.x < NF) {
        int f = threadIdx.x;
        double cnt = (double)BB * NE;
        double mu = stats[f] / cnt;
        double var = stats[NF + f] / cnt - mu * mu;
        float sc = (float)((double)bng[f] / sqrt(var + (double)EPS_));
        sc_s[f] = sc;
        sh_s[f] = bnb[f] - (float)mu * sc;
    }
    __syncthreads();
    int gid = blockIdx.x * blockDim.x + threadIdx.x; // r*NF + f
    if (gid >= BB * NF) return;
    int f = gid % NF;
    long long id = (long long)x[gid] + (long long)f * FIELD_DIM;
    float sc = sc_s[f], sh = sh_s[f];
    const float4* p = (const float4*)(emb + id * NE);
    float4* o = (float4*)(flat) + (size_t)gid * 4;
#pragma unroll
    for (int i = 0; i < 4; ++i) {
        float4 v = p[i];
        o[i] = make_float4(fmaf(v.x, sc, sh), fmaf(v.y, sc, sh),
                           fmaf(v.z, sc, sh), fmaf(v.w, sc, sh));
    }
}

// ---------------- controller GEMM split-K: round-5 body, K halves [0,320) / [320,624) ----------
__launch_bounds__(256)
__global__ void k_ctrl_gemm_sk(const float* __restrict__ flat, const float* __restrict__ wct,
                               double* __restrict__ zp) {
    __shared__ float As[64][68];       // [row][kk], padded
    __shared__ float Ws[64][49];       // [kk][col]
    const int t = threadIdx.x;
    const int tn = t & 15;             // col group: cols 3tn..3tn+2
    const int tm = t >> 4;             // row group: rows 4tm..4tm+3
    const int bm = blockIdx.x & 255;
    const int half = blockIdx.x >> 8;
    const int m0 = bm * 64;
    const int kbeg = half ? 320 : 0;
    const int kend = half ? 624 : 320;
    double acc[4][3] = {};
    for (int k0 = kbeg; k0 < kend; k0 += 64) {
        const int kl = (kend - k0 >= 64) ? 64 : (kend - k0);   // 64 or 48
        const int kl4 = kl >> 2;
#pragma unroll
        for (int i = 0; i < 4; ++i) {
            int idx = t + 256 * i;     // 0..1023
            int row = idx >> 4, c4 = idx & 15;
            if (c4 < kl4) {
                float4 v = *(const float4*)(flat + (size_t)(m0 + row) * ND + k0 + c4 * 4);
                *(float4*)&As[row][c4 * 4] = v;
            }
        }
        {
            int col = t >> 4;          // 0..15
            int c4 = t & 15;
#pragma unroll
            for (int cp = 0; cp < 3; ++cp, col += 16) {
                if (c4 < kl4) {
                    float4 v = *(const float4*)(wct + (size_t)col * ND + k0 + c4 * 4);
                    Ws[c4 * 4 + 0][col] = v.x; Ws[c4 * 4 + 1][col] = v.y;
                    Ws[c4 * 4 + 2][col] = v.z; Ws[c4 * 4 + 3][col] = v.w;
                }
            }
        }
        __syncthreads();
#pragma unroll 4
        for (int kk = 0; kk < kl; ++kk) {
            double a0 = (double)As[4 * tm + 0][kk];
            double a1 = (double)As[4 * tm + 1][kk];
            double a2 = (double)As[4 * tm + 2][kk];
            double a3 = (double)As[4 * tm + 3][kk];
            double w0 = (double)Ws[kk][3 * tn + 0];
            double w1 = (double)Ws[kk][3 * tn + 1];
            double w2 = (double)Ws[kk][3 * tn + 2];
            acc[0][0] += a0 * w0; acc[0][1] += a0 * w1; acc[0][2] += a0 * w2;
            acc[1][0] += a1 * w0; acc[1][1] += a1 * w1; acc[1][2] += a1 * w2;
            acc[2][0] += a2 * w0; acc[2][1] += a2 * w1; acc[2][2] += a2 * w2;
            acc[3][0] += a3 * w0; acc[3][1] += a3 * w1; acc[3][2] += a3 * w2;
        }
        __syncthreads();
    }
    double* zph = zp + (size_t)half * BB * NF;
#pragma unroll
    for (int j = 0; j < 3; ++j) {
        int col = 3 * tn + j;
        if (col < NF) {
#pragma unroll
            for (int i = 0; i < 4; ++i)
                zph[(size_t)(m0 + 4 * tm + i) * NF + col] = acc[i][j];
        }
    }
}

// ---------------- split-K reduce: z = (float)(p0+p1+bias), fused col stats ----------------
__global__ void k_ctrl_reduce(const double* __restrict__ zp, const float* __restrict__ bias,
                              float* __restrict__ z, double* __restrict__ stats) {
    __shared__ double Sred[2][16][48];
    const int t = threadIdx.x;
    const int tn = t & 15;
    const int tm = t >> 4;
    const int m0 = blockIdx.x * 64;
#pragma unroll
    for (int j = 0; j < 3; ++j) {
        int col = 3 * tn + j;
        double s = 0.0, q = 0.0;
        if (col < NF) {
            float bs = bias[col];
#pragma unroll
            for (int i = 0; i < 4; ++i) {
                size_t idx = (size_t)(m0 + 4 * tm + i) * NF + col;
                double p01 = zp[idx] + zp[(size_t)BB * NF + idx];
                float v = (float)(p01 + (double)bs);
                z[idx] = v;
                s += (double)v;
                q += (double)v * (double)v;
            }
        }
        Sred[0][tm][col] = s;
        Sred[1][tm][col] = q;
    }
    __syncthreads();
    if (t < NF) {
        double ts = 0.0, tq = 0.0;
#pragma unroll
        for (int i = 0; i < 16; ++i) { ts += Sred[0][i][t]; tq += Sred[1][i][t]; }
        atomicAdd(&stats[t], ts);
        atomicAdd(&stats[NF + t], tq);
    }
}

// ---------------- ctrl-BN finalize + BN+ReLU + RANK-BASED top-k + gate -> flatg (fused) --------
__global__ void k_topk_gate(const float* __restrict__ zc, const double* __restrict__ stats,
                            const float* __restrict__ cbg, const float* __restrict__ cbb,
                            const int* __restrict__ kptr, const float* __restrict__ flat,
                            unsigned short* __restrict__ flatg) {
    __shared__ float sc_s[NF], sh_s[NF];
    int t = threadIdx.x;
    if (t < NF) {
        double mu = stats[t] / (double)BB;
        double var = stats[NF + t] / (double)BB - mu * mu;
        float sc = (float)((double)cbg[t] / sqrt(var + (double)EPS_));
        sc_s[t] = sc;
        sh_s[t] = cbb[t] - (float)mu * sc;
    }
    __syncthreads();
    int r = blockIdx.x * 4 + (t >> 6);
    int lane = t & 63;
    int k = kptr[0];
    bool active = (lane < NF);
    float w = -1.f;
    if (active) {
        float v = zc[(size_t)r * NF + lane];
        w = fmaxf(fmaf(v, sc_s[lane], sh_s[lane]), 0.f);
    }
    int rank = 0;
#pragma unroll
    for (int j = 0; j < NF; ++j) {
        float vj = __shfl(w, j, 64);
        rank += (vj > w || (vj == w && j < lane)) ? 1 : 0;
    }
    bool sel = active && (rank < k);
    float val = sel ? w : 0.f;
    float sum = val;
#pragma unroll
    for (int off = 32; off > 0; off >>= 1) sum += __shfl_xor(sum, off, 64);
    if (active) {
        float ms = sel ? ((sum > 0.f) ? (w / sum) : 0.f) : 0.f;
        const float* src = flat + (size_t)r * ND + lane * 16;
        unsigned short* dst = flatg + (size_t)r * 640 + lane * 16;
#pragma unroll
        for (int h = 0; h < 2; ++h) {
            union { s16x8 v; unsigned short u[8]; } p;
#pragma unroll
            for (int j = 0; j < 8; ++j) p.u[j] = f2bf(src[h * 8 + j] * ms);
            *(s16x8*)(dst + h * 8) = p.v;
        }
    } else if (lane == NF) {
        s16x8 zv = {};
        *(s16x8*)(flatg + (size_t)r * 640 + 624) = zv;
        *(s16x8*)(flatg + (size_t)r * 640 + 632) = zv;
    }
}

// ---------------- bf16 MFMA GEMM (layer 1): C = A @ Bt^T + bias, fused col stats ----------------
__launch_bounds__(256)
__global__ void k_mfma_gemm(const unsigned short* __restrict__ A,  // M x K bf16
                            const unsigned short* __restrict__ Bt, // N x K bf16
                            const float* __restrict__ bias,
                            unsigned short* __restrict__ C,        // M x N bf16
                            double* __restrict__ stats,            // 2*N fp64
                            int M, int K, int N, int lognx) {
    __shared__ char lds[32768];
    char* As = lds;
    char* Bs = lds + 16384;
    const int t = threadIdx.x;
    const int l = t & 63;
    const int w = t >> 6;
    int bx, by;
    xcd_map(blockIdx.x, lognx, bx, by);
    const int m0 = by * 128, n0 = bx * 128;
    const int Wr = (w >> 1) * 64, Wc = (w & 1) * 64;

    const int srow = t >> 3;            // 0..31
    const int sswz = (t & 7) ^ (srow & 7);
    const unsigned short* ga[4];
    const unsigned short* gb[4];
#pragma unroll
    for (int i = 0; i < 4; ++i) {
        ga[i] = A + (size_t)(m0 + i * 32 + srow) * K + sswz * 8;
        gb[i] = Bt + (size_t)(n0 + i * 32 + srow) * K + sswz * 8;
    }
    int a_off[4][2], b_off[4][2];
#pragma unroll
    for (int m = 0; m < 4; ++m) {
#pragma unroll
        for (int h = 0; h < 2; ++h) {
            int r = Wr + m * 16 + (l & 15);
            a_off[m][h] = r * 128 + (((h * 4 + (l >> 4)) ^ (r & 7)) << 4);
            int c = Wc + m * 16 + (l & 15);
            b_off[m][h] = c * 128 + (((h * 4 + (l >> 4)) ^ (c & 7)) << 4);
        }
    }
    f32x4 acc[4][4] = {};
    for (int k0 = 0; k0 < K; k0 += 64) {
#pragma unroll
        for (int i = 0; i < 4; ++i) {
            __builtin_amdgcn_global_load_lds(
                (const __attribute__((address_space(1))) void*)ga[i],
                (__attribute__((address_space(3))) void*)(As + i * 4096 + t * 16), 16, 0, 0);
            __builtin_amdgcn_global_load_lds(
                (const __attribute__((address_space(1))) void*)gb[i],
                (__attribute__((address_space(3))) void*)(Bs + i * 4096 + t * 16), 16, 0, 0);
            ga[i] += 64; gb[i] += 64;
        }
        __syncthreads();
#pragma unroll
        for (int h = 0; h < 2; ++h) {
            bfx8 af[4], bv[4];
#pragma unroll
            for (int m = 0; m < 4; ++m)
                af[m] = __builtin_bit_cast(bfx8, *(const s16x8*)(As + a_off[m][h]));
#pragma unroll
            for (int n = 0; n < 4; ++n)
                bv[n] = __builtin_bit_cast(bfx8, *(const s16x8*)(Bs + b_off[n][h]));
#pragma unroll
            for (int m = 0; m < 4; ++m)
#pragma unroll
                for (int n = 0; n < 4; ++n)
                    acc[m][n] = __builtin_amdgcn_mfma_f32_16x16x32_bf16(af[m], bv[n], acc[m][n], 0, 0, 0);
        }
        __syncthreads();
    }
#pragma unroll
    for (int n = 0; n < 4; ++n) {
        int nc = n0 + Wc + n * 16 + (l & 15);
        float bs = bias[nc];
        double s = 0.0, q = 0.0;
#pragma unroll
        for (int m = 0; m < 4; ++m) {
            int rbase = m0 + Wr + m * 16 + ((l >> 4) << 2);
#pragma unroll
            for (int i = 0; i < 4; ++i) {
                float v = acc[m][n][i] + bs;
                C[(size_t)(rbase + i) * N + nc] = f2bf(v);
                s += (double)v;
                q += (double)v * (double)v;
            }
        }
        s += __shfl_xor(s, 16, 64); s += __shfl_xor(s, 32, 64);
        q += __shfl_xor(q, 16, 64); q += __shfl_xor(q, 32, 64);
        if ((l >> 4) == 0) {
            atomicAdd(&stats[nc], s);
            atomicAdd(&stats[N + nc], q);
        }
    }
}

// ---------------- bf16 MFMA GEMM with fused input-BN+ReLU on A (layers 2,3) ----------------
// v13: A raw regs prefetched 1 K-step ahead (latency hidden under MFMA phase);
//      bf16 pack via v_cvt_pk_bf16_f32 (RNE, bit-identical to manual f2bf for finite values).
__launch_bounds__(256)
__global__ void k_mfma_gemm_bn(const unsigned short* __restrict__ A,   // M x K bf16 raw
                               const double* __restrict__ statsIn,     // 2*K (A's BN stats)
                               const float* __restrict__ g, const float* __restrict__ be,
                               const unsigned short* __restrict__ Bt,  // N x K bf16
                               const float* __restrict__ bias,
                               unsigned short* __restrict__ C,         // M x N bf16
                               double* __restrict__ stats,             // 2*N fp64
                               int M, int K, int N, int lognx) {
    __shared__ char lds[40960];
    char* As = lds;
    char* Bs = lds + 16384;
    float* scs = (float*)(lds + 32768);   // K floats
    float* shs = scs + K;                 // K floats (K<=1024 -> fits 8KB)
    const int t = threadIdx.x;
    const int l = t & 63;
    const int w = t >> 6;
    int bx, by;
    xcd_map(blockIdx.x, lognx, bx, by);
    const int m0 = by * 128, n0 = bx * 128;
    const int Wr = (w >> 1) * 64, Wc = (w & 1) * 64;

    constexpr double inv_bb = 1.0 / (double)BB;
    for (int c = t; c < K; c += 256) {
        double mu = statsIn[c] * inv_bb;
        double var = statsIn[K + c] * inv_bb - mu * mu;
        float sc = g[c] / sqrtf((float)var + EPS_);
        scs[c] = sc;
        shs[c] = be[c] - (float)mu * sc;
    }
    __syncthreads();

    const int srow = t >> 3;            // 0..31
    const int sswz = (t & 7) ^ (srow & 7);
    const unsigned short* ga[4];
    const unsigned short* gb[4];
#pragma unroll
    for (int i = 0; i < 4; ++i) {
        ga[i] = A + (size_t)(m0 + i * 32 + srow) * K + sswz * 8;
        gb[i] = Bt + (size_t)(n0 + i * 32 + srow) * K + sswz * 8;
    }
    int a_off[4][2], b_off[4][2];
#pragma unroll
    for (int m = 0; m < 4; ++m) {
#pragma unroll
        for (int h = 0; h < 2; ++h) {
            int r = Wr + m * 16 + (l & 15);
            a_off[m][h] = r * 128 + (((h * 4 + (l >> 4)) ^ (r & 7)) << 4);
            int c = Wc + m * 16 + (l & 15);
            b_off[m][h] = c * 128 + (((h * 4 + (l >> 4)) ^ (c & 7)) << 4);
        }
    }
    f32x4 acc[4][4] = {};
    // prologue: prefetch raw A regs for k0 = 0
    s16x8 praw[4];
#pragma unroll
    for (int i = 0; i < 4; ++i) { praw[i] = *(const s16x8*)ga[i]; ga[i] += 64; }

    for (int k0 = 0; k0 < K; k0 += 64) {
        // B: async global->LDS
#pragma unroll
        for (int i = 0; i < 4; ++i) {
            __builtin_amdgcn_global_load_lds(
                (const __attribute__((address_space(1))) void*)gb[i],
                (__attribute__((address_space(3))) void*)(Bs + i * 4096 + t * 16), 16, 0, 0);
            gb[i] += 64;
        }
        // A: BN+ReLU transform of prefetched regs, packed bf16 store to swizzled LDS
        {
            int kb = k0 + sswz * 8;
            float4 sc0 = *(const float4*)&scs[kb];
            float4 sc1 = *(const float4*)&scs[kb + 4];
            float4 sh0 = *(const float4*)&shs[kb];
            float4 sh1 = *(const float4*)&shs[kb + 4];
            float scl[8] = {sc0.x, sc0.y, sc0.z, sc0.w, sc1.x, sc1.y, sc1.z, sc1.w};
            float shl[8] = {sh0.x, sh0.y, sh0.z, sh0.w, sh1.x, sh1.y, sh1.z, sh1.w};
#pragma unroll
            for (int i = 0; i < 4; ++i) {
                union { s16x8 v; unsigned short u[8]; } pin;
                pin.v = praw[i];
                float f[8];
#pragma unroll
                for (int j = 0; j < 8; ++j)
                    f[j] = fmaxf(fmaf(bf2f(pin.u[j]), scl[j], shl[j]), 0.f);
                union { unsigned w4[4]; s16x8 v; } pout;
#pragma unroll
                for (int j = 0; j < 4; ++j) {
                    unsigned rr;
                    asm("v_cvt_pk_bf16_f32 %0, %1, %2" : "=v"(rr) : "v"(f[2 * j]), "v"(f[2 * j + 1]));
                    pout.w4[j] = rr;
                }
                *(s16x8*)(As + i * 4096 + t * 16) = pout.v;
            }
        }
        // prefetch raw A regs for next K-step (latency hides under MFMA + barriers)
        if (k0 + 64 < K) {
#pragma unroll
            for (int i = 0; i < 4; ++i) { praw[i] = *(const s16x8*)ga[i]; ga[i] += 64; }
        }
        __syncthreads();
#pragma unroll
        for (int h = 0; h < 2; ++h) {
            bfx8 af[4], bv[4];
#pragma unroll
            for (int m = 0; m < 4; ++m)
                af[m] = __builtin_bit_cast(bfx8, *(const s16x8*)(As + a_off[m][h]));
#pragma unroll
            for (int n = 0; n < 4; ++n)
                bv[n] = __builtin_bit_cast(bfx8, *(const s16x8*)(Bs + b_off[n][h]));
#pragma unroll
            for (int m = 0; m < 4; ++m)
#pragma unroll
                for (int n = 0; n < 4; ++n)
                    acc[m][n] = __builtin_amdgcn_mfma_f32_16x16x32_bf16(af[m], bv[n], acc[m][n], 0, 0, 0);
        }
        __syncthreads();
    }
#pragma unroll
    for (int n = 0; n < 4; ++n) {
        int nc = n0 + Wc + n * 16 + (l & 15);
        float bs = bias[nc];
        double s = 0.0, q = 0.0;
#pragma unroll
        for (int m = 0; m < 4; ++m) {
            int rbase = m0 + Wr + m * 16 + ((l >> 4) << 2);
#pragma unroll
            for (int i = 0; i < 4; ++i) {
                float v = acc[m][n][i] + bs;
                C[(size_t)(rbase + i) * N + nc] = f2bf(v);
                s += (double)v;
                q += (double)v * (double)v;
            }
        }
        s += __shfl_xor(s, 16, 64); s += __shfl_xor(s, 32, 64);
        q += __shfl_xor(q, 16, 64); q += __shfl_xor(q, 32, 64);
        if ((l >> 4) == 0) {
            atomicAdd(&stats[nc], s);
            atomicAdd(&stats[N + nc], q);
        }
    }
}

// ---------------- final: bn3+ReLU on raw h3, dot w_out, + wide linear, sigmoid ----------------
__global__ void k_out(const unsigned short* __restrict__ h3, const double* __restrict__ stats3,
                      const float* __restrict__ g3, const float* __restrict__ be3,
                      const float* __restrict__ wo, const float* __restrict__ bo,
                      const int* __restrict__ x, const float* __restrict__ lt,
                      const float* __restrict__ lb, float* __restrict__ out) {
    __shared__ float scs[256], shs[256];
    int t = threadIdx.x;
    {
        constexpr double inv_bb = 1.0 / (double)BB;
        double mu = stats3[t] * inv_bb;
        double var = stats3[256 + t] * inv_bb - mu * mu;
        float sc = g3[t] / sqrtf((float)var + EPS_);
        scs[t] = sc;
        shs[t] = be3[t] - (float)mu * sc;
    }
    __syncthreads();
    int r = blockIdx.x * 4 + (t >> 6);
    int lane = t & 63;
    float s = 0.f;
#pragma unroll
    for (int k = lane; k < 256; k += 64) {
        float xv = bf2f(h3[(size_t)r * 256 + k]);
        float hb = bf2f(f2bf(fmaxf(fmaf(xv, scs[k], shs[k]), 0.f)));
        s += hb * wo[k];
    }
    if (lane < NF) {
        long long id = (long long)x[r * NF + lane] + (long long)lane * FIELD_DIM;
        s += lt[id];
    }
#pragma unroll
    for (int off = 32; off > 0; off >>= 1) s += __shfl_xor(s, off, 64);
    if (lane == 0) {
        float tt = s + bo[0] + lb[0];
        out[r] = 1.f / (1.f + expf(-tt));
    }
}

extern "C" void kernel_launch(void* const* d_in, const int* in_sizes, int n_in,
                              void* d_out, int out_size, void* d_ws, size_t ws_size,
                              hipStream_t stream) {
    const int* x = (const int*)d_in[0];
    const float* emb = (const float*)d_in[1];
    const float* lint = (const float*)d_in[2];
    const float* linb = (const float*)d_in[3];
    const float* bng = (const float*)d_in[4];
    const float* bnb = (const float*)d_in[5];
    const float* cw = (const float*)d_in[6];
    const float* cb = (const float*)d_in[7];
    const float* cbg = (const float*)d_in[8];
    const float* cbb = (const float*)d_in[9];
    const float* w1 = (const float*)d_in[10];
    const float* b1 = (const float*)d_in[11];
    const float* g1 = (const float*)d_in[12];
    const float* be1 = (const float*)d_in[13];
    const float* w2 = (const float*)d_in[14];
    const float* b2 = (const float*)d_in[15];
    const float* g2 = (const float*)d_in[16];
    const float* be2 = (const float*)d_in[17];
    const float* w3 = (const float*)d_in[18];
    const float* b3 = (const float*)d_in[19];
    const float* g3 = (const float*)d_in[20];
    const float* be3 = (const float*)d_in[21];
    const float* wo = (const float*)d_in[22];
    const float* bo = (const float*)d_in[23];
    const int* kptr = (const int*)d_in[24];
    float* out = (float*)d_out;

    char* p = (char*)d_ws;
    float* flat = (float*)p;                 p += (size_t)BB * ND * 4;      // fp32, ctrl path
    unsigned short* flatg = (unsigned short*)p; p += (size_t)BB * 640 * 2;  // gated bf16, K-padded
    unsigned short* h1 = (unsigned short*)p; p += (size_t)BB * 1024 * 2;    // raw (pre-BN)
    unsigned short* h2 = (unsigned short*)p; p += (size_t)BB * 512 * 2;     // raw
    unsigned short* h3 = (unsigned short*)p; p += (size_t)BB * 256 * 2;     // raw
    unsigned short* w1t = (unsigned short*)p; p += (size_t)1024 * 640 * 2;
    unsigned short* w2t = (unsigned short*)p; p += (size_t)512 * 1024 * 2;
    unsigned short* w3t = (unsigned short*)p; p += (size_t)256 * 512 * 2;
    float* wct = (float*)p;                  p += (size_t)48 * ND * 4;      // ctrl w transposed fp32
    float* zc = (float*)p;                   p += (size_t)BB * NF * 4;
    double* zp = (double*)p;                 p += (size_t)2 * BB * NF * 8;  // split-K partials fp64
    // disjoint per-layer fp64 stat regions, zeroed inside k_prep
    double* stats_all = (double*)p;
    double* stats_f = stats_all;             // 2*39
    double* stats_c = stats_f + 2 * NF;      // 2*39
    double* stats_1 = stats_c + 2 * NF;      // 2*1024
    double* stats_2 = stats_1 + 2 * 1024;    // 2*512
    double* stats_3 = stats_2 + 2 * 512;     // 2*256
    int stats_doubles = 2 * (NF + NF + 1024 + 512 + 256); // 3662

    // ---- prep: tiled weight transposes + stats zero (one kernel, 1412 blocks) ----
    k_prep<<<1412, 256, 0, stream>>>(w1, w2, w3, cw, w1t, w2t, w3t, wct,
                                     stats_all, stats_doubles);

    // ---- field BN (finalize fused into flat_norm) ----
    k_field_stats<<<dim3(NF, BB / 256), 256, 0, stream>>>(x, emb, stats_f);
    k_flat_norm<<<(BB * NF + 255) / 256, 256, 0, stream>>>(x, emb, stats_f, bng, bnb, flat);

    // ---- controller: split-K GEMM (2 blocks/CU) + reduce/stats + fused finalize/topk/gate ----
    k_ctrl_gemm_sk<<<512, 256, 0, stream>>>(flat, wct, zp);
    k_ctrl_reduce<<<BB / 64, 256, 0, stream>>>(zp, cb, zc, stats_c);
    k_topk_gate<<<BB / 4, 256, 0, stream>>>(zc, stats_c, cbg, cbb, kptr, flat, flatg);

    // ---- MLP layer 1: 640(pad) -> 1024 (h1 raw), XCD-swizzled 1D grid ----
    k_mfma_gemm<<<(1024 / 128) * (BB / 128), 256, 0, stream>>>(flatg, w1t, b1, h1, stats_1,
                                                               BB, 640, 1024, 3);

    // ---- MLP layer 2: BN1+ReLU fused into A-staging; 1024 -> 512 (h2 raw) ----
    k_mfma_gemm_bn<<<(512 / 128) * (BB / 128), 256, 0, stream>>>(h1, stats_1, g1, be1,
                                                                 w2t, b2, h2, stats_2,
                                                                 BB, 1024, 512, 2);

    // ---- MLP layer 3: BN2+ReLU fused; 512 -> 256 (h3 raw) ----
    k_mfma_gemm_bn<<<(256 / 128) * (BB / 128), 256, 0, stream>>>(h2, stats_2, g2, be2,
                                                                 w3t, b3, h3, stats_3,
                                                                 BB, 512, 256, 1);

    // ---- output: BN3+ReLU + dot w_out + wide linear + sigmoid ----
    k_out<<<BB / 4, 256, 0, stream>>>(h3, stats_3, g3, be3, wo, bo, x, lint, linb, out);
}

// Round 14
// 224.054 us; speedup vs baseline: 1.5323x; 1.0131x over previous
//
#include <hip/hip_runtime.h>
#include <math.h>
#include <stdint.h>

constexpr int BB = 16384;   // batch
constexpr int NF = 39;      // fields
constexpr int NE = 16;      // embed dim
constexpr int ND = NF * NE; // 624
constexpr int FIELD_DIM = 26000;
constexpr float EPS_ = 1e-5f;

typedef __bf16 bfx8 __attribute__((ext_vector_type(8)));
typedef float f32x4 __attribute__((ext_vector_type(4)));
typedef short s16x8 __attribute__((ext_vector_type(8)));

static __device__ __forceinline__ unsigned short f2bf(float f) {
    union { float f; unsigned u; } a; a.f = f;
    unsigned r = a.u + 0x7fffu + ((a.u >> 16) & 1u); // RNE
    return (unsigned short)(r >> 16);
}
static __device__ __forceinline__ float bf2f(unsigned short u) {
    union { unsigned u; float f; } a; a.u = ((unsigned)u) << 16;
    return a.f;
}

// XCD-aware block remap: l -> (bx, by). ny must be 128 (=8 XCDs * 16 panels).
static __device__ __forceinline__ void xcd_map(int l, int lognx, int& bx, int& by) {
    int s = l >> 3;
    bx = s & ((1 << lognx) - 1);
    by = ((l & 7) << 4) + (s >> lognx);
}

// ---------------- fused prep: LDS-tiled weight transposes + ctrl transpose + stats zero --------
__global__ void k_prep(const float* __restrict__ w1, const float* __restrict__ w2,
                       const float* __restrict__ w3, const float* __restrict__ cw,
                       unsigned short* __restrict__ w1t, unsigned short* __restrict__ w2t,
                       unsigned short* __restrict__ w3t, float* __restrict__ wct,
                       double* __restrict__ stats, int nstats) {
    int b = blockIdx.x;
    if (b < 1280) {
        const float* in; unsigned short* outp; int K, N, Kpad, tid;
        if (b < 640)        { in = w1; outp = w1t; K = 624;  N = 1024; Kpad = 640;  tid = b; }
        else if (b < 1152)  { in = w2; outp = w2t; K = 1024; N = 512;  Kpad = 1024; tid = b - 640; }
        else                { in = w3; outp = w3t; K = 512;  N = 256;  Kpad = 512;  tid = b - 1152; }
        int tiles_n = N >> 5;
        int tk = tid / tiles_n, tn = tid % tiles_n;
        __shared__ float tile[32][33];
        int tx = threadIdx.x & 31, ty = threadIdx.x >> 5;  // 32 x 8
#pragma unroll
        for (int i = 0; i < 4; ++i) {
            int k = tk * 32 + ty + i * 8, n = tn * 32 + tx;
            tile[ty + i * 8][tx] = (k < K) ? in[(size_t)k * N + n] : 0.f;
        }
        __syncthreads();
#pragma unroll
        for (int i = 0; i < 4; ++i) {
            int n = tn * 32 + ty + i * 8, k = tk * 32 + tx;
            outp[(size_t)n * Kpad + k] = f2bf(tile[tx][ty + i * 8]);
        }
    } else if (b < 1397) {                // wct: (48, 624) fp32, rows>=39 zero
        int gid = (b - 1280) * 256 + threadIdx.x;
        if (gid < 48 * ND) {
            int j = gid / ND, k = gid % ND;
            wct[gid] = (j < NF) ? cw[(size_t)k * NF + j] : 0.f;
        }
    } else {                              // zero fp64 stats
        int gid = (b - 1397) * 256 + threadIdx.x;
        if (gid < nstats) stats[gid] = 0.0;
    }
}

// ---------------- field BN stats: sum/sumsq per field over (B, E), fp64 atomics ----------------
__global__ void k_field_stats(const int* __restrict__ x, const float* __restrict__ emb,
                              double* __restrict__ stats /* 2*NF */) {
    int f = blockIdx.x;
    int r = blockIdx.y * blockDim.x + threadIdx.x;
    double s = 0.0, q = 0.0;
    if (r < BB) {
        long long id = (long long)x[r * NF + f] + (long long)f * FIELD_DIM;
        const float4* p = (const float4*)(emb + id * NE);
#pragma unroll
        for (int i = 0; i < 4; ++i) {
            float4 v = p[i];
            s += (double)v.x; s += (double)v.y; s += (double)v.z; s += (double)v.w;
            q += (double)v.x * v.x; q += (double)v.y * v.y;
            q += (double)v.z * v.z; q += (double)v.w * v.w;
        }
    }
    __shared__ double ls[256], lq[256];
    ls[threadIdx.x] = s; lq[threadIdx.x] = q;
    __syncthreads();
    for (int off = 128; off > 0; off >>= 1) {
        if ((int)threadIdx.x < off) {
            ls[threadIdx.x] += ls[threadIdx.x + off];
            lq[threadIdx.x] += lq[threadIdx.x + off];
        }
        __syncthreads();
    }
    if (threadIdx.x == 0) {
        atomicAdd(&stats[f], ls[0]);
        atomicAdd(&stats[NF + f], lq[0]);
    }
}

// ---------------- gather + normalize -> flat (B, 624) fp32; field-BN finalize fused ----------------
__global__ void k_flat_norm(const int* __restrict__ x, const float* __restrict__ emb,
                            const double* __restrict__ stats, const float* __restrict__ bng,
                            const float* __restrict__ bnb, float* __restrict__ flat) {
    __shared__ float sc_s[NF], sh_s[NF];
    if ((int)threadIdx.x < NF) {
        int f = threadIdx.x;
        double cnt = (double)BB * NE;
        double mu = stats[f] / cnt;
        double var = stats[NF + f] / cnt - mu * mu;
        float sc = (float)((double)bng[f] / sqrt(var + (double)EPS_));
        sc_s[f] = sc;
        sh_s[f] = bnb[f] - (float)mu * sc;
    }
    __syncthreads();
    int gid = blockIdx.x * blockDim.x + threadIdx.x; // r*NF + f
    if (gid >= BB * NF) return;
    int f = gid % NF;
    long long id = (long long)x[gid] + (long long)f * FIELD_DIM;
    float sc = sc_s[f], sh = sh_s[f];
    const float4* p = (const float4*)(emb + id * NE);
    float4* o = (float4*)(flat) + (size_t)gid * 4;
#pragma unroll
    for (int i = 0; i < 4; ++i) {
        float4 v = p[i];
        o[i] = make_float4(fmaf(v.x, sc, sh), fmaf(v.y, sc, sh),
                           fmaf(v.z, sc, sh), fmaf(v.w, sc, sh));
    }
}

// ---------------- controller GEMM split-K: round-5 body, K halves [0,320) / [320,624) ----------
__launch_bounds__(256)
__global__ void k_ctrl_gemm_sk(const float* __restrict__ flat, const float* __restrict__ wct,
                               double* __restrict__ zp) {
    __shared__ float As[64][68];       // [row][kk], padded
    __shared__ float Ws[64][49];       // [kk][col]
    const int t = threadIdx.x;
    const int tn = t & 15;             // col group: cols 3tn..3tn+2
    const int tm = t >> 4;             // row group: rows 4tm..4tm+3
    const int bm = blockIdx.x & 255;
    const int half = blockIdx.x >> 8;
    const int m0 = bm * 64;
    const int kbeg = half ? 320 : 0;
    const int kend = half ? 624 : 320;
    double acc[4][3] = {};
    for (int k0 = kbeg; k0 < kend; k0 += 64) {
        const int kl = (kend - k0 >= 64) ? 64 : (kend - k0);   // 64 or 48
        const int kl4 = kl >> 2;
#pragma unroll
        for (int i = 0; i < 4; ++i) {
            int idx = t + 256 * i;     // 0..1023
            int row = idx >> 4, c4 = idx & 15;
            if (c4 < kl4) {
                float4 v = *(const float4*)(flat + (size_t)(m0 + row) * ND + k0 + c4 * 4);
                *(float4*)&As[row][c4 * 4] = v;
            }
        }
        {
            int col = t >> 4;          // 0..15
            int c4 = t & 15;
#pragma unroll
            for (int cp = 0; cp < 3; ++cp, col += 16) {
                if (c4 < kl4) {
                    float4 v = *(const float4*)(wct + (size_t)col * ND + k0 + c4 * 4);
                    Ws[c4 * 4 + 0][col] = v.x; Ws[c4 * 4 + 1][col] = v.y;
                    Ws[c4 * 4 + 2][col] = v.z; Ws[c4 * 4 + 3][col] = v.w;
                }
            }
        }
        __syncthreads();
#pragma unroll 4
        for (int kk = 0; kk < kl; ++kk) {
            double a0 = (double)As[4 * tm + 0][kk];
            double a1 = (double)As[4 * tm + 1][kk];
            double a2 = (double)As[4 * tm + 2][kk];
            double a3 = (double)As[4 * tm + 3][kk];
            double w0 = (double)Ws[kk][3 * tn + 0];
            double w1 = (double)Ws[kk][3 * tn + 1];
            double w2 = (double)Ws[kk][3 * tn + 2];
            acc[0][0] += a0 * w0; acc[0][1] += a0 * w1; acc[0][2] += a0 * w2;
            acc[1][0] += a1 * w0; acc[1][1] += a1 * w1; acc[1][2] += a1 * w2;
            acc[2][0] += a2 * w0; acc[2][1] += a2 * w1; acc[2][2] += a2 * w2;
            acc[3][0] += a3 * w0; acc[3][1] += a3 * w1; acc[3][2] += a3 * w2;
        }
        __syncthreads();
    }
    double* zph = zp + (size_t)half * BB * NF;
#pragma unroll
    for (int j = 0; j < 3; ++j) {
        int col = 3 * tn + j;
        if (col < NF) {
#pragma unroll
            for (int i = 0; i < 4; ++i)
                zph[(size_t)(m0 + 4 * tm + i) * NF + col] = acc[i][j];
        }
    }
}

// ---------------- split-K reduce: z = (float)(p0+p1+bias), fused col stats ----------------
__global__ void k_ctrl_reduce(const double* __restrict__ zp, const float* __restrict__ bias,
                              float* __restrict__ z, double* __restrict__ stats) {
    __shared__ double Sred[2][16][48];
    const int t = threadIdx.x;
    const int tn = t & 15;
    const int tm = t >> 4;
    const int m0 = blockIdx.x * 64;
#pragma unroll
    for (int j = 0; j < 3; ++j) {
        int col = 3 * tn + j;
        double s = 0.0, q = 0.0;
        if (col < NF) {
            float bs = bias[col];
#pragma unroll
            for (int i = 0; i < 4; ++i) {
                size_t idx = (size_t)(m0 + 4 * tm + i) * NF + col;
                double p01 = zp[idx] + zp[(size_t)BB * NF + idx];
                float v = (float)(p01 + (double)bs);
                z[idx] = v;
                s += (double)v;
                q += (double)v * (double)v;
            }
        }
        Sred[0][tm][col] = s;
        Sred[1][tm][col] = q;
    }
    __syncthreads();
    if (t < NF) {
        double ts = 0.0, tq = 0.0;
#pragma unroll
        for (int i = 0; i < 16; ++i) { ts += Sred[0][i][t]; tq += Sred[1][i][t]; }
        atomicAdd(&stats[t], ts);
        atomicAdd(&stats[NF + t], tq);
    }
}

// ---------------- ctrl-BN finalize + BN+ReLU + RANK-BASED top-k + gate -> flatg (fused) --------
__global__ void k_topk_gate(const float* __restrict__ zc, const double* __restrict__ stats,
                            const float* __restrict__ cbg, const float* __restrict__ cbb,
                            const int* __restrict__ kptr, const float* __restrict__ flat,
                            unsigned short* __restrict__ flatg) {
    __shared__ float sc_s[NF], sh_s[NF];
    int t = threadIdx.x;
    if (t < NF) {
        double mu = stats[t] / (double)BB;
        double var = stats[NF + t] / (double)BB - mu * mu;
        float sc = (float)((double)cbg[t] / sqrt(var + (double)EPS_));
        sc_s[t] = sc;
        sh_s[t] = cbb[t] - (float)mu * sc;
    }
    __syncthreads();
    int r = blockIdx.x * 4 + (t >> 6);
    int lane = t & 63;
    int k = kptr[0];
    bool active = (lane < NF);
    float w = -1.f;
    if (active) {
        float v = zc[(size_t)r * NF + lane];
        w = fmaxf(fmaf(v, sc_s[lane], sh_s[lane]), 0.f);
    }
    int rank = 0;
#pragma unroll
    for (int j = 0; j < NF; ++j) {
        float vj = __shfl(w, j, 64);
        rank += (vj > w || (vj == w && j < lane)) ? 1 : 0;
    }
    bool sel = active && (rank < k);
    float val = sel ? w : 0.f;
    float sum = val;
#pragma unroll
    for (int off = 32; off > 0; off >>= 1) sum += __shfl_xor(sum, off, 64);
    if (active) {
        float ms = sel ? ((sum > 0.f) ? (w / sum) : 0.f) : 0.f;
        const float* src = flat + (size_t)r * ND + lane * 16;
        unsigned short* dst = flatg + (size_t)r * 640 + lane * 16;
#pragma unroll
        for (int h = 0; h < 2; ++h) {
            union { s16x8 v; unsigned short u[8]; } p;
#pragma unroll
            for (int j = 0; j < 8; ++j) p.u[j] = f2bf(src[h * 8 + j] * ms);
            *(s16x8*)(dst + h * 8) = p.v;
        }
    } else if (lane == NF) {
        s16x8 zv = {};
        *(s16x8*)(flatg + (size_t)r * 640 + 624) = zv;
        *(s16x8*)(flatg + (size_t)r * 640 + 632) = zv;
    }
}

// ---------------- bf16 MFMA GEMM (layer 1): 2-phase double-buffered pipeline ----------------
// Per iter: issue gload_lds for tile t+1 into buf^1, compute tile t from buf, ONE barrier
// (its vmcnt(0) drain sits after the MFMAs -> load latency hides under compute).
__launch_bounds__(256)
__global__ void k_mfma_gemm(const unsigned short* __restrict__ A,  // M x K bf16
                            const unsigned short* __restrict__ Bt, // N x K bf16
                            const float* __restrict__ bias,
                            unsigned short* __restrict__ C,        // M x N bf16
                            double* __restrict__ stats,            // 2*N fp64
                            int M, int K, int N, int lognx) {
    __shared__ char lds[65536];   // A0 A1 B0 B1, 16KB each
    const int t = threadIdx.x;
    const int l = t & 63;
    const int w = t >> 6;
    int bx, by;
    xcd_map(blockIdx.x, lognx, bx, by);
    const int m0 = by * 128, n0 = bx * 128;
    const int Wr = (w >> 1) * 64, Wc = (w & 1) * 64;

    const int srow = t >> 3;            // 0..31
    const int sswz = (t & 7) ^ (srow & 7);
    const unsigned short* ga[4];
    const unsigned short* gb[4];
#pragma unroll
    for (int i = 0; i < 4; ++i) {
        ga[i] = A + (size_t)(m0 + i * 32 + srow) * K + sswz * 8;
        gb[i] = Bt + (size_t)(n0 + i * 32 + srow) * K + sswz * 8;
    }
    int a_off[4][2], b_off[4][2];
#pragma unroll
    for (int m = 0; m < 4; ++m) {
#pragma unroll
        for (int h = 0; h < 2; ++h) {
            int r = Wr + m * 16 + (l & 15);
            a_off[m][h] = r * 128 + (((h * 4 + (l >> 4)) ^ (r & 7)) << 4);
            int c = Wc + m * 16 + (l & 15);
            b_off[m][h] = c * 128 + (((h * 4 + (l >> 4)) ^ (c & 7)) << 4);
        }
    }
    const int nt = K >> 6;
    f32x4 acc[4][4] = {};
    // prologue: stage tile 0 into buffer 0
#pragma unroll
    for (int i = 0; i < 4; ++i) {
        __builtin_amdgcn_global_load_lds(
            (const __attribute__((address_space(1))) void*)ga[i],
            (__attribute__((address_space(3))) void*)(lds + i * 4096 + t * 16), 16, 0, 0);
        __builtin_amdgcn_global_load_lds(
            (const __attribute__((address_space(1))) void*)gb[i],
            (__attribute__((address_space(3))) void*)(lds + 32768 + i * 4096 + t * 16), 16, 0, 0);
        ga[i] += 64; gb[i] += 64;
    }
    __syncthreads();
    for (int ts = 0; ts < nt; ++ts) {
        const int cur = ts & 1;
        if (ts + 1 < nt) {
            char* An = lds + (cur ^ 1) * 16384;
            char* Bn = lds + 32768 + (cur ^ 1) * 16384;
#pragma unroll
            for (int i = 0; i < 4; ++i) {
                __builtin_amdgcn_global_load_lds(
                    (const __attribute__((address_space(1))) void*)ga[i],
                    (__attribute__((address_space(3))) void*)(An + i * 4096 + t * 16), 16, 0, 0);
                __builtin_amdgcn_global_load_lds(
                    (const __attribute__((address_space(1))) void*)gb[i],
                    (__attribute__((address_space(3))) void*)(Bn + i * 4096 + t * 16), 16, 0, 0);
                ga[i] += 64; gb[i] += 64;
            }
        }
        const char* Ac = lds + cur * 16384;
        const char* Bc = lds + 32768 + cur * 16384;
#pragma unroll
        for (int h = 0; h < 2; ++h) {
            bfx8 af[4], bv[4];
#pragma unroll
            for (int m = 0; m < 4; ++m)
                af[m] = __builtin_bit_cast(bfx8, *(const s16x8*)(Ac + a_off[m][h]));
#pragma unroll
            for (int n = 0; n < 4; ++n)
                bv[n] = __builtin_bit_cast(bfx8, *(const s16x8*)(Bc + b_off[n][h]));
#pragma unroll
            for (int m = 0; m < 4; ++m)
#pragma unroll
                for (int n = 0; n < 4; ++n)
                    acc[m][n] = __builtin_amdgcn_mfma_f32_16x16x32_bf16(af[m], bv[n], acc[m][n], 0, 0, 0);
        }
        __syncthreads();   // drains next-tile loads (overlapped with the MFMAs above)
    }
#pragma unroll
    for (int n = 0; n < 4; ++n) {
        int nc = n0 + Wc + n * 16 + (l & 15);
        float bs = bias[nc];
        double s = 0.0, q = 0.0;
#pragma unroll
        for (int m = 0; m < 4; ++m) {
            int rbase = m0 + Wr + m * 16 + ((l >> 4) << 2);
#pragma unroll
            for (int i = 0; i < 4; ++i) {
                float v = acc[m][n][i] + bs;
                C[(size_t)(rbase + i) * N + nc] = f2bf(v);
                s += (double)v;
                q += (double)v * (double)v;
            }
        }
        s += __shfl_xor(s, 16, 64); s += __shfl_xor(s, 32, 64);
        q += __shfl_xor(q, 16, 64); q += __shfl_xor(q, 32, 64);
        if ((l >> 4) == 0) {
            atomicAdd(&stats[nc], s);
            atomicAdd(&stats[N + nc], q);
        }
    }
}

// ---------------- bf16 MFMA GEMM with fused input-BN+ReLU on A (layers 2,3) ----------------
// 2-phase double-buffered: B gload_lds + A reg->BN->ds_write both target buf^1 for tile t+1
// while MFMAs consume buf; one barrier per iter. praw reg-prefetch runs one more step ahead.
__launch_bounds__(256)
__global__ void k_mfma_gemm_bn(const unsigned short* __restrict__ A,   // M x K bf16 raw
                               const double* __restrict__ statsIn,     // 2*K (A's BN stats)
                               const float* __restrict__ g, const float* __restrict__ be,
                               const unsigned short* __restrict__ Bt,  // N x K bf16
                               const float* __restrict__ bias,
                               unsigned short* __restrict__ C,         // M x N bf16
                               double* __restrict__ stats,             // 2*N fp64
                               int M, int K, int N, int lognx) {
    __shared__ char lds[73728];           // A0 A1 B0 B1 (16KB each) + scs/shs (8KB)
    float* scs = (float*)(lds + 65536);   // K floats
    float* shs = scs + K;                 // K floats (K<=1024)
    const int t = threadIdx.x;
    const int l = t & 63;
    const int w = t >> 6;
    int bx, by;
    xcd_map(blockIdx.x, lognx, bx, by);
    const int m0 = by * 128, n0 = bx * 128;
    const int Wr = (w >> 1) * 64, Wc = (w & 1) * 64;

    constexpr double inv_bb = 1.0 / (double)BB;
    for (int c = t; c < K; c += 256) {
        double mu = statsIn[c] * inv_bb;
        double var = statsIn[K + c] * inv_bb - mu * mu;
        float sc = g[c] / sqrtf((float)var + EPS_);
        scs[c] = sc;
        shs[c] = be[c] - (float)mu * sc;
    }
    __syncthreads();

    const int srow = t >> 3;            // 0..31
    const int sswz = (t & 7) ^ (srow & 7);
    const unsigned short* ga[4];
    const unsigned short* gb[4];
#pragma unroll
    for (int i = 0; i < 4; ++i) {
        ga[i] = A + (size_t)(m0 + i * 32 + srow) * K + sswz * 8;
        gb[i] = Bt + (size_t)(n0 + i * 32 + srow) * K + sswz * 8;
    }
    int a_off[4][2], b_off[4][2];
#pragma unroll
    for (int m = 0; m < 4; ++m) {
#pragma unroll
        for (int h = 0; h < 2; ++h) {
            int r = Wr + m * 16 + (l & 15);
            a_off[m][h] = r * 128 + (((h * 4 + (l >> 4)) ^ (r & 7)) << 4);
            int c = Wc + m * 16 + (l & 15);
            b_off[m][h] = c * 128 + (((h * 4 + (l >> 4)) ^ (c & 7)) << 4);
        }
    }
    const int nt = K >> 6;
    f32x4 acc[4][4] = {};
    s16x8 praw[4];

    // A BN transform + ds_write of prefetched regs into buffer `buf` for K-step base kb0
    auto write_a = [&](int buf, int kb0) {
        char* Ad = lds + buf * 16384;
        int kb = kb0 + sswz * 8;
        float4 sc0 = *(const float4*)&scs[kb];
        float4 sc1 = *(const float4*)&scs[kb + 4];
        float4 sh0 = *(const float4*)&shs[kb];
        float4 sh1 = *(const float4*)&shs[kb + 4];
        float scl[8] = {sc0.x, sc0.y, sc0.z, sc0.w, sc1.x, sc1.y, sc1.z, sc1.w};
        float shl[8] = {sh0.x, sh0.y, sh0.z, sh0.w, sh1.x, sh1.y, sh1.z, sh1.w};
#pragma unroll
        for (int i = 0; i < 4; ++i) {
            union { s16x8 v; unsigned short u[8]; } pin;
            pin.v = praw[i];
            float f[8];
#pragma unroll
            for (int j = 0; j < 8; ++j)
                f[j] = fmaxf(fmaf(bf2f(pin.u[j]), scl[j], shl[j]), 0.f);
            union { unsigned w4[4]; s16x8 v; } pout;
#pragma unroll
            for (int j = 0; j < 4; ++j) {
                unsigned rr;
                asm("v_cvt_pk_bf16_f32 %0, %1, %2" : "=v"(rr) : "v"(f[2 * j]), "v"(f[2 * j + 1]));
                pout.w4[j] = rr;
            }
            *(s16x8*)(Ad + i * 4096 + t * 16) = pout.v;
        }
    };
    auto load_praw = [&]() {
#pragma unroll
        for (int i = 0; i < 4; ++i) { praw[i] = *(const s16x8*)ga[i]; ga[i] += 64; }
    };
    auto stage_b = [&](int buf) {
        char* Bd = lds + 32768 + buf * 16384;
#pragma unroll
        for (int i = 0; i < 4; ++i) {
            __builtin_amdgcn_global_load_lds(
                (const __attribute__((address_space(1))) void*)gb[i],
                (__attribute__((address_space(3))) void*)(Bd + i * 4096 + t * 16), 16, 0, 0);
            gb[i] += 64;
        }
    };

    // prologue: tile 0 into buffer 0; prefetch praw for tile 1
    load_praw();                 // praw = A(0)
    stage_b(0);                  // B(0) -> B0
    write_a(0, 0);               // A(0) -> A0
    if (nt > 1) load_praw();     // praw = A(1)
    __syncthreads();

    for (int ts = 0; ts < nt; ++ts) {
        const int cur = ts & 1;
        if (ts + 1 < nt) {
            stage_b(cur ^ 1);                    // B(t+1) -> other buffer
            write_a(cur ^ 1, (ts + 1) << 6);     // A(t+1) from praw -> other buffer
            if (ts + 2 < nt) load_praw();        // praw = A(t+2)
        }
        const char* Ac = lds + cur * 16384;
        const char* Bc = lds + 32768 + cur * 16384;
#pragma unroll
        for (int h = 0; h < 2; ++h) {
            bfx8 af[4], bv[4];
#pragma unroll
            for (int m = 0; m < 4; ++m)
                af[m] = __builtin_bit_cast(bfx8, *(const s16x8*)(Ac + a_off[m][h]));
#pragma unroll
            for (int n = 0; n < 4; ++n)
                bv[n] = __builtin_bit_cast(bfx8, *(const s16x8*)(Bc + b_off[n][h]));
#pragma unroll
            for (int m = 0; m < 4; ++m)
#pragma unroll
                for (int n = 0; n < 4; ++n)
                    acc[m][n] = __builtin_amdgcn_mfma_f32_16x16x32_bf16(af[m], bv[n], acc[m][n], 0, 0, 0);
        }
        __syncthreads();   // drains next-tile B loads + A writes (overlapped with MFMAs)
    }
#pragma unroll
    for (int n = 0; n < 4; ++n) {
        int nc = n0 + Wc + n * 16 + (l & 15);
        float bs = bias[nc];
        double s = 0.0, q = 0.0;
#pragma unroll
        for (int m = 0; m < 4; ++m) {
            int rbase = m0 + Wr + m * 16 + ((l >> 4) << 2);
#pragma unroll
            for (int i = 0; i < 4; ++i) {
                float v = acc[m][n][i] + bs;
                C[(size_t)(rbase + i) * N + nc] = f2bf(v);
                s += (double)v;
                q += (double)v * (double)v;
            }
        }
        s += __shfl_xor(s, 16, 64); s += __shfl_xor(s, 32, 64);
        q += __shfl_xor(q, 16, 64); q += __shfl_xor(q, 32, 64);
        if ((l >> 4) == 0) {
            atomicAdd(&stats[nc], s);
            atomicAdd(&stats[N + nc], q);
        }
    }
}

// ---------------- final: bn3+ReLU on raw h3, dot w_out, + wide linear, sigmoid ----------------
__global__ void k_out(const unsigned short* __restrict__ h3, const double* __restrict__ stats3,
                      const float* __restrict__ g3, const float* __restrict__ be3,
                      const float* __restrict__ wo, const float* __restrict__ bo,
                      const int* __restrict__ x, const float* __restrict__ lt,
                      const float* __restrict__ lb, float* __restrict__ out) {
    __shared__ float scs[256], shs[256];
    int t = threadIdx.x;
    {
        constexpr double inv_bb = 1.0 / (double)BB;
        double mu = stats3[t] * inv_bb;
        double var = stats3[256 + t] * inv_bb - mu * mu;
        float sc = g3[t] / sqrtf((float)var + EPS_);
        scs[t] = sc;
        shs[t] = be3[t] - (float)mu * sc;
    }
    __syncthreads();
    int r = blockIdx.x * 4 + (t >> 6);
    int lane = t & 63;
    float s = 0.f;
#pragma unroll
    for (int k = lane; k < 256; k += 64) {
        float xv = bf2f(h3[(size_t)r * 256 + k]);
        float hb = bf2f(f2bf(fmaxf(fmaf(xv, scs[k], shs[k]), 0.f)));
        s += hb * wo[k];
    }
    if (lane < NF) {
        long long id = (long long)x[r * NF + lane] + (long long)lane * FIELD_DIM;
        s += lt[id];
    }
#pragma unroll
    for (int off = 32; off > 0; off >>= 1) s += __shfl_xor(s, off, 64);
    if (lane == 0) {
        float tt = s + bo[0] + lb[0];
        out[r] = 1.f / (1.f + expf(-tt));
    }
}

extern "C" void kernel_launch(void* const* d_in, const int* in_sizes, int n_in,
                              void* d_out, int out_size, void* d_ws, size_t ws_size,
                              hipStream_t stream) {
    const int* x = (const int*)d_in[0];
    const float* emb = (const float*)d_in[1];
    const float* lint = (const float*)d_in[2];
    const float* linb = (const float*)d_in[3];
    const float* bng = (const float*)d_in[4];
    const float* bnb = (const float*)d_in[5];
    const float* cw = (const float*)d_in[6];
    const float* cb = (const float*)d_in[7];
    const float* cbg = (const float*)d_in[8];
    const float* cbb = (const float*)d_in[9];
    const float* w1 = (const float*)d_in[10];
    const float* b1 = (const float*)d_in[11];
    const float* g1 = (const float*)d_in[12];
    const float* be1 = (const float*)d_in[13];
    const float* w2 = (const float*)d_in[14];
    const float* b2 = (const float*)d_in[15];
    const float* g2 = (const float*)d_in[16];
    const float* be2 = (const float*)d_in[17];
    const float* w3 = (const float*)d_in[18];
    const float* b3 = (const float*)d_in[19];
    const float* g3 = (const float*)d_in[20];
    const float* be3 = (const float*)d_in[21];
    const float* wo = (const float*)d_in[22];
    const float* bo = (const float*)d_in[23];
    const int* kptr = (const int*)d_in[24];
    float* out = (float*)d_out;

    char* p = (char*)d_ws;
    float* flat = (float*)p;                 p += (size_t)BB * ND * 4;      // fp32, ctrl path
    unsigned short* flatg = (unsigned short*)p; p += (size_t)BB * 640 * 2;  // gated bf16, K-padded
    unsigned short* h1 = (unsigned short*)p; p += (size_t)BB * 1024 * 2;    // raw (pre-BN)
    unsigned short* h2 = (unsigned short*)p; p += (size_t)BB * 512 * 2;     // raw
    unsigned short* h3 = (unsigned short*)p; p += (size_t)BB * 256 * 2;     // raw
    unsigned short* w1t = (unsigned short*)p; p += (size_t)1024 * 640 * 2;
    unsigned short* w2t = (unsigned short*)p; p += (size_t)512 * 1024 * 2;
    unsigned short* w3t = (unsigned short*)p; p += (size_t)256 * 512 * 2;
    float* wct = (float*)p;                  p += (size_t)48 * ND * 4;      // ctrl w transposed fp32
    float* zc = (float*)p;                   p += (size_t)BB * NF * 4;
    double* zp = (double*)p;                 p += (size_t)2 * BB * NF * 8;  // split-K partials fp64
    // disjoint per-layer fp64 stat regions, zeroed inside k_prep
    double* stats_all = (double*)p;
    double* stats_f = stats_all;             // 2*39
    double* stats_c = stats_f + 2 * NF;      // 2*39
    double* stats_1 = stats_c + 2 * NF;      // 2*1024
    double* stats_2 = stats_1 + 2 * 1024;    // 2*512
    double* stats_3 = stats_2 + 2 * 512;     // 2*256
    int stats_doubles = 2 * (NF + NF + 1024 + 512 + 256); // 3662

    // ---- prep: tiled weight transposes + stats zero (one kernel, 1412 blocks) ----
    k_prep<<<1412, 256, 0, stream>>>(w1, w2, w3, cw, w1t, w2t, w3t, wct,
                                     stats_all, stats_doubles);

    // ---- field BN (finalize fused into flat_norm) ----
    k_field_stats<<<dim3(NF, BB / 256), 256, 0, stream>>>(x, emb, stats_f);
    k_flat_norm<<<(BB * NF + 255) / 256, 256, 0, stream>>>(x, emb, stats_f, bng, bnb, flat);

    // ---- controller: split-K GEMM (2 blocks/CU) + reduce/stats + fused finalize/topk/gate ----
    k_ctrl_gemm_sk<<<512, 256, 0, stream>>>(flat, wct, zp);
    k_ctrl_reduce<<<BB / 64, 256, 0, stream>>>(zp, cb, zc, stats_c);
    k_topk_gate<<<BB / 4, 256, 0, stream>>>(zc, stats_c, cbg, cbb, kptr, flat, flatg);

    // ---- MLP layer 1: 640(pad) -> 1024 (h1 raw), XCD-swizzled 1D grid, 2-phase pipeline ----
    k_mfma_gemm<<<(1024 / 128) * (BB / 128), 256, 0, stream>>>(flatg, w1t, b1, h1, stats_1,
                                                               BB, 640, 1024, 3);

    // ---- MLP layer 2: BN1+ReLU fused into A-staging; 1024 -> 512 (h2 raw) ----
    k_mfma_gemm_bn<<<(512 / 128) * (BB / 128), 256, 0, stream>>>(h1, stats_1, g1, be1,
                                                                 w2t, b2, h2, stats_2,
                                                                 BB, 1024, 512, 2);

    // ---- MLP layer 3: BN2+ReLU fused; 512 -> 256 (h3 raw) ----
    k_mfma_gemm_bn<<<(256 / 128) * (BB / 128), 256, 0, stream>>>(h2, stats_2, g2, be2,
                                                                 w3t, b3, h3, stats_3,
                                                                 BB, 512, 256, 1);

    // ---- output: BN3+ReLU + dot w_out + wide linear + sigmoid ----
    k_out<<<BB / 4, 256, 0, stream>>>(h3, stats_3, g3, be3, wo, bo, x, lint, linb, out);
}

// Round 15
// 211.049 us; speedup vs baseline: 1.6267x; 1.0616x over previous
//
#include <hip/hip_runtime.h>
#include <math.h>
#include <stdint.h>

constexpr int BB = 16384;   // batch
constexpr int NF = 39;      // fields
constexpr int NE = 16;      // embed dim
constexpr int ND = NF * NE; // 624
constexpr int FIELD_DIM = 26000;
constexpr float EPS_ = 1e-5f;

typedef __bf16 bfx8 __attribute__((ext_vector_type(8)));
typedef float f32x4 __attribute__((ext_vector_type(4)));
typedef short s16x8 __attribute__((ext_vector_type(8)));

static __device__ __forceinline__ unsigned short f2bf(float f) {
    union { float f; unsigned u; } a; a.f = f;
    unsigned r = a.u + 0x7fffu + ((a.u >> 16) & 1u); // RNE
    return (unsigned short)(r >> 16);
}
static __device__ __forceinline__ float bf2f(unsigned short u) {
    union { unsigned u; float f; } a; a.u = ((unsigned)u) << 16;
    return a.f;
}

// XCD-aware block remap: l -> (bx, by). ny must be 128 (=8 XCDs * 16 panels).
static __device__ __forceinline__ void xcd_map(int l, int lognx, int& bx, int& by) {
    int s = l >> 3;
    bx = s & ((1 << lognx) - 1);
    by = ((l & 7) << 4) + (s >> lognx);
}

// ---------------- fused prep: LDS-tiled weight transposes + ctrl transpose + stats zero --------
__global__ void k_prep(const float* __restrict__ w1, const float* __restrict__ w2,
                       const float* __restrict__ w3, const float* __restrict__ cw,
                       unsigned short* __restrict__ w1t, unsigned short* __restrict__ w2t,
                       unsigned short* __restrict__ w3t, float* __restrict__ wct,
                       double* __restrict__ stats, int nstats) {
    int b = blockIdx.x;
    if (b < 1280) {
        const float* in; unsigned short* outp; int K, N, Kpad, tid;
        if (b < 640)        { in = w1; outp = w1t; K = 624;  N = 1024; Kpad = 640;  tid = b; }
        else if (b < 1152)  { in = w2; outp = w2t; K = 1024; N = 512;  Kpad = 1024; tid = b - 640; }
        else                { in = w3; outp = w3t; K = 512;  N = 256;  Kpad = 512;  tid = b - 1152; }
        int tiles_n = N >> 5;
        int tk = tid / tiles_n, tn = tid % tiles_n;
        __shared__ float tile[32][33];
        int tx = threadIdx.x & 31, ty = threadIdx.x >> 5;  // 32 x 8
#pragma unroll
        for (int i = 0; i < 4; ++i) {
            int k = tk * 32 + ty + i * 8, n = tn * 32 + tx;
            tile[ty + i * 8][tx] = (k < K) ? in[(size_t)k * N + n] : 0.f;
        }
        __syncthreads();
#pragma unroll
        for (int i = 0; i < 4; ++i) {
            int n = tn * 32 + ty + i * 8, k = tk * 32 + tx;
            outp[(size_t)n * Kpad + k] = f2bf(tile[tx][ty + i * 8]);
        }
    } else if (b < 1397) {                // wct: (48, 624) fp32, rows>=39 zero
        int gid = (b - 1280) * 256 + threadIdx.x;
        if (gid < 48 * ND) {
            int j = gid / ND, k = gid % ND;
            wct[gid] = (j < NF) ? cw[(size_t)k * NF + j] : 0.f;
        }
    } else {                              // zero fp64 stats
        int gid = (b - 1397) * 256 + threadIdx.x;
        if (gid < nstats) stats[gid] = 0.0;
    }
}

// ---------------- field BN stats: sum/sumsq per field over (B, E), fp64 atomics ----------------
__global__ void k_field_stats(const int* __restrict__ x, const float* __restrict__ emb,
                              double* __restrict__ stats /* 2*NF */) {
    int f = blockIdx.x;
    int r = blockIdx.y * blockDim.x + threadIdx.x;
    double s = 0.0, q = 0.0;
    if (r < BB) {
        long long id = (long long)x[r * NF + f] + (long long)f * FIELD_DIM;
        const float4* p = (const float4*)(emb + id * NE);
#pragma unroll
        for (int i = 0; i < 4; ++i) {
            float4 v = p[i];
            s += (double)v.x; s += (double)v.y; s += (double)v.z; s += (double)v.w;
            q += (double)v.x * v.x; q += (double)v.y * v.y;
            q += (double)v.z * v.z; q += (double)v.w * v.w;
        }
    }
    __shared__ double ls[256], lq[256];
    ls[threadIdx.x] = s; lq[threadIdx.x] = q;
    __syncthreads();
    for (int off = 128; off > 0; off >>= 1) {
        if ((int)threadIdx.x < off) {
            ls[threadIdx.x] += ls[threadIdx.x + off];
            lq[threadIdx.x] += lq[threadIdx.x + off];
        }
        __syncthreads();
    }
    if (threadIdx.x == 0) {
        atomicAdd(&stats[f], ls[0]);
        atomicAdd(&stats[NF + f], lq[0]);
    }
}

// ---------------- controller GEMM split-K, gather-fused A (flat eliminated) ----------------
// 512 blocks x 256 threads. Tile 64 rows x 48 cols, K halves [0,320) / [320,624).
// A staged on the fly: emb gather via LDS offset table + field-BN affine (bit-identical to flat).
__launch_bounds__(256)
__global__ void k_ctrl_gemm_sk(const int* __restrict__ x, const float* __restrict__ emb,
                               const double* __restrict__ stats_f,
                               const float* __restrict__ bng, const float* __restrict__ bnb,
                               const float* __restrict__ wct, double* __restrict__ zp) {
    __shared__ float As[64][68];       // [row][kk], padded
    __shared__ float Ws[64][49];       // [kk][col]
    __shared__ int xoff[64 * NF];      // per-(row,field) emb float-offset
    __shared__ float fsc[NF], fsh[NF];
    const int t = threadIdx.x;
    const int tn = t & 15;             // col group: cols 3tn..3tn+2
    const int tm = t >> 4;             // row group: rows 4tm..4tm+3
    const int bm = blockIdx.x & 255;
    const int half = blockIdx.x >> 8;
    const int m0 = bm * 64;
    const int kbeg = half ? 320 : 0;
    const int kend = half ? 624 : 320;

    // field-BN finalize (same formula as the old k_flat_norm -> bit-identical)
    if (t < NF) {
        double cnt = (double)BB * NE;
        double mu = stats_f[t] / cnt;
        double var = stats_f[NF + t] / cnt - mu * mu;
        float sc = (float)((double)bng[t] / sqrt(var + (double)EPS_));
        fsc[t] = sc;
        fsh[t] = bnb[t] - (float)mu * sc;
    }
    // x offsets for this block's 64 rows (coalesced)
    const int* xrow = x + m0 * NF;
    for (int j = t; j < 64 * NF; j += 256) {
        int f = j % NF;
        xoff[j] = (xrow[j] + f * FIELD_DIM) * NE;
    }
    __syncthreads();

    double acc[4][3] = {};
    for (int k0 = kbeg; k0 < kend; k0 += 64) {
        const int kl = (kend - k0 >= 64) ? 64 : (kend - k0);   // 64 or 48
        const int kl4 = kl >> 2;
        // stage A: gather from emb + field-BN affine (recomputes flat values exactly)
#pragma unroll
        for (int i = 0; i < 4; ++i) {
            int idx = t + 256 * i;     // 0..1023
            int row = idx >> 4, c4 = idx & 15;
            if (c4 < kl4) {
                int k = k0 + c4 * 4;
                int f = k >> 4;
                float4 v = *(const float4*)(emb + xoff[row * NF + f] + (k & 12));
                float sc = fsc[f], sh = fsh[f];
                float4 nv = make_float4(fmaf(v.x, sc, sh), fmaf(v.y, sc, sh),
                                        fmaf(v.z, sc, sh), fmaf(v.w, sc, sh));
                *(float4*)&As[row][c4 * 4] = nv;
            }
        }
        // stage W: 48 cols x kl floats, transposed into [kk][col]
        {
            int col = t >> 4;          // 0..15
            int c4 = t & 15;
#pragma unroll
            for (int cp = 0; cp < 3; ++cp, col += 16) {
                if (c4 < kl4) {
                    float4 v = *(const float4*)(wct + (size_t)col * ND + k0 + c4 * 4);
                    Ws[c4 * 4 + 0][col] = v.x; Ws[c4 * 4 + 1][col] = v.y;
                    Ws[c4 * 4 + 2][col] = v.z; Ws[c4 * 4 + 3][col] = v.w;
                }
            }
        }
        __syncthreads();
#pragma unroll 4
        for (int kk = 0; kk < kl; ++kk) {
            double a0 = (double)As[4 * tm + 0][kk];
            double a1 = (double)As[4 * tm + 1][kk];
            double a2 = (double)As[4 * tm + 2][kk];
            double a3 = (double)As[4 * tm + 3][kk];
            double w0 = (double)Ws[kk][3 * tn + 0];
            double w1 = (double)Ws[kk][3 * tn + 1];
            double w2 = (double)Ws[kk][3 * tn + 2];
            acc[0][0] += a0 * w0; acc[0][1] += a0 * w1; acc[0][2] += a0 * w2;
            acc[1][0] += a1 * w0; acc[1][1] += a1 * w1; acc[1][2] += a1 * w2;
            acc[2][0] += a2 * w0; acc[2][1] += a2 * w1; acc[2][2] += a2 * w2;
            acc[3][0] += a3 * w0; acc[3][1] += a3 * w1; acc[3][2] += a3 * w2;
        }
        __syncthreads();
    }
    double* zph = zp + (size_t)half * BB * NF;
#pragma unroll
    for (int j = 0; j < 3; ++j) {
        int col = 3 * tn + j;
        if (col < NF) {
#pragma unroll
            for (int i = 0; i < 4; ++i)
                zph[(size_t)(m0 + 4 * tm + i) * NF + col] = acc[i][j];
        }
    }
}

// ---------------- split-K reduce: z = (float)(p0+p1+bias), fused col stats ----------------
__global__ void k_ctrl_reduce(const double* __restrict__ zp, const float* __restrict__ bias,
                              float* __restrict__ z, double* __restrict__ stats) {
    __shared__ double Sred[2][16][48];
    const int t = threadIdx.x;
    const int tn = t & 15;
    const int tm = t >> 4;
    const int m0 = blockIdx.x * 64;
#pragma unroll
    for (int j = 0; j < 3; ++j) {
        int col = 3 * tn + j;
        double s = 0.0, q = 0.0;
        if (col < NF) {
            float bs = bias[col];
#pragma unroll
            for (int i = 0; i < 4; ++i) {
                size_t idx = (size_t)(m0 + 4 * tm + i) * NF + col;
                double p01 = zp[idx] + zp[(size_t)BB * NF + idx];
                float v = (float)(p01 + (double)bs);
                z[idx] = v;
                s += (double)v;
                q += (double)v * (double)v;
            }
        }
        Sred[0][tm][col] = s;
        Sred[1][tm][col] = q;
    }
    __syncthreads();
    if (t < NF) {
        double ts = 0.0, tq = 0.0;
#pragma unroll
        for (int i = 0; i < 16; ++i) { ts += Sred[0][i][t]; tq += Sred[1][i][t]; }
        atomicAdd(&stats[t], ts);
        atomicAdd(&stats[NF + t], tq);
    }
}

// ---------------- ctrl-BN finalize + BN+ReLU + rank top-k + gather-gate -> flatg (fused) --------
// Gating now re-gathers emb and applies field-BN inline (bit-identical to old flat read).
__global__ void k_topk_gate(const float* __restrict__ zc, const double* __restrict__ stats,
                            const float* __restrict__ cbg, const float* __restrict__ cbb,
                            const int* __restrict__ kptr, const int* __restrict__ x,
                            const float* __restrict__ emb, const double* __restrict__ stats_f,
                            const float* __restrict__ bng, const float* __restrict__ bnb,
                            unsigned short* __restrict__ flatg) {
    __shared__ float sc_s[NF], sh_s[NF], fsc[NF], fsh[NF];
    int t = threadIdx.x;
    if (t < NF) {
        double mu = stats[t] / (double)BB;
        double var = stats[NF + t] / (double)BB - mu * mu;
        float sc = (float)((double)cbg[t] / sqrt(var + (double)EPS_));
        sc_s[t] = sc;
        sh_s[t] = cbb[t] - (float)mu * sc;
        double cnt = (double)BB * NE;
        double muf = stats_f[t] / cnt;
        double varf = stats_f[NF + t] / cnt - muf * muf;
        float scf = (float)((double)bng[t] / sqrt(varf + (double)EPS_));
        fsc[t] = scf;
        fsh[t] = bnb[t] - (float)muf * scf;
    }
    __syncthreads();
    int r = blockIdx.x * 4 + (t >> 6);
    int lane = t & 63;
    int k = kptr[0];
    bool active = (lane < NF);
    float w = -1.f;
    if (active) {
        float v = zc[(size_t)r * NF + lane];
        w = fmaxf(fmaf(v, sc_s[lane], sh_s[lane]), 0.f);
    }
    int rank = 0;
#pragma unroll
    for (int j = 0; j < NF; ++j) {
        float vj = __shfl(w, j, 64);
        rank += (vj > w || (vj == w && j < lane)) ? 1 : 0;
    }
    bool sel = active && (rank < k);
    float val = sel ? w : 0.f;
    float sum = val;
#pragma unroll
    for (int off = 32; off > 0; off >>= 1) sum += __shfl_xor(sum, off, 64);
    if (active) {
        float ms = sel ? ((sum > 0.f) ? (w / sum) : 0.f) : 0.f;
        int o = (x[r * NF + lane] + lane * FIELD_DIM) * NE;
        const float4* pe = (const float4*)(emb + o);
        float sc = fsc[lane], sh = fsh[lane];
        unsigned short* dst = flatg + (size_t)r * 640 + lane * 16;
#pragma unroll
        for (int h = 0; h < 2; ++h) {
            float4 e0 = pe[h * 2], e1 = pe[h * 2 + 1];
            float e[8] = {e0.x, e0.y, e0.z, e0.w, e1.x, e1.y, e1.z, e1.w};
            union { s16x8 v; unsigned short u[8]; } p;
#pragma unroll
            for (int j = 0; j < 8; ++j)
                p.u[j] = f2bf(fmaf(e[j], sc, sh) * ms);   // same op order as flat path
            *(s16x8*)(dst + h * 8) = p.v;
        }
    } else if (lane == NF) {
        s16x8 zv = {};
        *(s16x8*)(flatg + (size_t)r * 640 + 624) = zv;
        *(s16x8*)(flatg + (size_t)r * 640 + 632) = zv;
    }
}

// ---------------- bf16 MFMA GEMM (layer 1): 2-phase double-buffered pipeline ----------------
__launch_bounds__(256)
__global__ void k_mfma_gemm(const unsigned short* __restrict__ A,  // M x K bf16
                            const unsigned short* __restrict__ Bt, // N x K bf16
                            const float* __restrict__ bias,
                            unsigned short* __restrict__ C,        // M x N bf16
                            double* __restrict__ stats,            // 2*N fp64
                            int M, int K, int N, int lognx) {
    __shared__ char lds[65536];   // A0 A1 B0 B1, 16KB each
    const int t = threadIdx.x;
    const int l = t & 63;
    const int w = t >> 6;
    int bx, by;
    xcd_map(blockIdx.x, lognx, bx, by);
    const int m0 = by * 128, n0 = bx * 128;
    const int Wr = (w >> 1) * 64, Wc = (w & 1) * 64;

    const int srow = t >> 3;            // 0..31
    const int sswz = (t & 7) ^ (srow & 7);
    const unsigned short* ga[4];
    const unsigned short* gb[4];
#pragma unroll
    for (int i = 0; i < 4; ++i) {
        ga[i] = A + (size_t)(m0 + i * 32 + srow) * K + sswz * 8;
        gb[i] = Bt + (size_t)(n0 + i * 32 + srow) * K + sswz * 8;
    }
    int a_off[4][2], b_off[4][2];
#pragma unroll
    for (int m = 0; m < 4; ++m) {
#pragma unroll
        for (int h = 0; h < 2; ++h) {
            int r = Wr + m * 16 + (l & 15);
            a_off[m][h] = r * 128 + (((h * 4 + (l >> 4)) ^ (r & 7)) << 4);
            int c = Wc + m * 16 + (l & 15);
            b_off[m][h] = c * 128 + (((h * 4 + (l >> 4)) ^ (c & 7)) << 4);
        }
    }
    const int nt = K >> 6;
    f32x4 acc[4][4] = {};
#pragma unroll
    for (int i = 0; i < 4; ++i) {
        __builtin_amdgcn_global_load_lds(
            (const __attribute__((address_space(1))) void*)ga[i],
            (__attribute__((address_space(3))) void*)(lds + i * 4096 + t * 16), 16, 0, 0);
        __builtin_amdgcn_global_load_lds(
            (const __attribute__((address_space(1))) void*)gb[i],
            (__attribute__((address_space(3))) void*)(lds + 32768 + i * 4096 + t * 16), 16, 0, 0);
        ga[i] += 64; gb[i] += 64;
    }
    __syncthreads();
    for (int ts = 0; ts < nt; ++ts) {
        const int cur = ts & 1;
        if (ts + 1 < nt) {
            char* An = lds + (cur ^ 1) * 16384;
            char* Bn = lds + 32768 + (cur ^ 1) * 16384;
#pragma unroll
            for (int i = 0; i < 4; ++i) {
                __builtin_amdgcn_global_load_lds(
                    (const __attribute__((address_space(1))) void*)ga[i],
                    (__attribute__((address_space(3))) void*)(An + i * 4096 + t * 16), 16, 0, 0);
                __builtin_amdgcn_global_load_lds(
                    (const __attribute__((address_space(1))) void*)gb[i],
                    (__attribute__((address_space(3))) void*)(Bn + i * 4096 + t * 16), 16, 0, 0);
                ga[i] += 64; gb[i] += 64;
            }
        }
        const char* Ac = lds + cur * 16384;
        const char* Bc = lds + 32768 + cur * 16384;
#pragma unroll
        for (int h = 0; h < 2; ++h) {
            bfx8 af[4], bv[4];
#pragma unroll
            for (int m = 0; m < 4; ++m)
                af[m] = __builtin_bit_cast(bfx8, *(const s16x8*)(Ac + a_off[m][h]));
#pragma unroll
            for (int n = 0; n < 4; ++n)
                bv[n] = __builtin_bit_cast(bfx8, *(const s16x8*)(Bc + b_off[n][h]));
#pragma unroll
            for (int m = 0; m < 4; ++m)
#pragma unroll
                for (int n = 0; n < 4; ++n)
                    acc[m][n] = __builtin_amdgcn_mfma_f32_16x16x32_bf16(af[m], bv[n], acc[m][n], 0, 0, 0);
        }
        __syncthreads();
    }
#pragma unroll
    for (int n = 0; n < 4; ++n) {
        int nc = n0 + Wc + n * 16 + (l & 15);
        float bs = bias[nc];
        double s = 0.0, q = 0.0;
#pragma unroll
        for (int m = 0; m < 4; ++m) {
            int rbase = m0 + Wr + m * 16 + ((l >> 4) << 2);
#pragma unroll
            for (int i = 0; i < 4; ++i) {
                float v = acc[m][n][i] + bs;
                C[(size_t)(rbase + i) * N + nc] = f2bf(v);
                s += (double)v;
                q += (double)v * (double)v;
            }
        }
        s += __shfl_xor(s, 16, 64); s += __shfl_xor(s, 32, 64);
        q += __shfl_xor(q, 16, 64); q += __shfl_xor(q, 32, 64);
        if ((l >> 4) == 0) {
            atomicAdd(&stats[nc], s);
            atomicAdd(&stats[N + nc], q);
        }
    }
}

// ---------------- bf16 MFMA GEMM with fused input-BN+ReLU on A (layers 2,3) ----------------
__launch_bounds__(256)
__global__ void k_mfma_gemm_bn(const unsigned short* __restrict__ A,   // M x K bf16 raw
                               const double* __restrict__ statsIn,     // 2*K (A's BN stats)
                               const float* __restrict__ g, const float* __restrict__ be,
                               const unsigned short* __restrict__ Bt,  // N x K bf16
                               const float* __restrict__ bias,
                               unsigned short* __restrict__ C,         // M x N bf16
                               double* __restrict__ stats,             // 2*N fp64
                               int M, int K, int N, int lognx) {
    __shared__ char lds[73728];           // A0 A1 B0 B1 (16KB each) + scs/shs (8KB)
    float* scs = (float*)(lds + 65536);   // K floats
    float* shs = scs + K;                 // K floats (K<=1024)
    const int t = threadIdx.x;
    const int l = t & 63;
    const int w = t >> 6;
    int bx, by;
    xcd_map(blockIdx.x, lognx, bx, by);
    const int m0 = by * 128, n0 = bx * 128;
    const int Wr = (w >> 1) * 64, Wc = (w & 1) * 64;

    constexpr double inv_bb = 1.0 / (double)BB;
    for (int c = t; c < K; c += 256) {
        double mu = statsIn[c] * inv_bb;
        double var = statsIn[K + c] * inv_bb - mu * mu;
        float sc = g[c] / sqrtf((float)var + EPS_);
        scs[c] = sc;
        shs[c] = be[c] - (float)mu * sc;
    }
    __syncthreads();

    const int srow = t >> 3;            // 0..31
    const int sswz = (t & 7) ^ (srow & 7);
    const unsigned short* ga[4];
    const unsigned short* gb[4];
#pragma unroll
    for (int i = 0; i < 4; ++i) {
        ga[i] = A + (size_t)(m0 + i * 32 + srow) * K + sswz * 8;
        gb[i] = Bt + (size_t)(n0 + i * 32 + srow) * K + sswz * 8;
    }
    int a_off[4][2], b_off[4][2];
#pragma unroll
    for (int m = 0; m < 4; ++m) {
#pragma unroll
        for (int h = 0; h < 2; ++h) {
            int r = Wr + m * 16 + (l & 15);
            a_off[m][h] = r * 128 + (((h * 4 + (l >> 4)) ^ (r & 7)) << 4);
            int c = Wc + m * 16 + (l & 15);
            b_off[m][h] = c * 128 + (((h * 4 + (l >> 4)) ^ (c & 7)) << 4);
        }
    }
    const int nt = K >> 6;
    f32x4 acc[4][4] = {};
    s16x8 praw[4];

    auto write_a = [&](int buf, int kb0) {
        char* Ad = lds + buf * 16384;
        int kb = kb0 + sswz * 8;
        float4 sc0 = *(const float4*)&scs[kb];
        float4 sc1 = *(const float4*)&scs[kb + 4];
        float4 sh0 = *(const float4*)&shs[kb];
        float4 sh1 = *(const float4*)&shs[kb + 4];
        float scl[8] = {sc0.x, sc0.y, sc0.z, sc0.w, sc1.x, sc1.y, sc1.z, sc1.w};
        float shl[8] = {sh0.x, sh0.y, sh0.z, sh0.w, sh1.x, sh1.y, sh1.z, sh1.w};
#pragma unroll
        for (int i = 0; i < 4; ++i) {
            union { s16x8 v; unsigned short u[8]; } pin;
            pin.v = praw[i];
            float f[8];
#pragma unroll
            for (int j = 0; j < 8; ++j)
                f[j] = fmaxf(fmaf(bf2f(pin.u[j]), scl[j], shl[j]), 0.f);
            union { unsigned w4[4]; s16x8 v; } pout;
#pragma unroll
            for (int j = 0; j < 4; ++j) {
                unsigned rr;
                asm("v_cvt_pk_bf16_f32 %0, %1, %2" : "=v"(rr) : "v"(f[2 * j]), "v"(f[2 * j + 1]));
                pout.w4[j] = rr;
            }
            *(s16x8*)(Ad + i * 4096 + t * 16) = pout.v;
        }
    };
    auto load_praw = [&]() {
#pragma unroll
        for (int i = 0; i < 4; ++i) { praw[i] = *(const s16x8*)ga[i]; ga[i] += 64; }
    };
    auto stage_b = [&](int buf) {
        char* Bd = lds + 32768 + buf * 16384;
#pragma unroll
        for (int i = 0; i < 4; ++i) {
            __builtin_amdgcn_global_load_lds(
                (const __attribute__((address_space(1))) void*)gb[i],
                (__attribute__((address_space(3))) void*)(Bd + i * 4096 + t * 16), 16, 0, 0);
            gb[i] += 64;
        }
    };

    load_praw();
    stage_b(0);
    write_a(0, 0);
    if (nt > 1) load_praw();
    __syncthreads();

    for (int ts = 0; ts < nt; ++ts) {
        const int cur = ts & 1;
        if (ts + 1 < nt) {
            stage_b(cur ^ 1);
            write_a(cur ^ 1, (ts + 1) << 6);
            if (ts + 2 < nt) load_praw();
        }
        const char* Ac = lds + cur * 16384;
        const char* Bc = lds + 32768 + cur * 16384;
#pragma unroll
        for (int h = 0; h < 2; ++h) {
            bfx8 af[4], bv[4];
#pragma unroll
            for (int m = 0; m < 4; ++m)
                af[m] = __builtin_bit_cast(bfx8, *(const s16x8*)(Ac + a_off[m][h]));
#pragma unroll
            for (int n = 0; n < 4; ++n)
                bv[n] = __builtin_bit_cast(bfx8, *(const s16x8*)(Bc + b_off[n][h]));
#pragma unroll
            for (int m = 0; m < 4; ++m)
#pragma unroll
                for (int n = 0; n < 4; ++n)
                    acc[m][n] = __builtin_amdgcn_mfma_f32_16x16x32_bf16(af[m], bv[n], acc[m][n], 0, 0, 0);
        }
        __syncthreads();
    }
#pragma unroll
    for (int n = 0; n < 4; ++n) {
        int nc = n0 + Wc + n * 16 + (l & 15);
        float bs = bias[nc];
        double s = 0.0, q = 0.0;
#pragma unroll
        for (int m = 0; m < 4; ++m) {
            int rbase = m0 + Wr + m * 16 + ((l >> 4) << 2);
#pragma unroll
            for (int i = 0; i < 4; ++i) {
                float v = acc[m][n][i] + bs;
                C[(size_t)(rbase + i) * N + nc] = f2bf(v);
                s += (double)v;
                q += (double)v * (double)v;
            }
        }
        s += __shfl_xor(s, 16, 64); s += __shfl_xor(s, 32, 64);
        q += __shfl_xor(q, 16, 64); q += __shfl_xor(q, 32, 64);
        if ((l >> 4) == 0) {
            atomicAdd(&stats[nc], s);
            atomicAdd(&stats[N + nc], q);
        }
    }
}

// ---------------- final: bn3+ReLU on raw h3, dot w_out, + wide linear, sigmoid ----------------
__global__ void k_out(const unsigned short* __restrict__ h3, const double* __restrict__ stats3,
                      const float* __restrict__ g3, const float* __restrict__ be3,
                      const float* __restrict__ wo, const float* __restrict__ bo,
                      const int* __restrict__ x, const float* __restrict__ lt,
                      const float* __restrict__ lb, float* __restrict__ out) {
    __shared__ float scs[256], shs[256];
    int t = threadIdx.x;
    {
        constexpr double inv_bb = 1.0 / (double)BB;
        double mu = stats3[t] * inv_bb;
        double var = stats3[256 + t] * inv_bb - mu * mu;
        float sc = g3[t] / sqrtf((float)var + EPS_);
        scs[t] = sc;
        shs[t] = be3[t] - (float)mu * sc;
    }
    __syncthreads();
    int r = blockIdx.x * 4 + (t >> 6);
    int lane = t & 63;
    float s = 0.f;
#pragma unroll
    for (int k = lane; k < 256; k += 64) {
        float xv = bf2f(h3[(size_t)r * 256 + k]);
        float hb = bf2f(f2bf(fmaxf(fmaf(xv, scs[k], shs[k]), 0.f)));
        s += hb * wo[k];
    }
    if (lane < NF) {
        long long id = (long long)x[r * NF + lane] + (long long)lane * FIELD_DIM;
        s += lt[id];
    }
#pragma unroll
    for (int off = 32; off > 0; off >>= 1) s += __shfl_xor(s, off, 64);
    if (lane == 0) {
        float tt = s + bo[0] + lb[0];
        out[r] = 1.f / (1.f + expf(-tt));
    }
}

extern "C" void kernel_launch(void* const* d_in, const int* in_sizes, int n_in,
                              void* d_out, int out_size, void* d_ws, size_t ws_size,
                              hipStream_t stream) {
    const int* x = (const int*)d_in[0];
    const float* emb = (const float*)d_in[1];
    const float* lint = (const float*)d_in[2];
    const float* linb = (const float*)d_in[3];
    const float* bng = (const float*)d_in[4];
    const float* bnb = (const float*)d_in[5];
    const float* cw = (const float*)d_in[6];
    const float* cb = (const float*)d_in[7];
    const float* cbg = (const float*)d_in[8];
    const float* cbb = (const float*)d_in[9];
    const float* w1 = (const float*)d_in[10];
    const float* b1 = (const float*)d_in[11];
    const float* g1 = (const float*)d_in[12];
    const float* be1 = (const float*)d_in[13];
    const float* w2 = (const float*)d_in[14];
    const float* b2 = (const float*)d_in[15];
    const float* g2 = (const float*)d_in[16];
    const float* be2 = (const float*)d_in[17];
    const float* w3 = (const float*)d_in[18];
    const float* b3 = (const float*)d_in[19];
    const float* g3 = (const float*)d_in[20];
    const float* be3 = (const float*)d_in[21];
    const float* wo = (const float*)d_in[22];
    const float* bo = (const float*)d_in[23];
    const int* kptr = (const int*)d_in[24];
    float* out = (float*)d_out;

    char* p = (char*)d_ws;
    unsigned short* flatg = (unsigned short*)p; p += (size_t)BB * 640 * 2;  // gated bf16, K-padded
    unsigned short* h1 = (unsigned short*)p; p += (size_t)BB * 1024 * 2;    // raw (pre-BN)
    unsigned short* h2 = (unsigned short*)p; p += (size_t)BB * 512 * 2;     // raw
    unsigned short* h3 = (unsigned short*)p; p += (size_t)BB * 256 * 2;     // raw
    unsigned short* w1t = (unsigned short*)p; p += (size_t)1024 * 640 * 2;
    unsigned short* w2t = (unsigned short*)p; p += (size_t)512 * 1024 * 2;
    unsigned short* w3t = (unsigned short*)p; p += (size_t)256 * 512 * 2;
    float* wct = (float*)p;                  p += (size_t)48 * ND * 4;      // ctrl w transposed fp32
    float* zc = (float*)p;                   p += (size_t)BB * NF * 4;
    double* zp = (double*)p;                 p += (size_t)2 * BB * NF * 8;  // split-K partials fp64
    // disjoint per-layer fp64 stat regions, zeroed inside k_prep
    double* stats_all = (double*)p;
    double* stats_f = stats_all;             // 2*39
    double* stats_c = stats_f + 2 * NF;      // 2*39
    double* stats_1 = stats_c + 2 * NF;      // 2*1024
    double* stats_2 = stats_1 + 2 * 1024;    // 2*512
    double* stats_3 = stats_2 + 2 * 512;     // 2*256
    int stats_doubles = 2 * (NF + NF + 1024 + 512 + 256); // 3662

    // ---- prep: tiled weight transposes + stats zero (one kernel, 1412 blocks) ----
    k_prep<<<1412, 256, 0, stream>>>(w1, w2, w3, cw, w1t, w2t, w3t, wct,
                                     stats_all, stats_doubles);

    // ---- field BN stats (finalize is recomputed in consumers, bit-identically) ----
    k_field_stats<<<dim3(NF, BB / 256), 256, 0, stream>>>(x, emb, stats_f);

    // ---- controller: gather-fused split-K GEMM + reduce/stats + fused finalize/topk/gate ----
    k_ctrl_gemm_sk<<<512, 256, 0, stream>>>(x, emb, stats_f, bng, bnb, wct, zp);
    k_ctrl_reduce<<<BB / 64, 256, 0, stream>>>(zp, cb, zc, stats_c);
    k_topk_gate<<<BB / 4, 256, 0, stream>>>(zc, stats_c, cbg, cbb, kptr, x, emb,
                                            stats_f, bng, bnb, flatg);

    // ---- MLP layer 1: 640(pad) -> 1024 (h1 raw), XCD-swizzled 1D grid, 2-phase pipeline ----
    k_mfma_gemm<<<(1024 / 128) * (BB / 128), 256, 0, stream>>>(flatg, w1t, b1, h1, stats_1,
                                                               BB, 640, 1024, 3);

    // ---- MLP layer 2: BN1+ReLU fused into A-staging; 1024 -> 512 (h2 raw) ----
    k_mfma_gemm_bn<<<(512 / 128) * (BB / 128), 256, 0, stream>>>(h1, stats_1, g1, be1,
                                                                 w2t, b2, h2, stats_2,
                                                                 BB, 1024, 512, 2);

    // ---- MLP layer 3: BN2+ReLU fused; 512 -> 256 (h3 raw) ----
    k_mfma_gemm_bn<<<(256 / 128) * (BB / 128), 256, 0, stream>>>(h2, stats_2, g2, be2,
                                                                 w3t, b3, h3, stats_3,
                                                                 BB, 512, 256, 1);

    // ---- output: BN3+ReLU + dot w_out + wide linear + sigmoid ----
    k_out<<<BB / 4, 256, 0, stream>>>(h3, stats_3, g3, be3, wo, bo, x, lint, linb, out);
}

// Round 16
// 208.929 us; speedup vs baseline: 1.6432x; 1.0101x over previous
//
#include <hip/hip_runtime.h>
#include <math.h>
#include <stdint.h>

constexpr int BB = 16384;   // batch
constexpr int NF = 39;      // fields
constexpr int NE = 16;      // embed dim
constexpr int ND = NF * NE; // 624
constexpr int FIELD_DIM = 26000;
constexpr float EPS_ = 1e-5f;

typedef __bf16 bfx8 __attribute__((ext_vector_type(8)));
typedef float f32x4 __attribute__((ext_vector_type(4)));
typedef short s16x8 __attribute__((ext_vector_type(8)));

static __device__ __forceinline__ unsigned short f2bf(float f) {
    union { float f; unsigned u; } a; a.f = f;
    unsigned r = a.u + 0x7fffu + ((a.u >> 16) & 1u); // RNE
    return (unsigned short)(r >> 16);
}
static __device__ __forceinline__ float bf2f(unsigned short u) {
    union { unsigned u; float f; } a; a.u = ((unsigned)u) << 16;
    return a.f;
}

// XCD-aware block remap: l -> (bx, by). ny must be 128 (=8 XCDs * 16 panels).
static __device__ __forceinline__ void xcd_map(int l, int lognx, int& bx, int& by) {
    int s = l >> 3;
    bx = s & ((1 << lognx) - 1);
    by = ((l & 7) << 4) + (s >> lognx);
}

// ---------------- fused prep: LDS-tiled weight transposes + ctrl transpose + stats zero --------
__global__ void k_prep(const float* __restrict__ w1, const float* __restrict__ w2,
                       const float* __restrict__ w3, const float* __restrict__ cw,
                       unsigned short* __restrict__ w1t, unsigned short* __restrict__ w2t,
                       unsigned short* __restrict__ w3t, float* __restrict__ wct,
                       double* __restrict__ stats, int nstats) {
    int b = blockIdx.x;
    if (b < 1280) {
        const float* in; unsigned short* outp; int K, N, Kpad, tid;
        if (b < 640)        { in = w1; outp = w1t; K = 624;  N = 1024; Kpad = 640;  tid = b; }
        else if (b < 1152)  { in = w2; outp = w2t; K = 1024; N = 512;  Kpad = 1024; tid = b - 640; }
        else                { in = w3; outp = w3t; K = 512;  N = 256;  Kpad = 512;  tid = b - 1152; }
        int tiles_n = N >> 5;
        int tk = tid / tiles_n, tn = tid % tiles_n;
        __shared__ float tile[32][33];
        int tx = threadIdx.x & 31, ty = threadIdx.x >> 5;  // 32 x 8
#pragma unroll
        for (int i = 0; i < 4; ++i) {
            int k = tk * 32 + ty + i * 8, n = tn * 32 + tx;
            tile[ty + i * 8][tx] = (k < K) ? in[(size_t)k * N + n] : 0.f;
        }
        __syncthreads();
#pragma unroll
        for (int i = 0; i < 4; ++i) {
            int n = tn * 32 + ty + i * 8, k = tk * 32 + tx;
            outp[(size_t)n * Kpad + k] = f2bf(tile[tx][ty + i * 8]);
        }
    } else if (b < 1397) {                // wct: (48, 624) fp32, rows>=39 zero
        int gid = (b - 1280) * 256 + threadIdx.x;
        if (gid < 48 * ND) {
            int j = gid / ND, k = gid % ND;
            wct[gid] = (j < NF) ? cw[(size_t)k * NF + j] : 0.f;
        }
    } else {                              // zero fp64 stats
        int gid = (b - 1397) * 256 + threadIdx.x;
        if (gid < nstats) stats[gid] = 0.0;
    }
}

// ---------------- field BN stats: sum/sumsq per field over (B, E), fp64 atomics ----------------
__global__ void k_field_stats(const int* __restrict__ x, const float* __restrict__ emb,
                              double* __restrict__ stats /* 2*NF */) {
    int f = blockIdx.x;
    int r = blockIdx.y * blockDim.x + threadIdx.x;
    double s = 0.0, q = 0.0;
    if (r < BB) {
        long long id = (long long)x[r * NF + f] + (long long)f * FIELD_DIM;
        const float4* p = (const float4*)(emb + id * NE);
#pragma unroll
        for (int i = 0; i < 4; ++i) {
            float4 v = p[i];
            s += (double)v.x; s += (double)v.y; s += (double)v.z; s += (double)v.w;
            q += (double)v.x * v.x; q += (double)v.y * v.y;
            q += (double)v.z * v.z; q += (double)v.w * v.w;
        }
    }
    __shared__ double ls[256], lq[256];
    ls[threadIdx.x] = s; lq[threadIdx.x] = q;
    __syncthreads();
    for (int off = 128; off > 0; off >>= 1) {
        if ((int)threadIdx.x < off) {
            ls[threadIdx.x] += ls[threadIdx.x + off];
            lq[threadIdx.x] += lq[threadIdx.x + off];
        }
        __syncthreads();
    }
    if (threadIdx.x == 0) {
        atomicAdd(&stats[f], ls[0]);
        atomicAdd(&stats[NF + f], lq[0]);
    }
}

// ---------------- controller GEMM split-K x4, gather-fused A ----------------
// 1024 blocks x 256 threads (4 blocks/CU). Tile 64 rows x 48 cols.
// K quarters: [0,192) [192,320) [320,512) [512,624), 64-aligned staging chunks.
__launch_bounds__(256)
__global__ void k_ctrl_gemm_sk(const int* __restrict__ x, const float* __restrict__ emb,
                               const double* __restrict__ stats_f,
                               const float* __restrict__ bng, const float* __restrict__ bnb,
                               const float* __restrict__ wct, double* __restrict__ zp) {
    __shared__ float As[64][68];       // [row][kk], padded
    __shared__ float Ws[64][49];       // [kk][col]
    __shared__ int xoff[64 * NF];      // per-(row,field) emb float-offset
    __shared__ float fsc[NF], fsh[NF];
    const int t = threadIdx.x;
    const int tn = t & 15;             // col group: cols 3tn..3tn+2
    const int tm = t >> 4;             // row group: rows 4tm..4tm+3
    const int bm = blockIdx.x & 255;
    const int qt = blockIdx.x >> 8;    // 0..3
    const int m0 = bm * 64;
    const int kbq[5] = {0, 192, 320, 512, 624};
    const int kbeg = kbq[qt];
    const int kend = kbq[qt + 1];

    // field-BN finalize (same formula as before -> bit-identical values)
    if (t < NF) {
        double cnt = (double)BB * NE;
        double mu = stats_f[t] / cnt;
        double var = stats_f[NF + t] / cnt - mu * mu;
        float sc = (float)((double)bng[t] / sqrt(var + (double)EPS_));
        fsc[t] = sc;
        fsh[t] = bnb[t] - (float)mu * sc;
    }
    // x offsets for this block's 64 rows (coalesced)
    const int* xrow = x + m0 * NF;
    for (int j = t; j < 64 * NF; j += 256) {
        int f = j % NF;
        xoff[j] = (xrow[j] + f * FIELD_DIM) * NE;
    }
    __syncthreads();

    double acc[4][3] = {};
    for (int k0 = kbeg; k0 < kend; k0 += 64) {
        const int kl = (kend - k0 >= 64) ? 64 : (kend - k0);   // 64 or 48
        const int kl4 = kl >> 2;
        // stage A: gather from emb + field-BN affine (recomputes flat values exactly)
#pragma unroll
        for (int i = 0; i < 4; ++i) {
            int idx = t + 256 * i;     // 0..1023
            int row = idx >> 4, c4 = idx & 15;
            if (c4 < kl4) {
                int k = k0 + c4 * 4;
                int f = k >> 4;
                float4 v = *(const float4*)(emb + xoff[row * NF + f] + (k & 12));
                float sc = fsc[f], sh = fsh[f];
                float4 nv = make_float4(fmaf(v.x, sc, sh), fmaf(v.y, sc, sh),
                                        fmaf(v.z, sc, sh), fmaf(v.w, sc, sh));
                *(float4*)&As[row][c4 * 4] = nv;
            }
        }
        // stage W: 48 cols x kl floats, transposed into [kk][col]
        {
            int col = t >> 4;          // 0..15
            int c4 = t & 15;
#pragma unroll
            for (int cp = 0; cp < 3; ++cp, col += 16) {
                if (c4 < kl4) {
                    float4 v = *(const float4*)(wct + (size_t)col * ND + k0 + c4 * 4);
                    Ws[c4 * 4 + 0][col] = v.x; Ws[c4 * 4 + 1][col] = v.y;
                    Ws[c4 * 4 + 2][col] = v.z; Ws[c4 * 4 + 3][col] = v.w;
                }
            }
        }
        __syncthreads();
#pragma unroll 4
        for (int kk = 0; kk < kl; ++kk) {
            double a0 = (double)As[4 * tm + 0][kk];
            double a1 = (double)As[4 * tm + 1][kk];
            double a2 = (double)As[4 * tm + 2][kk];
            double a3 = (double)As[4 * tm + 3][kk];
            double w0 = (double)Ws[kk][3 * tn + 0];
            double w1 = (double)Ws[kk][3 * tn + 1];
            double w2 = (double)Ws[kk][3 * tn + 2];
            acc[0][0] += a0 * w0; acc[0][1] += a0 * w1; acc[0][2] += a0 * w2;
            acc[1][0] += a1 * w0; acc[1][1] += a1 * w1; acc[1][2] += a1 * w2;
            acc[2][0] += a2 * w0; acc[2][1] += a2 * w1; acc[2][2] += a2 * w2;
            acc[3][0] += a3 * w0; acc[3][1] += a3 * w1; acc[3][2] += a3 * w2;
        }
        __syncthreads();
    }
    double* zph = zp + (size_t)qt * BB * NF;
#pragma unroll
    for (int j = 0; j < 3; ++j) {
        int col = 3 * tn + j;
        if (col < NF) {
#pragma unroll
            for (int i = 0; i < 4; ++i)
                zph[(size_t)(m0 + 4 * tm + i) * NF + col] = acc[i][j];
        }
    }
}

// ---------------- split-K reduce: z = (float)(((p0+p1)+(p2+p3))+bias), fused col stats --------
__global__ void k_ctrl_reduce(const double* __restrict__ zp, const float* __restrict__ bias,
                              float* __restrict__ z, double* __restrict__ stats) {
    __shared__ double Sred[2][16][48];
    const int t = threadIdx.x;
    const int tn = t & 15;
    const int tm = t >> 4;
    const int m0 = blockIdx.x * 64;
    const size_t H = (size_t)BB * NF;
#pragma unroll
    for (int j = 0; j < 3; ++j) {
        int col = 3 * tn + j;
        double s = 0.0, q = 0.0;
        if (col < NF) {
            float bs = bias[col];
#pragma unroll
            for (int i = 0; i < 4; ++i) {
                size_t idx = (size_t)(m0 + 4 * tm + i) * NF + col;
                double p01 = (zp[idx] + zp[H + idx]) + (zp[2 * H + idx] + zp[3 * H + idx]);
                float v = (float)(p01 + (double)bs);
                z[idx] = v;
                s += (double)v;
                q += (double)v * (double)v;
            }
        }
        Sred[0][tm][col] = s;
        Sred[1][tm][col] = q;
    }
    __syncthreads();
    if (t < NF) {
        double ts = 0.0, tq = 0.0;
#pragma unroll
        for (int i = 0; i < 16; ++i) { ts += Sred[0][i][t]; tq += Sred[1][i][t]; }
        atomicAdd(&stats[t], ts);
        atomicAdd(&stats[NF + t], tq);
    }
}

// ---------------- ctrl-BN finalize + BN+ReLU + rank top-k + gather-gate -> flatg (fused) --------
__global__ void k_topk_gate(const float* __restrict__ zc, const double* __restrict__ stats,
                            const float* __restrict__ cbg, const float* __restrict__ cbb,
                            const int* __restrict__ kptr, const int* __restrict__ x,
                            const float* __restrict__ emb, const double* __restrict__ stats_f,
                            const float* __restrict__ bng, const float* __restrict__ bnb,
                            unsigned short* __restrict__ flatg) {
    __shared__ float sc_s[NF], sh_s[NF], fsc[NF], fsh[NF];
    int t = threadIdx.x;
    if (t < NF) {
        double mu = stats[t] / (double)BB;
        double var = stats[NF + t] / (double)BB - mu * mu;
        float sc = (float)((double)cbg[t] / sqrt(var + (double)EPS_));
        sc_s[t] = sc;
        sh_s[t] = cbb[t] - (float)mu * sc;
        double cnt = (double)BB * NE;
        double muf = stats_f[t] / cnt;
        double varf = stats_f[NF + t] / cnt - muf * muf;
        float scf = (float)((double)bng[t] / sqrt(varf + (double)EPS_));
        fsc[t] = scf;
        fsh[t] = bnb[t] - (float)muf * scf;
    }
    __syncthreads();
    int r = blockIdx.x * 4 + (t >> 6);
    int lane = t & 63;
    int k = kptr[0];
    bool active = (lane < NF);
    float w = -1.f;
    if (active) {
        float v = zc[(size_t)r * NF + lane];
        w = fmaxf(fmaf(v, sc_s[lane], sh_s[lane]), 0.f);
    }
    int rank = 0;
#pragma unroll
    for (int j = 0; j < NF; ++j) {
        float vj = __shfl(w, j, 64);
        rank += (vj > w || (vj == w && j < lane)) ? 1 : 0;
    }
    bool sel = active && (rank < k);
    float val = sel ? w : 0.f;
    float sum = val;
#pragma unroll
    for (int off = 32; off > 0; off >>= 1) sum += __shfl_xor(sum, off, 64);
    if (active) {
        float ms = sel ? ((sum > 0.f) ? (w / sum) : 0.f) : 0.f;
        int o = (x[r * NF + lane] + lane * FIELD_DIM) * NE;
        const float4* pe = (const float4*)(emb + o);
        float sc = fsc[lane], sh = fsh[lane];
        unsigned short* dst = flatg + (size_t)r * 640 + lane * 16;
#pragma unroll
        for (int h = 0; h < 2; ++h) {
            float4 e0 = pe[h * 2], e1 = pe[h * 2 + 1];
            float e[8] = {e0.x, e0.y, e0.z, e0.w, e1.x, e1.y, e1.z, e1.w};
            union { s16x8 v; unsigned short u[8]; } p;
#pragma unroll
            for (int j = 0; j < 8; ++j)
                p.u[j] = f2bf(fmaf(e[j], sc, sh) * ms);   // same op order as flat path
            *(s16x8*)(dst + h * 8) = p.v;
        }
    } else if (lane == NF) {
        s16x8 zv = {};
        *(s16x8*)(flatg + (size_t)r * 640 + 624) = zv;
        *(s16x8*)(flatg + (size_t)r * 640 + 632) = zv;
    }
}

// ---------------- bf16 MFMA GEMM (layer 1): 2-phase double-buffered pipeline ----------------
__launch_bounds__(256)
__global__ void k_mfma_gemm(const unsigned short* __restrict__ A,  // M x K bf16
                            const unsigned short* __restrict__ Bt, // N x K bf16
                            const float* __restrict__ bias,
                            unsigned short* __restrict__ C,        // M x N bf16
                            double* __restrict__ stats,            // 2*N fp64
                            int M, int K, int N, int lognx) {
    __shared__ char lds[65536];   // A0 A1 B0 B1, 16KB each
    const int t = threadIdx.x;
    const int l = t & 63;
    const int w = t >> 6;
    int bx, by;
    xcd_map(blockIdx.x, lognx, bx, by);
    const int m0 = by * 128, n0 = bx * 128;
    const int Wr = (w >> 1) * 64, Wc = (w & 1) * 64;

    const int srow = t >> 3;            // 0..31
    const int sswz = (t & 7) ^ (srow & 7);
    const unsigned short* ga[4];
    const unsigned short* gb[4];
#pragma unroll
    for (int i = 0; i < 4; ++i) {
        ga[i] = A + (size_t)(m0 + i * 32 + srow) * K + sswz * 8;
        gb[i] = Bt + (size_t)(n0 + i * 32 + srow) * K + sswz * 8;
    }
    int a_off[4][2], b_off[4][2];
#pragma unroll
    for (int m = 0; m < 4; ++m) {
#pragma unroll
        for (int h = 0; h < 2; ++h) {
            int r = Wr + m * 16 + (l & 15);
            a_off[m][h] = r * 128 + (((h * 4 + (l >> 4)) ^ (r & 7)) << 4);
            int c = Wc + m * 16 + (l & 15);
            b_off[m][h] = c * 128 + (((h * 4 + (l >> 4)) ^ (c & 7)) << 4);
        }
    }
    const int nt = K >> 6;
    f32x4 acc[4][4] = {};
#pragma unroll
    for (int i = 0; i < 4; ++i) {
        __builtin_amdgcn_global_load_lds(
            (const __attribute__((address_space(1))) void*)ga[i],
            (__attribute__((address_space(3))) void*)(lds + i * 4096 + t * 16), 16, 0, 0);
        __builtin_amdgcn_global_load_lds(
            (const __attribute__((address_space(1))) void*)gb[i],
            (__attribute__((address_space(3))) void*)(lds + 32768 + i * 4096 + t * 16), 16, 0, 0);
        ga[i] += 64; gb[i] += 64;
    }
    __syncthreads();
    for (int ts = 0; ts < nt; ++ts) {
        const int cur = ts & 1;
        if (ts + 1 < nt) {
            char* An = lds + (cur ^ 1) * 16384;
            char* Bn = lds + 32768 + (cur ^ 1) * 16384;
#pragma unroll
            for (int i = 0; i < 4; ++i) {
                __builtin_amdgcn_global_load_lds(
                    (const __attribute__((address_space(1))) void*)ga[i],
                    (__attribute__((address_space(3))) void*)(An + i * 4096 + t * 16), 16, 0, 0);
                __builtin_amdgcn_global_load_lds(
                    (const __attribute__((address_space(1))) void*)gb[i],
                    (__attribute__((address_space(3))) void*)(Bn + i * 4096 + t * 16), 16, 0, 0);
                ga[i] += 64; gb[i] += 64;
            }
        }
        const char* Ac = lds + cur * 16384;
        const char* Bc = lds + 32768 + cur * 16384;
#pragma unroll
        for (int h = 0; h < 2; ++h) {
            bfx8 af[4], bv[4];
#pragma unroll
            for (int m = 0; m < 4; ++m)
                af[m] = __builtin_bit_cast(bfx8, *(const s16x8*)(Ac + a_off[m][h]));
#pragma unroll
            for (int n = 0; n < 4; ++n)
                bv[n] = __builtin_bit_cast(bfx8, *(const s16x8*)(Bc + b_off[n][h]));
#pragma unroll
            for (int m = 0; m < 4; ++m)
#pragma unroll
                for (int n = 0; n < 4; ++n)
                    acc[m][n] = __builtin_amdgcn_mfma_f32_16x16x32_bf16(af[m], bv[n], acc[m][n], 0, 0, 0);
        }
        __syncthreads();
    }
#pragma unroll
    for (int n = 0; n < 4; ++n) {
        int nc = n0 + Wc + n * 16 + (l & 15);
        float bs = bias[nc];
        double s = 0.0, q = 0.0;
#pragma unroll
        for (int m = 0; m < 4; ++m) {
            int rbase = m0 + Wr + m * 16 + ((l >> 4) << 2);
#pragma unroll
            for (int i = 0; i < 4; ++i) {
                float v = acc[m][n][i] + bs;
                C[(size_t)(rbase + i) * N + nc] = f2bf(v);
                s += (double)v;
                q += (double)v * (double)v;
            }
        }
        s += __shfl_xor(s, 16, 64); s += __shfl_xor(s, 32, 64);
        q += __shfl_xor(q, 16, 64); q += __shfl_xor(q, 32, 64);
        if ((l >> 4) == 0) {
            atomicAdd(&stats[nc], s);
            atomicAdd(&stats[N + nc], q);
        }
    }
}

// ---------------- bf16 MFMA GEMM with fused input-BN+ReLU on A (layers 2,3) ----------------
__launch_bounds__(256)
__global__ void k_mfma_gemm_bn(const unsigned short* __restrict__ A,   // M x K bf16 raw
                               const double* __restrict__ statsIn,     // 2*K (A's BN stats)
                               const float* __restrict__ g, const float* __restrict__ be,
                               const unsigned short* __restrict__ Bt,  // N x K bf16
                               const float* __restrict__ bias,
                               unsigned short* __restrict__ C,         // M x N bf16
                               double* __restrict__ stats,             // 2*N fp64
                               int M, int K, int N, int lognx) {
    __shared__ char lds[73728];           // A0 A1 B0 B1 (16KB each) + scs/shs (8KB)
    float* scs = (float*)(lds + 65536);   // K floats
    float* shs = scs + K;                 // K floats (K<=1024)
    const int t = threadIdx.x;
    const int l = t & 63;
    const int w = t >> 6;
    int bx, by;
    xcd_map(blockIdx.x, lognx, bx, by);
    const int m0 = by * 128, n0 = bx * 128;
    const int Wr = (w >> 1) * 64, Wc = (w & 1) * 64;

    constexpr double inv_bb = 1.0 / (double)BB;
    for (int c = t; c < K; c += 256) {
        double mu = statsIn[c] * inv_bb;
        double var = statsIn[K + c] * inv_bb - mu * mu;
        float sc = g[c] / sqrtf((float)var + EPS_);
        scs[c] = sc;
        shs[c] = be[c] - (float)mu * sc;
    }
    __syncthreads();

    const int srow = t >> 3;            // 0..31
    const int sswz = (t & 7) ^ (srow & 7);
    const unsigned short* ga[4];
    const unsigned short* gb[4];
#pragma unroll
    for (int i = 0; i < 4; ++i) {
        ga[i] = A + (size_t)(m0 + i * 32 + srow) * K + sswz * 8;
        gb[i] = Bt + (size_t)(n0 + i * 32 + srow) * K + sswz * 8;
    }
    int a_off[4][2], b_off[4][2];
#pragma unroll
    for (int m = 0; m < 4; ++m) {
#pragma unroll
        for (int h = 0; h < 2; ++h) {
            int r = Wr + m * 16 + (l & 15);
            a_off[m][h] = r * 128 + (((h * 4 + (l >> 4)) ^ (r & 7)) << 4);
            int c = Wc + m * 16 + (l & 15);
            b_off[m][h] = c * 128 + (((h * 4 + (l >> 4)) ^ (c & 7)) << 4);
        }
    }
    const int nt = K >> 6;
    f32x4 acc[4][4] = {};
    s16x8 praw[4];

    auto write_a = [&](int buf, int kb0) {
        char* Ad = lds + buf * 16384;
        int kb = kb0 + sswz * 8;
        float4 sc0 = *(const float4*)&scs[kb];
        float4 sc1 = *(const float4*)&scs[kb + 4];
        float4 sh0 = *(const float4*)&shs[kb];
        float4 sh1 = *(const float4*)&shs[kb + 4];
        float scl[8] = {sc0.x, sc0.y, sc0.z, sc0.w, sc1.x, sc1.y, sc1.z, sc1.w};
        float shl[8] = {sh0.x, sh0.y, sh0.z, sh0.w, sh1.x, sh1.y, sh1.z, sh1.w};
#pragma unroll
        for (int i = 0; i < 4; ++i) {
            union { s16x8 v; unsigned short u[8]; } pin;
            pin.v = praw[i];
            float f[8];
#pragma unroll
            for (int j = 0; j < 8; ++j)
                f[j] = fmaxf(fmaf(bf2f(pin.u[j]), scl[j], shl[j]), 0.f);
            union { unsigned w4[4]; s16x8 v; } pout;
#pragma unroll
            for (int j = 0; j < 4; ++j) {
                unsigned rr;
                asm("v_cvt_pk_bf16_f32 %0, %1, %2" : "=v"(rr) : "v"(f[2 * j]), "v"(f[2 * j + 1]));
                pout.w4[j] = rr;
            }
            *(s16x8*)(Ad + i * 4096 + t * 16) = pout.v;
        }
    };
    auto load_praw = [&]() {
#pragma unroll
        for (int i = 0; i < 4; ++i) { praw[i] = *(const s16x8*)ga[i]; ga[i] += 64; }
    };
    auto stage_b = [&](int buf) {
        char* Bd = lds + 32768 + buf * 16384;
#pragma unroll
        for (int i = 0; i < 4; ++i) {
            __builtin_amdgcn_global_load_lds(
                (const __attribute__((address_space(1))) void*)gb[i],
                (__attribute__((address_space(3))) void*)(Bd + i * 4096 + t * 16), 16, 0, 0);
            gb[i] += 64;
        }
    };

    load_praw();
    stage_b(0);
    write_a(0, 0);
    if (nt > 1) load_praw();
    __syncthreads();

    for (int ts = 0; ts < nt; ++ts) {
        const int cur = ts & 1;
        if (ts + 1 < nt) {
            stage_b(cur ^ 1);
            write_a(cur ^ 1, (ts + 1) << 6);
            if (ts + 2 < nt) load_praw();
        }
        const char* Ac = lds + cur * 16384;
        const char* Bc = lds + 32768 + cur * 16384;
#pragma unroll
        for (int h = 0; h < 2; ++h) {
            bfx8 af[4], bv[4];
#pragma unroll
            for (int m = 0; m < 4; ++m)
                af[m] = __builtin_bit_cast(bfx8, *(const s16x8*)(Ac + a_off[m][h]));
#pragma unroll
            for (int n = 0; n < 4; ++n)
                bv[n] = __builtin_bit_cast(bfx8, *(const s16x8*)(Bc + b_off[n][h]));
#pragma unroll
            for (int m = 0; m < 4; ++m)
#pragma unroll
                for (int n = 0; n < 4; ++n)
                    acc[m][n] = __builtin_amdgcn_mfma_f32_16x16x32_bf16(af[m], bv[n], acc[m][n], 0, 0, 0);
        }
        __syncthreads();
    }
#pragma unroll
    for (int n = 0; n < 4; ++n) {
        int nc = n0 + Wc + n * 16 + (l & 15);
        float bs = bias[nc];
        double s = 0.0, q = 0.0;
#pragma unroll
        for (int m = 0; m < 4; ++m) {
            int rbase = m0 + Wr + m * 16 + ((l >> 4) << 2);
#pragma unroll
            for (int i = 0; i < 4; ++i) {
                float v = acc[m][n][i] + bs;
                C[(size_t)(rbase + i) * N + nc] = f2bf(v);
                s += (double)v;
                q += (double)v * (double)v;
            }
        }
        s += __shfl_xor(s, 16, 64); s += __shfl_xor(s, 32, 64);
        q += __shfl_xor(q, 16, 64); q += __shfl_xor(q, 32, 64);
        if ((l >> 4) == 0) {
            atomicAdd(&stats[nc], s);
            atomicAdd(&stats[N + nc], q);
        }
    }
}

// ---------------- final: bn3+ReLU on raw h3, dot w_out, + wide linear, sigmoid ----------------
__global__ void k_out(const unsigned short* __restrict__ h3, const double* __restrict__ stats3,
                      const float* __restrict__ g3, const float* __restrict__ be3,
                      const float* __restrict__ wo, const float* __restrict__ bo,
                      const int* __restrict__ x, const float* __restrict__ lt,
                      const float* __restrict__ lb, float* __restrict__ out) {
    __shared__ float scs[256], shs[256];
    int t = threadIdx.x;
    {
        constexpr double inv_bb = 1.0 / (double)BB;
        double mu = stats3[t] * inv_bb;
        double var = stats3[256 + t] * inv_bb - mu * mu;
        float sc = g3[t] / sqrtf((float)var + EPS_);
        scs[t] = sc;
        shs[t] = be3[t] - (float)mu * sc;
    }
    __syncthreads();
    int r = blockIdx.x * 4 + (t >> 6);
    int lane = t & 63;
    float s = 0.f;
#pragma unroll
    for (int k = lane; k < 256; k += 64) {
        float xv = bf2f(h3[(size_t)r * 256 + k]);
        float hb = bf2f(f2bf(fmaxf(fmaf(xv, scs[k], shs[k]), 0.f)));
        s += hb * wo[k];
    }
    if (lane < NF) {
        long long id = (long long)x[r * NF + lane] + (long long)lane * FIELD_DIM;
        s += lt[id];
    }
#pragma unroll
    for (int off = 32; off > 0; off >>= 1) s += __shfl_xor(s, off, 64);
    if (lane == 0) {
        float tt = s + bo[0] + lb[0];
        out[r] = 1.f / (1.f + expf(-tt));
    }
}

extern "C" void kernel_launch(void* const* d_in, const int* in_sizes, int n_in,
                              void* d_out, int out_size, void* d_ws, size_t ws_size,
                              hipStream_t stream) {
    const int* x = (const int*)d_in[0];
    const float* emb = (const float*)d_in[1];
    const float* lint = (const float*)d_in[2];
    const float* linb = (const float*)d_in[3];
    const float* bng = (const float*)d_in[4];
    const float* bnb = (const float*)d_in[5];
    const float* cw = (const float*)d_in[6];
    const float* cb = (const float*)d_in[7];
    const float* cbg = (const float*)d_in[8];
    const float* cbb = (const float*)d_in[9];
    const float* w1 = (const float*)d_in[10];
    const float* b1 = (const float*)d_in[11];
    const float* g1 = (const float*)d_in[12];
    const float* be1 = (const float*)d_in[13];
    const float* w2 = (const float*)d_in[14];
    const float* b2 = (const float*)d_in[15];
    const float* g2 = (const float*)d_in[16];
    const float* be2 = (const float*)d_in[17];
    const float* w3 = (const float*)d_in[18];
    const float* b3 = (const float*)d_in[19];
    const float* g3 = (const float*)d_in[20];
    const float* be3 = (const float*)d_in[21];
    const float* wo = (const float*)d_in[22];
    const float* bo = (const float*)d_in[23];
    const int* kptr = (const int*)d_in[24];
    float* out = (float*)d_out;

    char* p = (char*)d_ws;
    unsigned short* flatg = (unsigned short*)p; p += (size_t)BB * 640 * 2;  // gated bf16, K-padded
    unsigned short* h1 = (unsigned short*)p; p += (size_t)BB * 1024 * 2;    // raw (pre-BN)
    unsigned short* h2 = (unsigned short*)p; p += (size_t)BB * 512 * 2;     // raw
    unsigned short* h3 = (unsigned short*)p; p += (size_t)BB * 256 * 2;     // raw
    unsigned short* w1t = (unsigned short*)p; p += (size_t)1024 * 640 * 2;
    unsigned short* w2t = (unsigned short*)p; p += (size_t)512 * 1024 * 2;
    unsigned short* w3t = (unsigned short*)p; p += (size_t)256 * 512 * 2;
    float* wct = (float*)p;                  p += (size_t)48 * ND * 4;      // ctrl w transposed fp32
    float* zc = (float*)p;                   p += (size_t)BB * NF * 4;
    double* zp = (double*)p;                 p += (size_t)4 * BB * NF * 8;  // split-K x4 partials fp64
    // disjoint per-layer fp64 stat regions, zeroed inside k_prep
    double* stats_all = (double*)p;
    double* stats_f = stats_all;             // 2*39
    double* stats_c = stats_f + 2 * NF;      // 2*39
    double* stats_1 = stats_c + 2 * NF;      // 2*1024
    double* stats_2 = stats_1 + 2 * 1024;    // 2*512
    double* stats_3 = stats_2 + 2 * 512;     // 2*256
    int stats_doubles = 2 * (NF + NF + 1024 + 512 + 256); // 3662

    // ---- prep: tiled weight transposes + stats zero (one kernel, 1412 blocks) ----
    k_prep<<<1412, 256, 0, stream>>>(w1, w2, w3, cw, w1t, w2t, w3t, wct,
                                     stats_all, stats_doubles);

    // ---- field BN stats (finalize is recomputed in consumers, bit-identically) ----
    k_field_stats<<<dim3(NF, BB / 256), 256, 0, stream>>>(x, emb, stats_f);

    // ---- controller: gather-fused split-K x4 GEMM + reduce/stats + fused finalize/topk/gate ----
    k_ctrl_gemm_sk<<<1024, 256, 0, stream>>>(x, emb, stats_f, bng, bnb, wct, zp);
    k_ctrl_reduce<<<BB / 64, 256, 0, stream>>>(zp, cb, zc, stats_c);
    k_topk_gate<<<BB / 4, 256, 0, stream>>>(zc, stats_c, cbg, cbb, kptr, x, emb,
                                            stats_f, bng, bnb, flatg);

    // ---- MLP layer 1: 640(pad) -> 1024 (h1 raw), XCD-swizzled 1D grid, 2-phase pipeline ----
    k_mfma_gemm<<<(1024 / 128) * (BB / 128), 256, 0, stream>>>(flatg, w1t, b1, h1, stats_1,
                                                               BB, 640, 1024, 3);

    // ---- MLP layer 2: BN1+ReLU fused into A-staging; 1024 -> 512 (h2 raw) ----
    k_mfma_gemm_bn<<<(512 / 128) * (BB / 128), 256, 0, stream>>>(h1, stats_1, g1, be1,
                                                                 w2t, b2, h2, stats_2,
                                                                 BB, 1024, 512, 2);

    // ---- MLP layer 3: BN2+ReLU fused; 512 -> 256 (h3 raw) ----
    k_mfma_gemm_bn<<<(256 / 128) * (BB / 128), 256, 0, stream>>>(h2, stats_2, g2, be2,
                                                                 w3t, b3, h3, stats_3,
                                                                 BB, 512, 256, 1);

    // ---- output: BN3+ReLU + dot w_out + wide linear + sigmoid ----
    k_out<<<BB / 4, 256, 0, stream>>>(h3, stats_3, g3, be3, wo, bo, x, lint, linb, out);
}